// Round 3
// baseline (2237.351 us; speedup 1.0000x reference)
//
#include <hip/hip_runtime.h>
#include <math.h>

#define HDIM 256
#define NMOL 4096
#define NPROT 4096
#define NEDGE 65536
#define NG 32

typedef _Float16 f16x8 __attribute__((ext_vector_type(8)));
typedef __attribute__((ext_vector_type(4))) float f32x4;

__device__ __forceinline__ void splitf(float x, _Float16& h, _Float16& l) {
  h = (_Float16)x;
  l = (_Float16)(x - (float)h);
}

// ---------------------------------------------------------------------------
// Transpose + convert 14 H x H fp32 weights into split f16 planes Wt[n][k].
struct PtrPack { const float* p[14]; };

__global__ __launch_bounds__(256) void k_prep_wt(PtrPack pk, _Float16* __restrict__ dh,
                                                 _Float16* __restrict__ dl) {
  __shared__ float Ts[64][68];
  const int m = blockIdx.z;
  const int n0 = blockIdx.y * 64, k0 = blockIdx.x * 64;
  const float* W = pk.p[m];
  const int t = threadIdx.x;
#pragma unroll
  for (int rep = 0; rep < 16; ++rep) {
    int k = rep * 4 + (t >> 6);
    int n = t & 63;
    Ts[n][k] = W[(size_t)(k0 + k) * 256 + n0 + n];
  }
  __syncthreads();
#pragma unroll
  for (int rep = 0; rep < 2; ++rep) {
    int idx = t + rep * 256;
    int nr = idx >> 3, koff = (idx & 7) * 8;
    f16x8 vh, vl;
#pragma unroll
    for (int i = 0; i < 8; ++i) {
      _Float16 h, l;
      splitf(Ts[nr][koff + i], h, l);
      vh[i] = h; vl[i] = l;
    }
    size_t off = (size_t)m * 65536 + (size_t)(n0 + nr) * 256 + k0 + koff;
    *(f16x8*)&dh[off] = vh;
    *(f16x8*)&dl[off] = vl;
  }
}

// ---------------------------------------------------------------------------
// node embedding (fp32 out)
__global__ __launch_bounds__(256) void k_node_embed(
    const float* __restrict__ x, const float* __restrict__ w,
    const float* __restrict__ b, float* __restrict__ out, int K) {
  const int i = blockIdx.x;
  const int c = threadIdx.x;
  float acc = b[c];
  for (int k = 0; k < K; ++k) acc += x[i * K + k] * w[k * HDIM + c];
  out[(size_t)i * HDIM + c] = acc;
}

// ---------------------------------------------------------------------------
// GINE aggregation: 8 edges/block, fp32 x, fp32 atomics (exact fp32 math)
__global__ __launch_bounds__(256) void k_gine_agg(
    const float* __restrict__ x, const float* __restrict__ ea,
    const int* __restrict__ ei, const float* __restrict__ we,
    const float* __restrict__ be, float* __restrict__ agg, int E) {
  const int t = threadIdx.x;
  const int e = blockIdx.x * 8 + (t >> 5);
  const int c = (t & 31) * 8;
  const int src = ei[e];
  const int dst = ei[E + e];
  const float a0 = ea[2 * e], a1 = ea[2 * e + 1];
  float4 x0 = *(const float4*)&x[(size_t)src * HDIM + c];
  float4 x1 = *(const float4*)&x[(size_t)src * HDIM + c + 4];
  float4 w00 = *(const float4*)&we[c],        w01 = *(const float4*)&we[c + 4];
  float4 w10 = *(const float4*)&we[HDIM + c], w11 = *(const float4*)&we[HDIM + c + 4];
  float4 b0 = *(const float4*)&be[c],         b1 = *(const float4*)&be[c + 4];
  float xs[8] = {x0.x, x0.y, x0.z, x0.w, x1.x, x1.y, x1.z, x1.w};
  float ws0[8] = {w00.x, w00.y, w00.z, w00.w, w01.x, w01.y, w01.z, w01.w};
  float ws1[8] = {w10.x, w10.y, w10.z, w10.w, w11.x, w11.y, w11.z, w11.w};
  float bs[8] = {b0.x, b0.y, b0.z, b0.w, b1.x, b1.y, b1.z, b1.w};
#pragma unroll
  for (int i = 0; i < 8; ++i) {
    float m = xs[i] + a0 * ws0[i] + a1 * ws1[i] + bs[i];
    if (m > 0.f) atomicAdd(&agg[(size_t)dst * HDIM + c + i], m);
  }
}

// ---------------------------------------------------------------------------
// Split-f16 MFMA GEMM: C = act((A1 [+A2]) @ W + b), K=256, fp32 in/out.
// Each logical MFMA -> 3 f16 MFMAs (hi*hi + hi*lo + lo*hi), fp32 accum.
template <bool RELU, bool HASA2>
__global__ __launch_bounds__(256) void k_gemm_split(
    const float* __restrict__ A1, const float* __restrict__ A2,
    const _Float16* __restrict__ WtH, const _Float16* __restrict__ WtL,
    const float* __restrict__ bias, float* __restrict__ C) {
  __shared__ _Float16 Ah[64][72], Al[64][72], Bh[64][72], Bl[64][72];
  const int t = threadIdx.x;
  const int bm = blockIdx.x * 64, bn = blockIdx.y * 64;
  const int lane = t & 63, w = t >> 6;
  const int l15 = lane & 15, l4 = lane >> 4;
  const int wm = (w >> 1) * 32, wn = (w & 1) * 32;
  f32x4 acc[2][2] = {};
  for (int k0 = 0; k0 < 256; k0 += 64) {
    __syncthreads();
#pragma unroll
    for (int rep = 0; rep < 4; ++rep) {
      int idx = t + rep * 256;
      int r = idx >> 4, c4 = (idx & 15) * 4;
      float4 a = *(const float4*)&A1[(size_t)(bm + r) * 256 + k0 + c4];
      if (HASA2) {
        float4 a2 = *(const float4*)&A2[(size_t)(bm + r) * 256 + k0 + c4];
        a.x += a2.x; a.y += a2.y; a.z += a2.z; a.w += a2.w;
      }
      float av[4] = {a.x, a.y, a.z, a.w};
#pragma unroll
      for (int i = 0; i < 4; ++i) splitf(av[i], Ah[r][c4 + i], Al[r][c4 + i]);
    }
#pragma unroll
    for (int rep = 0; rep < 2; ++rep) {
      int idx = t + rep * 256;
      int nr = idx >> 3, koff = (idx & 7) * 8;
      size_t off = (size_t)(bn + nr) * 256 + k0 + koff;
      *(f16x8*)&Bh[nr][koff] = *(const f16x8*)&WtH[off];
      *(f16x8*)&Bl[nr][koff] = *(const f16x8*)&WtL[off];
    }
    __syncthreads();
#pragma unroll
    for (int kh = 0; kh < 2; ++kh) {
      f16x8 a0h = *(f16x8*)&Ah[wm + l15][kh * 32 + l4 * 8];
      f16x8 a0l = *(f16x8*)&Al[wm + l15][kh * 32 + l4 * 8];
      f16x8 a1h = *(f16x8*)&Ah[wm + 16 + l15][kh * 32 + l4 * 8];
      f16x8 a1l = *(f16x8*)&Al[wm + 16 + l15][kh * 32 + l4 * 8];
      f16x8 b0h = *(f16x8*)&Bh[wn + l15][kh * 32 + l4 * 8];
      f16x8 b0l = *(f16x8*)&Bl[wn + l15][kh * 32 + l4 * 8];
      f16x8 b1h = *(f16x8*)&Bh[wn + 16 + l15][kh * 32 + l4 * 8];
      f16x8 b1l = *(f16x8*)&Bl[wn + 16 + l15][kh * 32 + l4 * 8];
      acc[0][0] = __builtin_amdgcn_mfma_f32_16x16x32_f16(a0h, b0h, acc[0][0], 0, 0, 0);
      acc[0][0] = __builtin_amdgcn_mfma_f32_16x16x32_f16(a0h, b0l, acc[0][0], 0, 0, 0);
      acc[0][0] = __builtin_amdgcn_mfma_f32_16x16x32_f16(a0l, b0h, acc[0][0], 0, 0, 0);
      acc[0][1] = __builtin_amdgcn_mfma_f32_16x16x32_f16(a0h, b1h, acc[0][1], 0, 0, 0);
      acc[0][1] = __builtin_amdgcn_mfma_f32_16x16x32_f16(a0h, b1l, acc[0][1], 0, 0, 0);
      acc[0][1] = __builtin_amdgcn_mfma_f32_16x16x32_f16(a0l, b1h, acc[0][1], 0, 0, 0);
      acc[1][0] = __builtin_amdgcn_mfma_f32_16x16x32_f16(a1h, b0h, acc[1][0], 0, 0, 0);
      acc[1][0] = __builtin_amdgcn_mfma_f32_16x16x32_f16(a1h, b0l, acc[1][0], 0, 0, 0);
      acc[1][0] = __builtin_amdgcn_mfma_f32_16x16x32_f16(a1l, b0h, acc[1][0], 0, 0, 0);
      acc[1][1] = __builtin_amdgcn_mfma_f32_16x16x32_f16(a1h, b1h, acc[1][1], 0, 0, 0);
      acc[1][1] = __builtin_amdgcn_mfma_f32_16x16x32_f16(a1h, b1l, acc[1][1], 0, 0, 0);
      acc[1][1] = __builtin_amdgcn_mfma_f32_16x16x32_f16(a1l, b1h, acc[1][1], 0, 0, 0);
    }
  }
#pragma unroll
  for (int mi = 0; mi < 2; ++mi)
#pragma unroll
    for (int ni = 0; ni < 2; ++ni) {
      int col = bn + wn + ni * 16 + l15;
      float bv = bias[col];
#pragma unroll
      for (int r = 0; r < 4; ++r) {
        int row = bm + wm + mi * 16 + l4 * 4 + r;
        float v = acc[mi][ni][r] + bv;
        if (RELU) v = fmaxf(v, 0.f);
        C[(size_t)row * 256 + col] = v;
      }
    }
}

// ---------------------------------------------------------------------------
// Split-f16 MFMA flash attention. Block = (64-q tile, head); 4 waves.
// Out = Hin + softmax(Q K^T / 8) V, fp32 in/out, fp32 softmax state.
__global__ __launch_bounds__(256) void k_attn_split(
    const float* __restrict__ Q, const float* __restrict__ Kg,
    const float* __restrict__ Vg, const float* __restrict__ Hin,
    float* __restrict__ Out, int nk) {
  __shared__ _Float16 Kh[64][72], Kl[64][72];     // [k][d]
  __shared__ _Float16 Vth[64][72], Vtl[64][72];   // [d][k], chunk-swizzled
  __shared__ _Float16 Psh[4][16][72], Psl[4][16][72];  // per-wave P [q][k]
  const int t = threadIdx.x;
  const int h = blockIdx.y;
  const int q0 = blockIdx.x * 64;
  const int lane = t & 63, w = t >> 6;
  const int l15 = lane & 15, l4 = lane >> 4;

  f16x8 qh[2], ql[2];
  {
    const float* qrow = Q + (size_t)(q0 + w * 16 + l15) * 256 + h * 64;
#pragma unroll
    for (int kh = 0; kh < 2; ++kh) {
      float4 v0 = *(const float4*)(qrow + kh * 32 + l4 * 8);
      float4 v1 = *(const float4*)(qrow + kh * 32 + l4 * 8 + 4);
      float qv[8] = {v0.x, v0.y, v0.z, v0.w, v1.x, v1.y, v1.z, v1.w};
#pragma unroll
      for (int i = 0; i < 8; ++i) {
        _Float16 hh, ll;
        splitf(qv[i] * 0.125f, hh, ll);
        qh[kh][i] = hh; ql[kh][i] = ll;
      }
    }
  }
  f32x4 o[4] = {};
  float mrun[4] = {-1e30f, -1e30f, -1e30f, -1e30f};
  float lrun[4] = {0.f, 0.f, 0.f, 0.f};

  for (int k0 = 0; k0 < nk; k0 += 64) {
    __syncthreads();
#pragma unroll
    for (int rep = 0; rep < 4; ++rep) {
      int idx = t + rep * 256;
      int kr = idx >> 4, d4 = (idx & 15) * 4;
      float4 kv = *(const float4*)(Kg + (size_t)(k0 + kr) * 256 + h * 64 + d4);
      float4 vv = *(const float4*)(Vg + (size_t)(k0 + kr) * 256 + h * 64 + d4);
      float kvs[4] = {kv.x, kv.y, kv.z, kv.w};
      float vvs[4] = {vv.x, vv.y, vv.z, vv.w};
#pragma unroll
      for (int i = 0; i < 4; ++i) {
        splitf(kvs[i], Kh[kr][d4 + i], Kl[kr][d4 + i]);
        int d = d4 + i;
        int col = (((kr >> 3) ^ ((d >> 3) & 7)) << 3) + (kr & 7);
        splitf(vvs[i], Vth[d][col], Vtl[d][col]);
      }
    }
    __syncthreads();

    // S = Q K^T (per wave: 16 q x 64 k)
    f32x4 sf[4] = {};
#pragma unroll
    for (int kc = 0; kc < 4; ++kc) {
      f16x8 kf0h = *(f16x8*)&Kh[kc * 16 + l15][l4 * 8];
      f16x8 kf0l = *(f16x8*)&Kl[kc * 16 + l15][l4 * 8];
      f16x8 kf1h = *(f16x8*)&Kh[kc * 16 + l15][32 + l4 * 8];
      f16x8 kf1l = *(f16x8*)&Kl[kc * 16 + l15][32 + l4 * 8];
      sf[kc] = __builtin_amdgcn_mfma_f32_16x16x32_f16(qh[0], kf0h, sf[kc], 0, 0, 0);
      sf[kc] = __builtin_amdgcn_mfma_f32_16x16x32_f16(qh[0], kf0l, sf[kc], 0, 0, 0);
      sf[kc] = __builtin_amdgcn_mfma_f32_16x16x32_f16(ql[0], kf0h, sf[kc], 0, 0, 0);
      sf[kc] = __builtin_amdgcn_mfma_f32_16x16x32_f16(qh[1], kf1h, sf[kc], 0, 0, 0);
      sf[kc] = __builtin_amdgcn_mfma_f32_16x16x32_f16(qh[1], kf1l, sf[kc], 0, 0, 0);
      sf[kc] = __builtin_amdgcn_mfma_f32_16x16x32_f16(ql[1], kf1h, sf[kc], 0, 0, 0);
    }

    // online softmax per q-row (rows on 16-lane groups)
#pragma unroll
    for (int r = 0; r < 4; ++r) {
      float s0 = sf[0][r], s1 = sf[1][r], s2 = sf[2][r], s3 = sf[3][r];
      float mt = fmaxf(fmaxf(s0, s1), fmaxf(s2, s3));
      mt = fmaxf(mt, __shfl_xor(mt, 1, 64));
      mt = fmaxf(mt, __shfl_xor(mt, 2, 64));
      mt = fmaxf(mt, __shfl_xor(mt, 4, 64));
      mt = fmaxf(mt, __shfl_xor(mt, 8, 64));
      float mn = fmaxf(mrun[r], mt);
      float alpha = __expf(mrun[r] - mn);
      mrun[r] = mn;
      float p0 = __expf(s0 - mn), p1 = __expf(s1 - mn);
      float p2 = __expf(s2 - mn), p3 = __expf(s3 - mn);
      float rs = p0 + p1 + p2 + p3;
      rs += __shfl_xor(rs, 1, 64);
      rs += __shfl_xor(rs, 2, 64);
      rs += __shfl_xor(rs, 4, 64);
      rs += __shfl_xor(rs, 8, 64);
      lrun[r] = lrun[r] * alpha + rs;
      o[0][r] *= alpha; o[1][r] *= alpha; o[2][r] *= alpha; o[3][r] *= alpha;
      int prow = l4 * 4 + r;
      float ps[4] = {p0, p1, p2, p3};
#pragma unroll
      for (int kc = 0; kc < 4; ++kc)
        splitf(ps[kc], Psh[w][prow][kc * 16 + l15], Psl[w][prow][kc * 16 + l15]);
    }

    // O += P @ V (per-wave P tile; same-wave write->read)
#pragma unroll
    for (int kh = 0; kh < 2; ++kh) {
      f16x8 pah = *(f16x8*)&Psh[w][l15][kh * 32 + l4 * 8];
      f16x8 pal = *(f16x8*)&Psl[w][l15][kh * 32 + l4 * 8];
#pragma unroll
      for (int oc = 0; oc < 4; ++oc) {
        int d = oc * 16 + l15;
        int chunk = (kh * 4 + l4) ^ ((d >> 3) & 7);
        f16x8 vbh = *(f16x8*)&Vth[d][chunk * 8];
        f16x8 vbl = *(f16x8*)&Vtl[d][chunk * 8];
        o[oc] = __builtin_amdgcn_mfma_f32_16x16x32_f16(pah, vbh, o[oc], 0, 0, 0);
        o[oc] = __builtin_amdgcn_mfma_f32_16x16x32_f16(pah, vbl, o[oc], 0, 0, 0);
        o[oc] = __builtin_amdgcn_mfma_f32_16x16x32_f16(pal, vbh, o[oc], 0, 0, 0);
      }
    }
  }

#pragma unroll
  for (int oc = 0; oc < 4; ++oc) {
    int col = h * 64 + oc * 16 + l15;
#pragma unroll
    for (int r = 0; r < 4; ++r) {
      int row = q0 + w * 16 + l4 * 4 + r;
      Out[(size_t)row * 256 + col] = o[oc][r] / lrun[r] + Hin[(size_t)row * 256 + col];
    }
  }
}

// ---------------------------------------------------------------------------
__global__ __launch_bounds__(256) void k_segsum(
    const float* __restrict__ Hc, const int* __restrict__ batch,
    float* __restrict__ z, float* __restrict__ cnt) {
  const int i = blockIdx.x;
  const int c = threadIdx.x;
  const int g = batch[i];
  atomicAdd(&z[(size_t)g * 512 + c], Hc[(size_t)i * HDIM + c]);
  if (c == 0) atomicAdd(&cnt[g], 1.0f);
}

__global__ __launch_bounds__(256) void k_segdiv(float* __restrict__ z,
                                                const float* __restrict__ cnt) {
  const int idx = blockIdx.x * 256 + threadIdx.x;  // 32*512
  const int g = idx >> 9, c = idx & 511;
  const float cc = cnt[(c < 256) ? g : (32 + g)];
  z[idx] /= fmaxf(cc, 1.0f);
}

__global__ __launch_bounds__(256) void k_fc1(
    const float* __restrict__ z, const float* __restrict__ w,
    const float* __restrict__ b, float* __restrict__ out) {
  const int idx = blockIdx.x * 256 + threadIdx.x;  // 32*256
  const int r = idx >> 8, c = idx & 255;
  float acc = b[c];
  for (int k = 0; k < 512; ++k) acc += z[r * 512 + k] * w[k * HDIM + c];
  out[idx] = fmaxf(acc, 0.f);
}

__global__ __launch_bounds__(64) void k_fc2(
    const float* __restrict__ xin, const float* __restrict__ w,
    const float* __restrict__ b, float* __restrict__ out) {
  const int r = threadIdx.x;
  if (r < NG) {
    float acc = b[0];
    for (int k = 0; k < HDIM; ++k) acc += xin[r * HDIM + k] * w[k];
    out[r] = 1.0f / (1.0f + __expf(-acc));
  }
}

// ---------------------------------------------------------------------------
extern "C" void kernel_launch(void* const* d_in, const int* in_sizes, int n_in,
                              void* d_out, int out_size, void* d_ws, size_t ws_size,
                              hipStream_t stream) {
  const float* x_mol   = (const float*)d_in[0];
  const float* x_prot  = (const float*)d_in[1];
  const float* ea_mol  = (const float*)d_in[2];
  const float* ea_prot = (const float*)d_in[3];
  const int*   ei_mol  = (const int*)d_in[4];
  const int*   ei_prot = (const int*)d_in[5];
  const int*   b_mol   = (const int*)d_in[6];
  const int*   b_prot  = (const int*)d_in[7];
  const float* nlm_w = (const float*)d_in[8];
  const float* nlm_b = (const float*)d_in[9];
  const float* nlp_w = (const float*)d_in[10];
  const float* nlp_b = (const float*)d_in[11];
  const float* elm_w = (const float*)d_in[12];
  const float* elm_b = (const float*)d_in[13];
  const float* elp_w = (const float*)d_in[14];
  const float* elp_b = (const float*)d_in[15];
  const float* mol_w1 = (const float*)d_in[16];
  const float* mol_b1 = (const float*)d_in[17];
  const float* mol_w2 = (const float*)d_in[18];
  const float* mol_b2 = (const float*)d_in[19];
  const float* prot_w1 = (const float*)d_in[20];
  const float* prot_b1 = (const float*)d_in[21];
  const float* prot_w2 = (const float*)d_in[22];
  const float* prot_b2 = (const float*)d_in[23];
  const float* mp_wq = (const float*)d_in[24];
  const float* mp_bq = (const float*)d_in[25];
  const float* mp_wk = (const float*)d_in[26];
  const float* mp_bk = (const float*)d_in[27];
  const float* mp_wv = (const float*)d_in[28];
  const float* mp_bv = (const float*)d_in[29];
  const float* pm_wq = (const float*)d_in[30];
  const float* pm_bq = (const float*)d_in[31];
  const float* pm_wk = (const float*)d_in[32];
  const float* pm_bk = (const float*)d_in[33];
  const float* pm_wv = (const float*)d_in[34];
  const float* pm_bv = (const float*)d_in[35];
  const float* fc1_w = (const float*)d_in[36];
  const float* fc1_b = (const float*)d_in[37];
  const float* fc2_w = (const float*)d_in[38];
  const float* fc2_b = (const float*)d_in[39];
  float* out = (float*)d_out;

  // workspace carve (bytes); peak ~36.3 MB
  char* W8 = (char*)d_ws;
  const size_t MB = 1u << 20;
  float* hm  = (float*)(W8 + 0 * MB);
  float* hp  = (float*)(W8 + 4 * MB);
  float* t1  = (float*)(W8 + 8 * MB);   // aliases Qb (GINE temp vs attn Q)
  float* Qb  = (float*)(W8 + 8 * MB);
  float* Kb  = (float*)(W8 + 12 * MB);
  float* Vb  = (float*)(W8 + 16 * MB);
  float* hmc = (float*)(W8 + 20 * MB);
  float* hpc = (float*)(W8 + 24 * MB);
  float* agg = (float*)(W8 + 28 * MB);               // 4 MB
  _Float16* wtH = (_Float16*)(W8 + 32 * MB);         // 14*128 KB = 1.75 MB
  _Float16* wtL = (_Float16*)(W8 + 34 * MB);         // 1.75 MB
  float* zb  = (float*)(W8 + 36 * MB);               // 32*512
  float* cnt = zb + 32 * 512;                        // 64
  float* fch = cnt + 64;                             // 32*256

  // weight indices: 0,1 mol_w1 | 2,3 mol_w2 | 4,5 prot_w1 | 6,7 prot_w2
  // 8 mp_wq 9 mp_wk 10 mp_wv | 11 pm_wq 12 pm_wk 13 pm_wv
  PtrPack pk;
  pk.p[0] = mol_w1;           pk.p[1] = mol_w1 + 65536;
  pk.p[2] = mol_w2;           pk.p[3] = mol_w2 + 65536;
  pk.p[4] = prot_w1;          pk.p[5] = prot_w1 + 65536;
  pk.p[6] = prot_w2;          pk.p[7] = prot_w2 + 65536;
  pk.p[8] = mp_wq;  pk.p[9] = mp_wk;  pk.p[10] = mp_wv;
  pk.p[11] = pm_wq; pk.p[12] = pm_wk; pk.p[13] = pm_wv;
  k_prep_wt<<<dim3(4, 4, 14), 256, 0, stream>>>(pk, wtH, wtL);

  const dim3 ggrid(64, 4), gblk(256);
#define WTH(i) (wtH + (size_t)(i) * 65536)
#define WTL(i) (wtL + (size_t)(i) * 65536)

  k_node_embed<<<NMOL, 256, 0, stream>>>(x_mol, nlm_w, nlm_b, hm, 8);
  k_node_embed<<<NPROT, 256, 0, stream>>>(x_prot, nlp_w, nlp_b, hp, 4);

  for (int l = 0; l < 2; ++l) {
    hipMemsetAsync(agg, 0, 4 * MB, stream);
    k_gine_agg<<<NEDGE / 8, 256, 0, stream>>>(hm, ea_mol, ei_mol, elm_w, elm_b, agg, NEDGE);
    k_gemm_split<true, true><<<ggrid, gblk, 0, stream>>>(hm, agg, WTH(l), WTL(l),
                                                         mol_b1 + l * 256, t1);
    k_gemm_split<true, false><<<ggrid, gblk, 0, stream>>>(t1, nullptr, WTH(2 + l), WTL(2 + l),
                                                          mol_b2 + l * 256, hm);
  }
  for (int l = 0; l < 2; ++l) {
    hipMemsetAsync(agg, 0, 4 * MB, stream);
    k_gine_agg<<<NEDGE / 8, 256, 0, stream>>>(hp, ea_prot, ei_prot, elp_w, elp_b, agg, NEDGE);
    k_gemm_split<true, true><<<ggrid, gblk, 0, stream>>>(hp, agg, WTH(4 + l), WTL(4 + l),
                                                         prot_b1 + l * 256, t1);
    k_gemm_split<true, false><<<ggrid, gblk, 0, stream>>>(t1, nullptr, WTH(6 + l), WTL(6 + l),
                                                          prot_b2 + l * 256, hp);
  }

  // cross attention mol <- prot
  k_gemm_split<false, false><<<ggrid, gblk, 0, stream>>>(hm, nullptr, WTH(8), WTL(8), mp_bq, Qb);
  k_gemm_split<false, false><<<ggrid, gblk, 0, stream>>>(hp, nullptr, WTH(9), WTL(9), mp_bk, Kb);
  k_gemm_split<false, false><<<ggrid, gblk, 0, stream>>>(hp, nullptr, WTH(10), WTL(10), mp_bv, Vb);
  k_attn_split<<<dim3(64, 4), 256, 0, stream>>>(Qb, Kb, Vb, hm, hmc, 4096);

  // cross attention prot <- mol
  k_gemm_split<false, false><<<ggrid, gblk, 0, stream>>>(hp, nullptr, WTH(11), WTL(11), pm_bq, Qb);
  k_gemm_split<false, false><<<ggrid, gblk, 0, stream>>>(hm, nullptr, WTH(12), WTL(12), pm_bk, Kb);
  k_gemm_split<false, false><<<ggrid, gblk, 0, stream>>>(hm, nullptr, WTH(13), WTL(13), pm_bv, Vb);
  k_attn_split<<<dim3(64, 4), 256, 0, stream>>>(Qb, Kb, Vb, hp, hpc, 4096);

  // pooling + head
  hipMemsetAsync(zb, 0, (32 * 512 + 64) * 4, stream);
  k_segsum<<<NMOL, 256, 0, stream>>>(hmc, b_mol, zb, cnt);
  k_segsum<<<NPROT, 256, 0, stream>>>(hpc, b_prot, zb + 256, cnt + 32);
  k_segdiv<<<64, 256, 0, stream>>>(zb, cnt);
  k_fc1<<<32, 256, 0, stream>>>(zb, fc1_w, fc1_b, fch);
  k_fc2<<<1, 64, 0, stream>>>(fch, fc2_w, fc2_b, out);
#undef WTH
#undef WTL
}

// Round 5
// 907.759 us; speedup vs baseline: 2.4647x; 2.4647x over previous
//
#include <hip/hip_runtime.h>
#include <math.h>

#define HDIM 256
#define NMOL 4096
#define NPROT 4096
#define NEDGE 65536
#define NG 32

typedef _Float16 f16x8 __attribute__((ext_vector_type(8)));
typedef __attribute__((ext_vector_type(4))) float f32x4;

__device__ __forceinline__ void splitf(float x, _Float16& h, _Float16& l) {
  h = (_Float16)x;
  l = (_Float16)(x - (float)h);
}

// ---------------------------------------------------------------------------
// Transpose + convert 14 H x H fp32 weights into split f16 planes Wt[n][k].
struct PtrPack { const float* p[14]; };

__global__ __launch_bounds__(256) void k_prep_wt(PtrPack pk, _Float16* __restrict__ dh,
                                                 _Float16* __restrict__ dl) {
  __shared__ float Ts[64][68];
  const int m = blockIdx.z;
  const int n0 = blockIdx.y * 64, k0 = blockIdx.x * 64;
  const float* W = pk.p[m];
  const int t = threadIdx.x;
#pragma unroll
  for (int rep = 0; rep < 16; ++rep) {
    int k = rep * 4 + (t >> 6);
    int n = t & 63;
    Ts[n][k] = W[(size_t)(k0 + k) * 256 + n0 + n];
  }
  __syncthreads();
#pragma unroll
  for (int rep = 0; rep < 2; ++rep) {
    int idx = t + rep * 256;
    int nr = idx >> 3, koff = (idx & 7) * 8;
    f16x8 vh, vl;
#pragma unroll
    for (int i = 0; i < 8; ++i) {
      _Float16 h, l;
      splitf(Ts[nr][koff + i], h, l);
      vh[i] = h; vl[i] = l;
    }
    size_t off = (size_t)m * 65536 + (size_t)(n0 + nr) * 256 + k0 + koff;
    *(f16x8*)&dh[off] = vh;
    *(f16x8*)&dl[off] = vl;
  }
}

// ---------------------------------------------------------------------------
// node embedding (fp32 out)
__global__ __launch_bounds__(256) void k_node_embed(
    const float* __restrict__ x, const float* __restrict__ w,
    const float* __restrict__ b, float* __restrict__ out, int K) {
  const int i = blockIdx.x;
  const int c = threadIdx.x;
  float acc = b[c];
  for (int k = 0; k < K; ++k) acc += x[i * K + k] * w[k * HDIM + c];
  out[(size_t)i * HDIM + c] = acc;
}

// ---------------------------------------------------------------------------
// CSR build: count (into cur), exclusive scan (off + cur=prefix), scatter eids
__global__ __launch_bounds__(256) void k_csr_count(const int* __restrict__ ei,
                                                   int* __restrict__ cur, int E) {
  const int e = blockIdx.x * 256 + threadIdx.x;
  if (e < E) atomicAdd(&cur[ei[E + e]], 1);
}

__global__ __launch_bounds__(256) void k_csr_scan(int* __restrict__ cnt_cur,
                                                  int* __restrict__ off, int N) {
  // N = 4096, 256 threads x 16 elems
  __shared__ int tsum[256], tpre[257];
  const int t = threadIdx.x;
  const int base = t * 16;
  int loc[16], s = 0;
#pragma unroll
  for (int i = 0; i < 16; ++i) { loc[i] = cnt_cur[base + i]; s += loc[i]; }
  tsum[t] = s;
  __syncthreads();
  if (t == 0) {
    int a = 0;
    for (int i = 0; i < 256; ++i) { tpre[i] = a; a += tsum[i]; }
    tpre[256] = a;
  }
  __syncthreads();
  int a = tpre[t];
#pragma unroll
  for (int i = 0; i < 16; ++i) {
    off[base + i] = a;
    cnt_cur[base + i] = a;
    a += loc[i];
  }
  if (t == 255) off[N] = tpre[256];
}

__global__ __launch_bounds__(256) void k_csr_scatter(const int* __restrict__ ei,
                                                     int* __restrict__ cur,
                                                     int* __restrict__ eid, int E) {
  const int e = blockIdx.x * 256 + threadIdx.x;
  if (e < E) {
    int pos = atomicAdd(&cur[ei[E + e]], 1);
    eid[pos] = e;
  }
}

// ---------------------------------------------------------------------------
// GINE aggregation via CSR gather: one block per dst node, 256 thr = channels.
// agg[n,c] = sum_{e: dst(e)=n} relu(x[src(e),c] + a0*we0[c] + a1*we1[c] + be[c])
__global__ __launch_bounds__(256) void k_gine_agg_csr(
    const float* __restrict__ x, const float* __restrict__ ea,
    const int* __restrict__ ei_src, const int* __restrict__ off,
    const int* __restrict__ eid, const float* __restrict__ we,
    const float* __restrict__ be, float* __restrict__ agg) {
  const int n = blockIdx.x;
  const int c = threadIdx.x;
  const float w0 = we[c], w1 = we[HDIM + c], bb = be[c];
  const int j0 = off[n], j1 = off[n + 1];
  float sum = 0.f;
  for (int j = j0; j < j1; ++j) {
    int e = eid[j];
    int src = ei_src[e];
    float a0 = ea[2 * e], a1 = ea[2 * e + 1];
    float m = x[(size_t)src * HDIM + c] + a0 * w0 + a1 * w1 + bb;
    sum += fmaxf(m, 0.f);
  }
  agg[(size_t)n * HDIM + c] = sum;
}

// ---------------------------------------------------------------------------
// Split-f16 MFMA GEMM: C = act((A1 [+A2]) @ W + b), K=256, fp32 in/out.
// Each logical MFMA -> 3 f16 MFMAs (hi*hi + hi*lo + lo*hi), fp32 accum.
template <bool RELU, bool HASA2>
__global__ __launch_bounds__(256) void k_gemm_split(
    const float* __restrict__ A1, const float* __restrict__ A2,
    const _Float16* __restrict__ WtH, const _Float16* __restrict__ WtL,
    const float* __restrict__ bias, float* __restrict__ C) {
  __shared__ _Float16 Ah[64][72], Al[64][72], Bh[64][72], Bl[64][72];
  const int t = threadIdx.x;
  const int bm = blockIdx.x * 64, bn = blockIdx.y * 64;
  const int lane = t & 63, w = t >> 6;
  const int l15 = lane & 15, l4 = lane >> 4;
  const int wm = (w >> 1) * 32, wn = (w & 1) * 32;
  f32x4 acc[2][2] = {};
  for (int k0 = 0; k0 < 256; k0 += 64) {
    __syncthreads();
#pragma unroll
    for (int rep = 0; rep < 4; ++rep) {
      int idx = t + rep * 256;
      int r = idx >> 4, c4 = (idx & 15) * 4;
      float4 a = *(const float4*)&A1[(size_t)(bm + r) * 256 + k0 + c4];
      if (HASA2) {
        float4 a2 = *(const float4*)&A2[(size_t)(bm + r) * 256 + k0 + c4];
        a.x += a2.x; a.y += a2.y; a.z += a2.z; a.w += a2.w;
      }
      float av[4] = {a.x, a.y, a.z, a.w};
#pragma unroll
      for (int i = 0; i < 4; ++i) splitf(av[i], Ah[r][c4 + i], Al[r][c4 + i]);
    }
#pragma unroll
    for (int rep = 0; rep < 2; ++rep) {
      int idx = t + rep * 256;
      int nr = idx >> 3, koff = (idx & 7) * 8;
      size_t off = (size_t)(bn + nr) * 256 + k0 + koff;
      *(f16x8*)&Bh[nr][koff] = *(const f16x8*)&WtH[off];
      *(f16x8*)&Bl[nr][koff] = *(const f16x8*)&WtL[off];
    }
    __syncthreads();
#pragma unroll
    for (int kh = 0; kh < 2; ++kh) {
      f16x8 a0h = *(f16x8*)&Ah[wm + l15][kh * 32 + l4 * 8];
      f16x8 a0l = *(f16x8*)&Al[wm + l15][kh * 32 + l4 * 8];
      f16x8 a1h = *(f16x8*)&Ah[wm + 16 + l15][kh * 32 + l4 * 8];
      f16x8 a1l = *(f16x8*)&Al[wm + 16 + l15][kh * 32 + l4 * 8];
      f16x8 b0h = *(f16x8*)&Bh[wn + l15][kh * 32 + l4 * 8];
      f16x8 b0l = *(f16x8*)&Bl[wn + l15][kh * 32 + l4 * 8];
      f16x8 b1h = *(f16x8*)&Bh[wn + 16 + l15][kh * 32 + l4 * 8];
      f16x8 b1l = *(f16x8*)&Bl[wn + 16 + l15][kh * 32 + l4 * 8];
      acc[0][0] = __builtin_amdgcn_mfma_f32_16x16x32_f16(a0h, b0h, acc[0][0], 0, 0, 0);
      acc[0][0] = __builtin_amdgcn_mfma_f32_16x16x32_f16(a0h, b0l, acc[0][0], 0, 0, 0);
      acc[0][0] = __builtin_amdgcn_mfma_f32_16x16x32_f16(a0l, b0h, acc[0][0], 0, 0, 0);
      acc[0][1] = __builtin_amdgcn_mfma_f32_16x16x32_f16(a0h, b1h, acc[0][1], 0, 0, 0);
      acc[0][1] = __builtin_amdgcn_mfma_f32_16x16x32_f16(a0h, b1l, acc[0][1], 0, 0, 0);
      acc[0][1] = __builtin_amdgcn_mfma_f32_16x16x32_f16(a0l, b1h, acc[0][1], 0, 0, 0);
      acc[1][0] = __builtin_amdgcn_mfma_f32_16x16x32_f16(a1h, b0h, acc[1][0], 0, 0, 0);
      acc[1][0] = __builtin_amdgcn_mfma_f32_16x16x32_f16(a1h, b0l, acc[1][0], 0, 0, 0);
      acc[1][0] = __builtin_amdgcn_mfma_f32_16x16x32_f16(a1l, b0h, acc[1][0], 0, 0, 0);
      acc[1][1] = __builtin_amdgcn_mfma_f32_16x16x32_f16(a1h, b1h, acc[1][1], 0, 0, 0);
      acc[1][1] = __builtin_amdgcn_mfma_f32_16x16x32_f16(a1h, b1l, acc[1][1], 0, 0, 0);
      acc[1][1] = __builtin_amdgcn_mfma_f32_16x16x32_f16(a1l, b1h, acc[1][1], 0, 0, 0);
    }
  }
#pragma unroll
  for (int mi = 0; mi < 2; ++mi)
#pragma unroll
    for (int ni = 0; ni < 2; ++ni) {
      int col = bn + wn + ni * 16 + l15;
      float bv = bias[col];
#pragma unroll
      for (int r = 0; r < 4; ++r) {
        int row = bm + wm + mi * 16 + l4 * 4 + r;
        float v = acc[mi][ni][r] + bv;
        if (RELU) v = fmaxf(v, 0.f);
        C[(size_t)row * 256 + col] = v;
      }
    }
}

// ---------------------------------------------------------------------------
// Split-f16 MFMA flash attention. Block = (64-q tile, head); 4 waves.
// Out = Hin + softmax(Q K^T / 8) V, fp32 in/out, fp32 softmax state.
__global__ __launch_bounds__(256) void k_attn_split(
    const float* __restrict__ Q, const float* __restrict__ Kg,
    const float* __restrict__ Vg, const float* __restrict__ Hin,
    float* __restrict__ Out, int nk) {
  __shared__ _Float16 Kh[64][72], Kl[64][72];     // [k][d]
  __shared__ _Float16 Vth[64][72], Vtl[64][72];   // [d][k], chunk-swizzled
  __shared__ _Float16 Psh[4][16][72], Psl[4][16][72];  // per-wave P [q][k]
  const int t = threadIdx.x;
  const int h = blockIdx.y;
  const int q0 = blockIdx.x * 64;
  const int lane = t & 63, w = t >> 6;
  const int l15 = lane & 15, l4 = lane >> 4;

  f16x8 qh[2], ql[2];
  {
    const float* qrow = Q + (size_t)(q0 + w * 16 + l15) * 256 + h * 64;
#pragma unroll
    for (int kh = 0; kh < 2; ++kh) {
      float4 v0 = *(const float4*)(qrow + kh * 32 + l4 * 8);
      float4 v1 = *(const float4*)(qrow + kh * 32 + l4 * 8 + 4);
      float qv[8] = {v0.x, v0.y, v0.z, v0.w, v1.x, v1.y, v1.z, v1.w};
#pragma unroll
      for (int i = 0; i < 8; ++i) {
        _Float16 hh, ll;
        splitf(qv[i] * 0.125f, hh, ll);
        qh[kh][i] = hh; ql[kh][i] = ll;
      }
    }
  }
  f32x4 o[4] = {};
  float mrun[4] = {-1e30f, -1e30f, -1e30f, -1e30f};
  float lrun[4] = {0.f, 0.f, 0.f, 0.f};

  for (int k0 = 0; k0 < nk; k0 += 64) {
    __syncthreads();
#pragma unroll
    for (int rep = 0; rep < 4; ++rep) {
      int idx = t + rep * 256;
      int kr = idx >> 4, d4 = (idx & 15) * 4;
      float4 kv = *(const float4*)(Kg + (size_t)(k0 + kr) * 256 + h * 64 + d4);
      float4 vv = *(const float4*)(Vg + (size_t)(k0 + kr) * 256 + h * 64 + d4);
      float kvs[4] = {kv.x, kv.y, kv.z, kv.w};
      float vvs[4] = {vv.x, vv.y, vv.z, vv.w};
#pragma unroll
      for (int i = 0; i < 4; ++i) {
        splitf(kvs[i], Kh[kr][d4 + i], Kl[kr][d4 + i]);
        int d = d4 + i;
        int col = (((kr >> 3) ^ ((d >> 3) & 7)) << 3) + (kr & 7);
        splitf(vvs[i], Vth[d][col], Vtl[d][col]);
      }
    }
    __syncthreads();

    // S = Q K^T (per wave: 16 q x 64 k)
    f32x4 sf[4] = {};
#pragma unroll
    for (int kc = 0; kc < 4; ++kc) {
      f16x8 kf0h = *(f16x8*)&Kh[kc * 16 + l15][l4 * 8];
      f16x8 kf0l = *(f16x8*)&Kl[kc * 16 + l15][l4 * 8];
      f16x8 kf1h = *(f16x8*)&Kh[kc * 16 + l15][32 + l4 * 8];
      f16x8 kf1l = *(f16x8*)&Kl[kc * 16 + l15][32 + l4 * 8];
      sf[kc] = __builtin_amdgcn_mfma_f32_16x16x32_f16(qh[0], kf0h, sf[kc], 0, 0, 0);
      sf[kc] = __builtin_amdgcn_mfma_f32_16x16x32_f16(qh[0], kf0l, sf[kc], 0, 0, 0);
      sf[kc] = __builtin_amdgcn_mfma_f32_16x16x32_f16(ql[0], kf0h, sf[kc], 0, 0, 0);
      sf[kc] = __builtin_amdgcn_mfma_f32_16x16x32_f16(qh[1], kf1h, sf[kc], 0, 0, 0);
      sf[kc] = __builtin_amdgcn_mfma_f32_16x16x32_f16(qh[1], kf1l, sf[kc], 0, 0, 0);
      sf[kc] = __builtin_amdgcn_mfma_f32_16x16x32_f16(ql[1], kf1h, sf[kc], 0, 0, 0);
    }

    // online softmax per q-row (rows on 16-lane groups)
#pragma unroll
    for (int r = 0; r < 4; ++r) {
      float s0 = sf[0][r], s1 = sf[1][r], s2 = sf[2][r], s3 = sf[3][r];
      float mt = fmaxf(fmaxf(s0, s1), fmaxf(s2, s3));
      mt = fmaxf(mt, __shfl_xor(mt, 1, 64));
      mt = fmaxf(mt, __shfl_xor(mt, 2, 64));
      mt = fmaxf(mt, __shfl_xor(mt, 4, 64));
      mt = fmaxf(mt, __shfl_xor(mt, 8, 64));
      float mn = fmaxf(mrun[r], mt);
      float alpha = __expf(mrun[r] - mn);
      mrun[r] = mn;
      float p0 = __expf(s0 - mn), p1 = __expf(s1 - mn);
      float p2 = __expf(s2 - mn), p3 = __expf(s3 - mn);
      float rs = p0 + p1 + p2 + p3;
      rs += __shfl_xor(rs, 1, 64);
      rs += __shfl_xor(rs, 2, 64);
      rs += __shfl_xor(rs, 4, 64);
      rs += __shfl_xor(rs, 8, 64);
      lrun[r] = lrun[r] * alpha + rs;
      o[0][r] *= alpha; o[1][r] *= alpha; o[2][r] *= alpha; o[3][r] *= alpha;
      int prow = l4 * 4 + r;
      float ps[4] = {p0, p1, p2, p3};
#pragma unroll
      for (int kc = 0; kc < 4; ++kc)
        splitf(ps[kc], Psh[w][prow][kc * 16 + l15], Psl[w][prow][kc * 16 + l15]);
    }

    // O += P @ V (per-wave P tile; same-wave write->read)
#pragma unroll
    for (int kh = 0; kh < 2; ++kh) {
      f16x8 pah = *(f16x8*)&Psh[w][l15][kh * 32 + l4 * 8];
      f16x8 pal = *(f16x8*)&Psl[w][l15][kh * 32 + l4 * 8];
#pragma unroll
      for (int oc = 0; oc < 4; ++oc) {
        int d = oc * 16 + l15;
        int chunk = (kh * 4 + l4) ^ ((d >> 3) & 7);
        f16x8 vbh = *(f16x8*)&Vth[d][chunk * 8];
        f16x8 vbl = *(f16x8*)&Vtl[d][chunk * 8];
        o[oc] = __builtin_amdgcn_mfma_f32_16x16x32_f16(pah, vbh, o[oc], 0, 0, 0);
        o[oc] = __builtin_amdgcn_mfma_f32_16x16x32_f16(pah, vbl, o[oc], 0, 0, 0);
        o[oc] = __builtin_amdgcn_mfma_f32_16x16x32_f16(pal, vbh, o[oc], 0, 0, 0);
      }
    }
  }

#pragma unroll
  for (int oc = 0; oc < 4; ++oc) {
    int col = h * 64 + oc * 16 + l15;
#pragma unroll
    for (int r = 0; r < 4; ++r) {
      int row = q0 + w * 16 + l4 * 4 + r;
      Out[(size_t)row * 256 + col] = o[oc][r] / lrun[r] + Hin[(size_t)row * 256 + col];
    }
  }
}

// ---------------------------------------------------------------------------
__global__ __launch_bounds__(256) void k_segsum(
    const float* __restrict__ Hc, const int* __restrict__ batch,
    float* __restrict__ z, float* __restrict__ cnt) {
  const int i = blockIdx.x;
  const int c = threadIdx.x;
  const int g = batch[i];
  atomicAdd(&z[(size_t)g * 512 + c], Hc[(size_t)i * HDIM + c]);
  if (c == 0) atomicAdd(&cnt[g], 1.0f);
}

__global__ __launch_bounds__(256) void k_segdiv(float* __restrict__ z,
                                                const float* __restrict__ cnt) {
  const int idx = blockIdx.x * 256 + threadIdx.x;  // 32*512
  const int g = idx >> 9, c = idx & 511;
  const float cc = cnt[(c < 256) ? g : (32 + g)];
  z[idx] /= fmaxf(cc, 1.0f);
}

__global__ __launch_bounds__(256) void k_fc1(
    const float* __restrict__ z, const float* __restrict__ w,
    const float* __restrict__ b, float* __restrict__ out) {
  const int idx = blockIdx.x * 256 + threadIdx.x;  // 32*256
  const int r = idx >> 8, c = idx & 255;
  float acc = b[c];
  for (int k = 0; k < 512; ++k) acc += z[r * 512 + k] * w[k * HDIM + c];
  out[idx] = fmaxf(acc, 0.f);
}

__global__ __launch_bounds__(64) void k_fc2(
    const float* __restrict__ xin, const float* __restrict__ w,
    const float* __restrict__ b, float* __restrict__ out) {
  const int r = threadIdx.x;
  if (r < NG) {
    float acc = b[0];
    for (int k = 0; k < HDIM; ++k) acc += xin[r * HDIM + k] * w[k];
    out[r] = 1.0f / (1.0f + __expf(-acc));
  }
}

// ---------------------------------------------------------------------------
extern "C" void kernel_launch(void* const* d_in, const int* in_sizes, int n_in,
                              void* d_out, int out_size, void* d_ws, size_t ws_size,
                              hipStream_t stream) {
  const float* x_mol   = (const float*)d_in[0];
  const float* x_prot  = (const float*)d_in[1];
  const float* ea_mol  = (const float*)d_in[2];
  const float* ea_prot = (const float*)d_in[3];
  const int*   ei_mol  = (const int*)d_in[4];
  const int*   ei_prot = (const int*)d_in[5];
  const int*   b_mol   = (const int*)d_in[6];
  const int*   b_prot  = (const int*)d_in[7];
  const float* nlm_w = (const float*)d_in[8];
  const float* nlm_b = (const float*)d_in[9];
  const float* nlp_w = (const float*)d_in[10];
  const float* nlp_b = (const float*)d_in[11];
  const float* elm_w = (const float*)d_in[12];
  const float* elm_b = (const float*)d_in[13];
  const float* elp_w = (const float*)d_in[14];
  const float* elp_b = (const float*)d_in[15];
  const float* mol_w1 = (const float*)d_in[16];
  const float* mol_b1 = (const float*)d_in[17];
  const float* mol_w2 = (const float*)d_in[18];
  const float* mol_b2 = (const float*)d_in[19];
  const float* prot_w1 = (const float*)d_in[20];
  const float* prot_b1 = (const float*)d_in[21];
  const float* prot_w2 = (const float*)d_in[22];
  const float* prot_b2 = (const float*)d_in[23];
  const float* mp_wq = (const float*)d_in[24];
  const float* mp_bq = (const float*)d_in[25];
  const float* mp_wk = (const float*)d_in[26];
  const float* mp_bk = (const float*)d_in[27];
  const float* mp_wv = (const float*)d_in[28];
  const float* mp_bv = (const float*)d_in[29];
  const float* pm_wq = (const float*)d_in[30];
  const float* pm_bq = (const float*)d_in[31];
  const float* pm_wk = (const float*)d_in[32];
  const float* pm_bk = (const float*)d_in[33];
  const float* pm_wv = (const float*)d_in[34];
  const float* pm_bv = (const float*)d_in[35];
  const float* fc1_w = (const float*)d_in[36];
  const float* fc1_b = (const float*)d_in[37];
  const float* fc2_w = (const float*)d_in[38];
  const float* fc2_b = (const float*)d_in[39];
  float* out = (float*)d_out;

  // workspace carve (bytes); peak ~39 MB
  char* W8 = (char*)d_ws;
  const size_t MB = 1u << 20;
  float* hm  = (float*)(W8 + 0 * MB);
  float* hp  = (float*)(W8 + 4 * MB);
  float* t1  = (float*)(W8 + 8 * MB);   // aliases Qb (GINE temp vs attn Q)
  float* Qb  = (float*)(W8 + 8 * MB);
  float* Kb  = (float*)(W8 + 12 * MB);
  float* Vb  = (float*)(W8 + 16 * MB);
  float* hmc = (float*)(W8 + 20 * MB);
  float* hpc = (float*)(W8 + 24 * MB);
  float* agg = (float*)(W8 + 28 * MB);               // 4 MB
  _Float16* wtH = (_Float16*)(W8 + 32 * MB);         // 14*128 KB = 1.75 MB
  _Float16* wtL = (_Float16*)(W8 + 34 * MB);         // 1.75 MB
  float* zb  = (float*)(W8 + 36 * MB);               // 32*512
  float* cnt = zb + 32 * 512;                        // 64
  float* fch = cnt + 64;                             // 32*256
  int* off_m = (int*)(W8 + 37 * MB);                 // 4097
  int* cur_m = off_m + 4224;                         // 4096
  int* eid_m = cur_m + 4224;                         // 65536
  int* off_p = (int*)(W8 + 38 * MB);
  int* cur_p = off_p + 4224;
  int* eid_p = cur_p + 4224;

  // weight indices: 0,1 mol_w1 | 2,3 mol_w2 | 4,5 prot_w1 | 6,7 prot_w2
  // 8 mp_wq 9 mp_wk 10 mp_wv | 11 pm_wq 12 pm_wk 13 pm_wv
  PtrPack pk;
  pk.p[0] = mol_w1;           pk.p[1] = mol_w1 + 65536;
  pk.p[2] = mol_w2;           pk.p[3] = mol_w2 + 65536;
  pk.p[4] = prot_w1;          pk.p[5] = prot_w1 + 65536;
  pk.p[6] = prot_w2;          pk.p[7] = prot_w2 + 65536;
  pk.p[8] = mp_wq;  pk.p[9] = mp_wk;  pk.p[10] = mp_wv;
  pk.p[11] = pm_wq; pk.p[12] = pm_wk; pk.p[13] = pm_wv;
  k_prep_wt<<<dim3(4, 4, 14), 256, 0, stream>>>(pk, wtH, wtL);

  // CSR build (edge structure is fixed; build once per graph, reuse per layer)
  hipMemsetAsync(cur_m, 0, 4096 * 4, stream);
  hipMemsetAsync(cur_p, 0, 4096 * 4, stream);
  k_csr_count<<<NEDGE / 256, 256, 0, stream>>>(ei_mol, cur_m, NEDGE);
  k_csr_count<<<NEDGE / 256, 256, 0, stream>>>(ei_prot, cur_p, NEDGE);
  k_csr_scan<<<1, 256, 0, stream>>>(cur_m, off_m, NMOL);
  k_csr_scan<<<1, 256, 0, stream>>>(cur_p, off_p, NPROT);
  k_csr_scatter<<<NEDGE / 256, 256, 0, stream>>>(ei_mol, cur_m, eid_m, NEDGE);
  k_csr_scatter<<<NEDGE / 256, 256, 0, stream>>>(ei_prot, cur_p, eid_p, NEDGE);

  const dim3 ggrid(64, 4), gblk(256);
#define WTH(i) (wtH + (size_t)(i) * 65536)
#define WTL(i) (wtL + (size_t)(i) * 65536)

  k_node_embed<<<NMOL, 256, 0, stream>>>(x_mol, nlm_w, nlm_b, hm, 8);
  k_node_embed<<<NPROT, 256, 0, stream>>>(x_prot, nlp_w, nlp_b, hp, 4);

  for (int l = 0; l < 2; ++l) {
    k_gine_agg_csr<<<NMOL, 256, 0, stream>>>(hm, ea_mol, ei_mol, off_m, eid_m,
                                             elm_w, elm_b, agg);
    k_gemm_split<true, true><<<ggrid, gblk, 0, stream>>>(hm, agg, WTH(l), WTL(l),
                                                         mol_b1 + l * 256, t1);
    k_gemm_split<true, false><<<ggrid, gblk, 0, stream>>>(t1, nullptr, WTH(2 + l), WTL(2 + l),
                                                          mol_b2 + l * 256, hm);
  }
  for (int l = 0; l < 2; ++l) {
    k_gine_agg_csr<<<NPROT, 256, 0, stream>>>(hp, ea_prot, ei_prot, off_p, eid_p,
                                              elp_w, elp_b, agg);
    k_gemm_split<true, true><<<ggrid, gblk, 0, stream>>>(hp, agg, WTH(4 + l), WTL(4 + l),
                                                         prot_b1 + l * 256, t1);
    k_gemm_split<true, false><<<ggrid, gblk, 0, stream>>>(t1, nullptr, WTH(6 + l), WTL(6 + l),
                                                          prot_b2 + l * 256, hp);
  }

  // cross attention mol <- prot
  k_gemm_split<false, false><<<ggrid, gblk, 0, stream>>>(hm, nullptr, WTH(8), WTL(8), mp_bq, Qb);
  k_gemm_split<false, false><<<ggrid, gblk, 0, stream>>>(hp, nullptr, WTH(9), WTL(9), mp_bk, Kb);
  k_gemm_split<false, false><<<ggrid, gblk, 0, stream>>>(hp, nullptr, WTH(10), WTL(10), mp_bv, Vb);
  k_attn_split<<<dim3(64, 4), 256, 0, stream>>>(Qb, Kb, Vb, hm, hmc, 4096);

  // cross attention prot <- mol
  k_gemm_split<false, false><<<ggrid, gblk, 0, stream>>>(hp, nullptr, WTH(11), WTL(11), pm_bq, Qb);
  k_gemm_split<false, false><<<ggrid, gblk, 0, stream>>>(hm, nullptr, WTH(12), WTL(12), pm_bk, Kb);
  k_gemm_split<false, false><<<ggrid, gblk, 0, stream>>>(hm, nullptr, WTH(13), WTL(13), pm_bv, Vb);
  k_attn_split<<<dim3(64, 4), 256, 0, stream>>>(Qb, Kb, Vb, hp, hpc, 4096);

  // pooling + head
  hipMemsetAsync(zb, 0, (32 * 512 + 64) * 4, stream);
  k_segsum<<<NMOL, 256, 0, stream>>>(hmc, b_mol, zb, cnt);
  k_segsum<<<NPROT, 256, 0, stream>>>(hpc, b_prot, zb + 256, cnt + 32);
  k_segdiv<<<64, 256, 0, stream>>>(zb, cnt);
  k_fc1<<<32, 256, 0, stream>>>(zb, fc1_w, fc1_b, fch);
  k_fc2<<<1, 64, 0, stream>>>(fch, fc2_w, fc2_b, out);
#undef WTH
#undef WTL
}

// Round 6
// 766.650 us; speedup vs baseline: 2.9183x; 1.1841x over previous
//
#include <hip/hip_runtime.h>
#include <math.h>

#define HDIM 256
#define NMOL 4096
#define NPROT 4096
#define NEDGE 65536
#define NG 32

typedef _Float16 f16x8 __attribute__((ext_vector_type(8)));
typedef __attribute__((ext_vector_type(4))) float f32x4;

__device__ __forceinline__ void splitf(float x, _Float16& h, _Float16& l) {
  h = (_Float16)x;
  l = (_Float16)(x - (float)h);
}

// ---------------------------------------------------------------------------
// Transpose + convert 14 H x H fp32 weights into split f16 planes Wt[n][k].
struct PtrPack { const float* p[14]; };

__global__ __launch_bounds__(256) void k_prep_wt(PtrPack pk, _Float16* __restrict__ dh,
                                                 _Float16* __restrict__ dl) {
  __shared__ float Ts[64][68];
  const int m = blockIdx.z;
  const int n0 = blockIdx.y * 64, k0 = blockIdx.x * 64;
  const float* W = pk.p[m];
  const int t = threadIdx.x;
#pragma unroll
  for (int rep = 0; rep < 16; ++rep) {
    int k = rep * 4 + (t >> 6);
    int n = t & 63;
    Ts[n][k] = W[(size_t)(k0 + k) * 256 + n0 + n];
  }
  __syncthreads();
#pragma unroll
  for (int rep = 0; rep < 2; ++rep) {
    int idx = t + rep * 256;
    int nr = idx >> 3, koff = (idx & 7) * 8;
    f16x8 vh, vl;
#pragma unroll
    for (int i = 0; i < 8; ++i) {
      _Float16 h, l;
      splitf(Ts[nr][koff + i], h, l);
      vh[i] = h; vl[i] = l;
    }
    size_t off = (size_t)m * 65536 + (size_t)(n0 + nr) * 256 + k0 + koff;
    *(f16x8*)&dh[off] = vh;
    *(f16x8*)&dl[off] = vl;
  }
}

// ---------------------------------------------------------------------------
// node embedding (fp32 out)
__global__ __launch_bounds__(256) void k_node_embed(
    const float* __restrict__ x, const float* __restrict__ w,
    const float* __restrict__ b, float* __restrict__ out, int K) {
  const int i = blockIdx.x;
  const int c = threadIdx.x;
  float acc = b[c];
  for (int k = 0; k < K; ++k) acc += x[i * K + k] * w[k * HDIM + c];
  out[(size_t)i * HDIM + c] = acc;
}

// ---------------------------------------------------------------------------
// CSR build
__global__ __launch_bounds__(256) void k_csr_count(const int* __restrict__ ei,
                                                   int* __restrict__ cur, int E) {
  const int e = blockIdx.x * 256 + threadIdx.x;
  if (e < E) atomicAdd(&cur[ei[E + e]], 1);
}

__global__ __launch_bounds__(256) void k_csr_scan(int* __restrict__ cnt_cur,
                                                  int* __restrict__ off, int N) {
  __shared__ int tsum[256], tpre[257];
  const int t = threadIdx.x;
  const int base = t * 16;
  int loc[16], s = 0;
#pragma unroll
  for (int i = 0; i < 16; ++i) { loc[i] = cnt_cur[base + i]; s += loc[i]; }
  tsum[t] = s;
  __syncthreads();
  if (t == 0) {
    int a = 0;
    for (int i = 0; i < 256; ++i) { tpre[i] = a; a += tsum[i]; }
    tpre[256] = a;
  }
  __syncthreads();
  int a = tpre[t];
#pragma unroll
  for (int i = 0; i < 16; ++i) {
    off[base + i] = a;
    cnt_cur[base + i] = a;
    a += loc[i];
  }
  if (t == 255) off[N] = tpre[256];
}

__global__ __launch_bounds__(256) void k_csr_scatter(const int* __restrict__ ei,
                                                     int* __restrict__ cur,
                                                     int* __restrict__ eid, int E) {
  const int e = blockIdx.x * 256 + threadIdx.x;
  if (e < E) {
    int pos = atomicAdd(&cur[ei[E + e]], 1);
    eid[pos] = e;
  }
}

// ---------------------------------------------------------------------------
// GINE aggregation via CSR gather
__global__ __launch_bounds__(256) void k_gine_agg_csr(
    const float* __restrict__ x, const float* __restrict__ ea,
    const int* __restrict__ ei_src, const int* __restrict__ off,
    const int* __restrict__ eid, const float* __restrict__ we,
    const float* __restrict__ be, float* __restrict__ agg) {
  const int n = blockIdx.x;
  const int c = threadIdx.x;
  const float w0 = we[c], w1 = we[HDIM + c], bb = be[c];
  const int j0 = off[n], j1 = off[n + 1];
  float sum = 0.f;
  for (int j = j0; j < j1; ++j) {
    int e = eid[j];
    int src = ei_src[e];
    float a0 = ea[2 * e], a1 = ea[2 * e + 1];
    float m = x[(size_t)src * HDIM + c] + a0 * w0 + a1 * w1 + bb;
    sum += fmaxf(m, 0.f);
  }
  agg[(size_t)n * HDIM + c] = sum;
}

// ---------------------------------------------------------------------------
// Split fp32 activations [N][256] into f16 hi/lo planes (8 elems/thread)
__global__ __launch_bounds__(256) void k_split_act(const float* __restrict__ x,
                                                   _Float16* __restrict__ xh,
                                                   _Float16* __restrict__ xl) {
  const size_t idx = (size_t)(blockIdx.x * 256 + threadIdx.x) * 8;
  float4 a = *(const float4*)&x[idx];
  float4 b = *(const float4*)&x[idx + 4];
  float v[8] = {a.x, a.y, a.z, a.w, b.x, b.y, b.z, b.w};
  f16x8 vh, vl;
#pragma unroll
  for (int i = 0; i < 8; ++i) {
    _Float16 h, l;
    splitf(v[i], h, l);
    vh[i] = h; vl[i] = l;
  }
  *(f16x8*)&xh[idx] = vh;
  *(f16x8*)&xl[idx] = vl;
}

// ---------------------------------------------------------------------------
// Split-f16 MFMA GEMM, K=256. A: fp32 (+optional A2, split in-kernel) or
// pre-split planes. OUTMODE 0: fp32 C. OUTMODE 1: split f16 planes, scaled.
template <bool RELU, bool HASA2, bool PRESPLIT, int OUTMODE>
__global__ __launch_bounds__(256) void k_gemm_split(
    const float* __restrict__ A1, const float* __restrict__ A2,
    const _Float16* __restrict__ Ahg, const _Float16* __restrict__ Alg,
    const _Float16* __restrict__ WtH, const _Float16* __restrict__ WtL,
    const float* __restrict__ bias, float* __restrict__ C,
    _Float16* __restrict__ Ch, _Float16* __restrict__ Cl, float oscale) {
  __shared__ _Float16 Ah[64][72], Al[64][72], Bh[64][72], Bl[64][72];
  const int t = threadIdx.x;
  const int bm = blockIdx.x * 64, bn = blockIdx.y * 64;
  const int lane = t & 63, w = t >> 6;
  const int l15 = lane & 15, l4 = lane >> 4;
  const int wm = (w >> 1) * 32, wn = (w & 1) * 32;
  f32x4 acc[2][2] = {};
  for (int k0 = 0; k0 < 256; k0 += 64) {
    __syncthreads();
    if (PRESPLIT) {
#pragma unroll
      for (int rep = 0; rep < 2; ++rep) {
        int idx = t + rep * 256;
        int r = idx >> 3, k8 = (idx & 7) * 8;
        size_t off = (size_t)(bm + r) * 256 + k0 + k8;
        *(f16x8*)&Ah[r][k8] = *(const f16x8*)&Ahg[off];
        *(f16x8*)&Al[r][k8] = *(const f16x8*)&Alg[off];
      }
    } else {
#pragma unroll
      for (int rep = 0; rep < 4; ++rep) {
        int idx = t + rep * 256;
        int r = idx >> 4, c4 = (idx & 15) * 4;
        float4 a = *(const float4*)&A1[(size_t)(bm + r) * 256 + k0 + c4];
        if (HASA2) {
          float4 a2 = *(const float4*)&A2[(size_t)(bm + r) * 256 + k0 + c4];
          a.x += a2.x; a.y += a2.y; a.z += a2.z; a.w += a2.w;
        }
        float av[4] = {a.x, a.y, a.z, a.w};
#pragma unroll
        for (int i = 0; i < 4; ++i) splitf(av[i], Ah[r][c4 + i], Al[r][c4 + i]);
      }
    }
#pragma unroll
    for (int rep = 0; rep < 2; ++rep) {
      int idx = t + rep * 256;
      int nr = idx >> 3, koff = (idx & 7) * 8;
      size_t off = (size_t)(bn + nr) * 256 + k0 + koff;
      *(f16x8*)&Bh[nr][koff] = *(const f16x8*)&WtH[off];
      *(f16x8*)&Bl[nr][koff] = *(const f16x8*)&WtL[off];
    }
    __syncthreads();
#pragma unroll
    for (int kh = 0; kh < 2; ++kh) {
      f16x8 a0h = *(f16x8*)&Ah[wm + l15][kh * 32 + l4 * 8];
      f16x8 a0l = *(f16x8*)&Al[wm + l15][kh * 32 + l4 * 8];
      f16x8 a1h = *(f16x8*)&Ah[wm + 16 + l15][kh * 32 + l4 * 8];
      f16x8 a1l = *(f16x8*)&Al[wm + 16 + l15][kh * 32 + l4 * 8];
      f16x8 b0h = *(f16x8*)&Bh[wn + l15][kh * 32 + l4 * 8];
      f16x8 b0l = *(f16x8*)&Bl[wn + l15][kh * 32 + l4 * 8];
      f16x8 b1h = *(f16x8*)&Bh[wn + 16 + l15][kh * 32 + l4 * 8];
      f16x8 b1l = *(f16x8*)&Bl[wn + 16 + l15][kh * 32 + l4 * 8];
      acc[0][0] = __builtin_amdgcn_mfma_f32_16x16x32_f16(a0h, b0h, acc[0][0], 0, 0, 0);
      acc[0][0] = __builtin_amdgcn_mfma_f32_16x16x32_f16(a0h, b0l, acc[0][0], 0, 0, 0);
      acc[0][0] = __builtin_amdgcn_mfma_f32_16x16x32_f16(a0l, b0h, acc[0][0], 0, 0, 0);
      acc[0][1] = __builtin_amdgcn_mfma_f32_16x16x32_f16(a0h, b1h, acc[0][1], 0, 0, 0);
      acc[0][1] = __builtin_amdgcn_mfma_f32_16x16x32_f16(a0h, b1l, acc[0][1], 0, 0, 0);
      acc[0][1] = __builtin_amdgcn_mfma_f32_16x16x32_f16(a0l, b1h, acc[0][1], 0, 0, 0);
      acc[1][0] = __builtin_amdgcn_mfma_f32_16x16x32_f16(a1h, b0h, acc[1][0], 0, 0, 0);
      acc[1][0] = __builtin_amdgcn_mfma_f32_16x16x32_f16(a1h, b0l, acc[1][0], 0, 0, 0);
      acc[1][0] = __builtin_amdgcn_mfma_f32_16x16x32_f16(a1l, b0h, acc[1][0], 0, 0, 0);
      acc[1][1] = __builtin_amdgcn_mfma_f32_16x16x32_f16(a1h, b1h, acc[1][1], 0, 0, 0);
      acc[1][1] = __builtin_amdgcn_mfma_f32_16x16x32_f16(a1h, b1l, acc[1][1], 0, 0, 0);
      acc[1][1] = __builtin_amdgcn_mfma_f32_16x16x32_f16(a1l, b1h, acc[1][1], 0, 0, 0);
    }
  }
#pragma unroll
  for (int mi = 0; mi < 2; ++mi)
#pragma unroll
    for (int ni = 0; ni < 2; ++ni) {
      int col = bn + wn + ni * 16 + l15;
      float bv = bias[col];
#pragma unroll
      for (int r = 0; r < 4; ++r) {
        int row = bm + wm + mi * 16 + l4 * 4 + r;
        float v = acc[mi][ni][r] + bv;
        if (RELU) v = fmaxf(v, 0.f);
        if (OUTMODE == 0) {
          C[(size_t)row * 256 + col] = v;
        } else {
          v *= oscale;
          _Float16 hh, ll;
          splitf(v, hh, ll);
          Ch[(size_t)row * 256 + col] = hh;
          Cl[(size_t)row * 256 + col] = ll;
        }
      }
    }
}

// ---------------------------------------------------------------------------
// Transpose + split V: fp32 [4096][256] -> f16 planes Vt[256][4096]
__global__ __launch_bounds__(256) void k_transpose_split(
    const float* __restrict__ V, _Float16* __restrict__ Th, _Float16* __restrict__ Tl) {
  __shared__ float Ts[64][65];
  const int r0 = blockIdx.x * 64, c0 = blockIdx.y * 64;
  const int t = threadIdx.x;
#pragma unroll
  for (int rep = 0; rep < 16; ++rep) {
    int idx = rep * 256 + t;
    int r = idx >> 6, c = idx & 63;
    Ts[r][c] = V[(size_t)(r0 + r) * 256 + c0 + c];
  }
  __syncthreads();
#pragma unroll
  for (int rep = 0; rep < 2; ++rep) {
    int idx = rep * 256 + t;
    int c = idx >> 3, r8 = (idx & 7) * 8;
    f16x8 vh, vl;
#pragma unroll
    for (int i = 0; i < 8; ++i) {
      _Float16 h, l;
      splitf(Ts[r8 + i][c], h, l);
      vh[i] = h; vl[i] = l;
    }
    size_t off = (size_t)(c0 + c) * 4096 + r0 + r8;
    *(f16x8*)&Th[off] = vh;
    *(f16x8*)&Tl[off] = vl;
  }
}

// ---------------------------------------------------------------------------
// Split-f16 MFMA flash attention, k-split across blockIdx.z (2 halves).
// Inputs pre-split f16 planes; Q pre-scaled by 1/8. Writes unnormalized
// partial O plus per-row (m, l) for the combine pass.
__global__ __launch_bounds__(256) void k_attn2(
    const _Float16* __restrict__ Qh_g, const _Float16* __restrict__ Ql_g,
    const _Float16* __restrict__ Kh_g, const _Float16* __restrict__ Kl_g,
    const _Float16* __restrict__ Vth_g, const _Float16* __restrict__ Vtl_g,
    float* __restrict__ Opart, float* __restrict__ mpart, float* __restrict__ lpart,
    int nk_half) {
  __shared__ _Float16 Kh[64][72], Kl[64][72];     // [k][d]
  __shared__ _Float16 Vth[64][72], Vtl[64][72];   // [d][k], chunk-swizzled
  __shared__ _Float16 Psh[4][16][72], Psl[4][16][72];
  const int t = threadIdx.x;
  const int h = blockIdx.y;
  const int q0 = blockIdx.x * 64;
  const int half = blockIdx.z;
  const int kbase = half * nk_half;
  const int lane = t & 63, w = t >> 6;
  const int l15 = lane & 15, l4 = lane >> 4;

  f16x8 qh[2], ql[2];
  {
    size_t qoff = (size_t)(q0 + w * 16 + l15) * 256 + h * 64;
#pragma unroll
    for (int kh = 0; kh < 2; ++kh) {
      qh[kh] = *(const f16x8*)&Qh_g[qoff + kh * 32 + l4 * 8];
      ql[kh] = *(const f16x8*)&Ql_g[qoff + kh * 32 + l4 * 8];
    }
  }
  f32x4 o[4] = {};
  float mrun[4] = {-1e30f, -1e30f, -1e30f, -1e30f};
  float lrun[4] = {0.f, 0.f, 0.f, 0.f};

  for (int kt = 0; kt < nk_half; kt += 64) {
    const int k0 = kbase + kt;
    __syncthreads();
#pragma unroll
    for (int rep = 0; rep < 2; ++rep) {
      int idx = t + rep * 256;
      int r = idx >> 3, c8 = idx & 7;
      size_t koff = (size_t)(k0 + r) * 256 + h * 64 + c8 * 8;
      *(f16x8*)&Kh[r][c8 * 8] = *(const f16x8*)&Kh_g[koff];
      *(f16x8*)&Kl[r][c8 * 8] = *(const f16x8*)&Kl_g[koff];
      int sc = c8 ^ ((r >> 3) & 7);  // r = local d for V; c8 = k-chunk
      size_t voff = (size_t)(h * 64 + r) * 4096 + k0 + c8 * 8;
      *(f16x8*)&Vth[r][sc * 8] = *(const f16x8*)&Vth_g[voff];
      *(f16x8*)&Vtl[r][sc * 8] = *(const f16x8*)&Vtl_g[voff];
    }
    __syncthreads();

    // S = Q K^T (per wave: 16 q x 64 k)
    f32x4 sf[4] = {};
#pragma unroll
    for (int kc = 0; kc < 4; ++kc) {
      f16x8 kf0h = *(f16x8*)&Kh[kc * 16 + l15][l4 * 8];
      f16x8 kf0l = *(f16x8*)&Kl[kc * 16 + l15][l4 * 8];
      f16x8 kf1h = *(f16x8*)&Kh[kc * 16 + l15][32 + l4 * 8];
      f16x8 kf1l = *(f16x8*)&Kl[kc * 16 + l15][32 + l4 * 8];
      sf[kc] = __builtin_amdgcn_mfma_f32_16x16x32_f16(qh[0], kf0h, sf[kc], 0, 0, 0);
      sf[kc] = __builtin_amdgcn_mfma_f32_16x16x32_f16(qh[0], kf0l, sf[kc], 0, 0, 0);
      sf[kc] = __builtin_amdgcn_mfma_f32_16x16x32_f16(ql[0], kf0h, sf[kc], 0, 0, 0);
      sf[kc] = __builtin_amdgcn_mfma_f32_16x16x32_f16(qh[1], kf1h, sf[kc], 0, 0, 0);
      sf[kc] = __builtin_amdgcn_mfma_f32_16x16x32_f16(qh[1], kf1l, sf[kc], 0, 0, 0);
      sf[kc] = __builtin_amdgcn_mfma_f32_16x16x32_f16(ql[1], kf1h, sf[kc], 0, 0, 0);
    }

    // online softmax per q-row
#pragma unroll
    for (int r = 0; r < 4; ++r) {
      float s0 = sf[0][r], s1 = sf[1][r], s2 = sf[2][r], s3 = sf[3][r];
      float mt = fmaxf(fmaxf(s0, s1), fmaxf(s2, s3));
      mt = fmaxf(mt, __shfl_xor(mt, 1, 64));
      mt = fmaxf(mt, __shfl_xor(mt, 2, 64));
      mt = fmaxf(mt, __shfl_xor(mt, 4, 64));
      mt = fmaxf(mt, __shfl_xor(mt, 8, 64));
      float mn = fmaxf(mrun[r], mt);
      float alpha = __expf(mrun[r] - mn);
      mrun[r] = mn;
      float p0 = __expf(s0 - mn), p1 = __expf(s1 - mn);
      float p2 = __expf(s2 - mn), p3 = __expf(s3 - mn);
      float rs = p0 + p1 + p2 + p3;
      rs += __shfl_xor(rs, 1, 64);
      rs += __shfl_xor(rs, 2, 64);
      rs += __shfl_xor(rs, 4, 64);
      rs += __shfl_xor(rs, 8, 64);
      lrun[r] = lrun[r] * alpha + rs;
      o[0][r] *= alpha; o[1][r] *= alpha; o[2][r] *= alpha; o[3][r] *= alpha;
      int prow = l4 * 4 + r;
      float ps[4] = {p0, p1, p2, p3};
#pragma unroll
      for (int kc = 0; kc < 4; ++kc)
        splitf(ps[kc], Psh[w][prow][kc * 16 + l15], Psl[w][prow][kc * 16 + l15]);
    }

    // O += P @ V
#pragma unroll
    for (int kh = 0; kh < 2; ++kh) {
      f16x8 pah = *(f16x8*)&Psh[w][l15][kh * 32 + l4 * 8];
      f16x8 pal = *(f16x8*)&Psl[w][l15][kh * 32 + l4 * 8];
#pragma unroll
      for (int oc = 0; oc < 4; ++oc) {
        int d = oc * 16 + l15;
        int chunk = (kh * 4 + l4) ^ ((d >> 3) & 7);
        f16x8 vbh = *(f16x8*)&Vth[d][chunk * 8];
        f16x8 vbl = *(f16x8*)&Vtl[d][chunk * 8];
        o[oc] = __builtin_amdgcn_mfma_f32_16x16x32_f16(pah, vbh, o[oc], 0, 0, 0);
        o[oc] = __builtin_amdgcn_mfma_f32_16x16x32_f16(pah, vbl, o[oc], 0, 0, 0);
        o[oc] = __builtin_amdgcn_mfma_f32_16x16x32_f16(pal, vbh, o[oc], 0, 0, 0);
      }
    }
  }

#pragma unroll
  for (int oc = 0; oc < 4; ++oc) {
    int col = h * 64 + oc * 16 + l15;
#pragma unroll
    for (int r = 0; r < 4; ++r) {
      int row = q0 + w * 16 + l4 * 4 + r;
      Opart[((size_t)half * 4096 + row) * 256 + col] = o[oc][r];
    }
  }
  if (l15 == 0) {
#pragma unroll
    for (int r = 0; r < 4; ++r) {
      int row = q0 + w * 16 + l4 * 4 + r;
      mpart[(size_t)(half * 4 + h) * 4096 + row] = mrun[r];
      lpart[(size_t)(half * 4 + h) * 4096 + row] = lrun[r];
    }
  }
}

// Combine the two k-halves and add the residual (in-place OK: idx==idx).
__global__ __launch_bounds__(256) void k_attn_combine(
    const float* __restrict__ Opart, const float* __restrict__ mpart,
    const float* __restrict__ lpart, const float* __restrict__ Hin,
    float* __restrict__ Out) {
  const size_t idx = (size_t)blockIdx.x * 256 + threadIdx.x;  // 4096*256
  const int row = (int)(idx >> 8);
  const int col = (int)(idx & 255);
  const int h = col >> 6;
  float m1 = mpart[(size_t)h * 4096 + row];
  float m2 = mpart[(size_t)(4 + h) * 4096 + row];
  float l1 = lpart[(size_t)h * 4096 + row];
  float l2 = lpart[(size_t)(4 + h) * 4096 + row];
  float M = fmaxf(m1, m2);
  float e1 = __expf(m1 - M), e2 = __expf(m2 - M);
  float O1 = Opart[idx];
  float O2 = Opart[(size_t)4096 * 256 + idx];
  float L = l1 * e1 + l2 * e2;
  Out[idx] = (O1 * e1 + O2 * e2) / L + Hin[idx];
}

// ---------------------------------------------------------------------------
__global__ __launch_bounds__(256) void k_segsum(
    const float* __restrict__ Hc, const int* __restrict__ batch,
    float* __restrict__ z, float* __restrict__ cnt) {
  const int i = blockIdx.x;
  const int c = threadIdx.x;
  const int g = batch[i];
  atomicAdd(&z[(size_t)g * 512 + c], Hc[(size_t)i * HDIM + c]);
  if (c == 0) atomicAdd(&cnt[g], 1.0f);
}

__global__ __launch_bounds__(256) void k_segdiv(float* __restrict__ z,
                                                const float* __restrict__ cnt) {
  const int idx = blockIdx.x * 256 + threadIdx.x;
  const int g = idx >> 9, c = idx & 511;
  const float cc = cnt[(c < 256) ? g : (32 + g)];
  z[idx] /= fmaxf(cc, 1.0f);
}

__global__ __launch_bounds__(256) void k_fc1(
    const float* __restrict__ z, const float* __restrict__ w,
    const float* __restrict__ b, float* __restrict__ out) {
  const int idx = blockIdx.x * 256 + threadIdx.x;
  const int r = idx >> 8, c = idx & 255;
  float acc = b[c];
  for (int k = 0; k < 512; ++k) acc += z[r * 512 + k] * w[k * HDIM + c];
  out[idx] = fmaxf(acc, 0.f);
}

__global__ __launch_bounds__(64) void k_fc2(
    const float* __restrict__ xin, const float* __restrict__ w,
    const float* __restrict__ b, float* __restrict__ out) {
  const int r = threadIdx.x;
  if (r < NG) {
    float acc = b[0];
    for (int k = 0; k < HDIM; ++k) acc += xin[r * HDIM + k] * w[k];
    out[r] = 1.0f / (1.0f + __expf(-acc));
  }
}

// ---------------------------------------------------------------------------
extern "C" void kernel_launch(void* const* d_in, const int* in_sizes, int n_in,
                              void* d_out, int out_size, void* d_ws, size_t ws_size,
                              hipStream_t stream) {
  const float* x_mol   = (const float*)d_in[0];
  const float* x_prot  = (const float*)d_in[1];
  const float* ea_mol  = (const float*)d_in[2];
  const float* ea_prot = (const float*)d_in[3];
  const int*   ei_mol  = (const int*)d_in[4];
  const int*   ei_prot = (const int*)d_in[5];
  const int*   b_mol   = (const int*)d_in[6];
  const int*   b_prot  = (const int*)d_in[7];
  const float* nlm_w = (const float*)d_in[8];
  const float* nlm_b = (const float*)d_in[9];
  const float* nlp_w = (const float*)d_in[10];
  const float* nlp_b = (const float*)d_in[11];
  const float* elm_w = (const float*)d_in[12];
  const float* elm_b = (const float*)d_in[13];
  const float* elp_w = (const float*)d_in[14];
  const float* elp_b = (const float*)d_in[15];
  const float* mol_w1 = (const float*)d_in[16];
  const float* mol_b1 = (const float*)d_in[17];
  const float* mol_w2 = (const float*)d_in[18];
  const float* mol_b2 = (const float*)d_in[19];
  const float* prot_w1 = (const float*)d_in[20];
  const float* prot_b1 = (const float*)d_in[21];
  const float* prot_w2 = (const float*)d_in[22];
  const float* prot_b2 = (const float*)d_in[23];
  const float* mp_wq = (const float*)d_in[24];
  const float* mp_bq = (const float*)d_in[25];
  const float* mp_wk = (const float*)d_in[26];
  const float* mp_bk = (const float*)d_in[27];
  const float* mp_wv = (const float*)d_in[28];
  const float* mp_bv = (const float*)d_in[29];
  const float* pm_wq = (const float*)d_in[30];
  const float* pm_bq = (const float*)d_in[31];
  const float* pm_wk = (const float*)d_in[32];
  const float* pm_bk = (const float*)d_in[33];
  const float* pm_wv = (const float*)d_in[34];
  const float* pm_bv = (const float*)d_in[35];
  const float* fc1_w = (const float*)d_in[36];
  const float* fc1_b = (const float*)d_in[37];
  const float* fc2_w = (const float*)d_in[38];
  const float* fc2_b = (const float*)d_in[39];
  float* out = (float*)d_out;

  // workspace carve (bytes); peak ~51 MB
  char* W8 = (char*)d_ws;
  const size_t MB = 1u << 20;
  float* hm  = (float*)(W8 + 0 * MB);     // fp32 activations / final H_c (in-place)
  float* hp  = (float*)(W8 + 4 * MB);
  float* t1  = (float*)(W8 + 8 * MB);     // GINE temp; later V fp32
  float* Vb  = (float*)(W8 + 8 * MB);
  float* agg = (float*)(W8 + 12 * MB);
  _Float16* wtH = (_Float16*)(W8 + 16 * MB);
  _Float16* wtL = (_Float16*)(W8 + 18 * MB);
  _Float16* Qh = (_Float16*)(W8 + 20 * MB);
  _Float16* Ql = (_Float16*)(W8 + 22 * MB);
  _Float16* Kh = (_Float16*)(W8 + 24 * MB);
  _Float16* Kl = (_Float16*)(W8 + 26 * MB);
  _Float16* Vth = (_Float16*)(W8 + 28 * MB);
  _Float16* Vtl = (_Float16*)(W8 + 30 * MB);
  _Float16* hmh = (_Float16*)(W8 + 32 * MB);
  _Float16* hml = (_Float16*)(W8 + 34 * MB);
  _Float16* hph = (_Float16*)(W8 + 36 * MB);
  _Float16* hpl = (_Float16*)(W8 + 38 * MB);
  float* Opart = (float*)(W8 + 40 * MB);  // 8 MB
  float* mpart = (float*)(W8 + 48 * MB);  // 32768
  float* lpart = mpart + 32768;           // 32768
  float* zb  = lpart + 32768;             // 32*512
  float* cnt = zb + 32 * 512;             // 64
  float* fch = cnt + 64;                  // 32*256
  int* off_m = (int*)(W8 + 49 * MB);
  int* cur_m = off_m + 4224;
  int* eid_m = cur_m + 4224;
  int* off_p = (int*)(W8 + 50 * MB);
  int* cur_p = off_p + 4224;
  int* eid_p = cur_p + 4224;

  PtrPack pk;
  pk.p[0] = mol_w1;           pk.p[1] = mol_w1 + 65536;
  pk.p[2] = mol_w2;           pk.p[3] = mol_w2 + 65536;
  pk.p[4] = prot_w1;          pk.p[5] = prot_w1 + 65536;
  pk.p[6] = prot_w2;          pk.p[7] = prot_w2 + 65536;
  pk.p[8] = mp_wq;  pk.p[9] = mp_wk;  pk.p[10] = mp_wv;
  pk.p[11] = pm_wq; pk.p[12] = pm_wk; pk.p[13] = pm_wv;
  k_prep_wt<<<dim3(4, 4, 14), 256, 0, stream>>>(pk, wtH, wtL);

  hipMemsetAsync(cur_m, 0, 4096 * 4, stream);
  hipMemsetAsync(cur_p, 0, 4096 * 4, stream);
  k_csr_count<<<NEDGE / 256, 256, 0, stream>>>(ei_mol, cur_m, NEDGE);
  k_csr_count<<<NEDGE / 256, 256, 0, stream>>>(ei_prot, cur_p, NEDGE);
  k_csr_scan<<<1, 256, 0, stream>>>(cur_m, off_m, NMOL);
  k_csr_scan<<<1, 256, 0, stream>>>(cur_p, off_p, NPROT);
  k_csr_scatter<<<NEDGE / 256, 256, 0, stream>>>(ei_mol, cur_m, eid_m, NEDGE);
  k_csr_scatter<<<NEDGE / 256, 256, 0, stream>>>(ei_prot, cur_p, eid_p, NEDGE);

  const dim3 ggrid(64, 4), gblk(256);
#define WTH(i) (wtH + (size_t)(i) * 65536)
#define WTL(i) (wtL + (size_t)(i) * 65536)
#define GEMM_F32(RELU, HASA2, A1, A2, WI, B, C) \
  k_gemm_split<RELU, HASA2, false, 0><<<ggrid, gblk, 0, stream>>>( \
      A1, A2, nullptr, nullptr, WTH(WI), WTL(WI), B, C, nullptr, nullptr, 1.0f)
#define GEMM_SPLITOUT(AH, AL, WI, B, CH, CL, SC) \
  k_gemm_split<false, false, true, 1><<<ggrid, gblk, 0, stream>>>( \
      nullptr, nullptr, AH, AL, WTH(WI), WTL(WI), B, nullptr, CH, CL, SC)
#define GEMM_F32OUT_PRESPLIT(AH, AL, WI, B, C) \
  k_gemm_split<false, false, true, 0><<<ggrid, gblk, 0, stream>>>( \
      nullptr, nullptr, AH, AL, WTH(WI), WTL(WI), B, C, nullptr, nullptr, 1.0f)

  k_node_embed<<<NMOL, 256, 0, stream>>>(x_mol, nlm_w, nlm_b, hm, 8);
  k_node_embed<<<NPROT, 256, 0, stream>>>(x_prot, nlp_w, nlp_b, hp, 4);

  for (int l = 0; l < 2; ++l) {
    k_gine_agg_csr<<<NMOL, 256, 0, stream>>>(hm, ea_mol, ei_mol, off_m, eid_m,
                                             elm_w, elm_b, agg);
    GEMM_F32(true, true, hm, agg, l, mol_b1 + l * 256, t1);
    GEMM_F32(true, false, t1, nullptr, 2 + l, mol_b2 + l * 256, hm);
  }
  for (int l = 0; l < 2; ++l) {
    k_gine_agg_csr<<<NPROT, 256, 0, stream>>>(hp, ea_prot, ei_prot, off_p, eid_p,
                                              elp_w, elp_b, agg);
    GEMM_F32(true, true, hp, agg, 4 + l, prot_b1 + l * 256, t1);
    GEMM_F32(true, false, t1, nullptr, 6 + l, prot_b2 + l * 256, hp);
  }

  // pre-split final activations once for all 6 QKV GEMMs
  k_split_act<<<512, 256, 0, stream>>>(hm, hmh, hml);
  k_split_act<<<512, 256, 0, stream>>>(hp, hph, hpl);

  // cross attention mol <- prot
  GEMM_SPLITOUT(hmh, hml, 8, mp_bq, Qh, Ql, 0.125f);
  GEMM_SPLITOUT(hph, hpl, 9, mp_bk, Kh, Kl, 1.0f);
  GEMM_F32OUT_PRESPLIT(hph, hpl, 10, mp_bv, Vb);
  k_transpose_split<<<dim3(64, 4), 256, 0, stream>>>(Vb, Vth, Vtl);
  k_attn2<<<dim3(64, 4, 2), 256, 0, stream>>>(Qh, Ql, Kh, Kl, Vth, Vtl,
                                              Opart, mpart, lpart, 2048);
  k_attn_combine<<<4096, 256, 0, stream>>>(Opart, mpart, lpart, hm, hm);

  // cross attention prot <- mol
  GEMM_SPLITOUT(hph, hpl, 11, pm_bq, Qh, Ql, 0.125f);
  GEMM_SPLITOUT(hmh, hml, 12, pm_bk, Kh, Kl, 1.0f);
  GEMM_F32OUT_PRESPLIT(hmh, hml, 13, pm_bv, Vb);
  k_transpose_split<<<dim3(64, 4), 256, 0, stream>>>(Vb, Vth, Vtl);
  k_attn2<<<dim3(64, 4, 2), 256, 0, stream>>>(Qh, Ql, Kh, Kl, Vth, Vtl,
                                              Opart, mpart, lpart, 2048);
  k_attn_combine<<<4096, 256, 0, stream>>>(Opart, mpart, lpart, hp, hp);

  // pooling + head
  hipMemsetAsync(zb, 0, (32 * 512 + 64) * 4, stream);
  k_segsum<<<NMOL, 256, 0, stream>>>(hm, b_mol, zb, cnt);
  k_segsum<<<NPROT, 256, 0, stream>>>(hp, b_prot, zb + 256, cnt + 32);
  k_segdiv<<<64, 256, 0, stream>>>(zb, cnt);
  k_fc1<<<32, 256, 0, stream>>>(zb, fc1_w, fc1_b, fch);
  k_fc2<<<1, 64, 0, stream>>>(fch, fc2_w, fc2_b, out);
#undef WTH
#undef WTL
#undef GEMM_F32
#undef GEMM_SPLITOUT
#undef GEMM_F32OUT_PRESPLIT
}

// Round 7
// 698.152 us; speedup vs baseline: 3.2047x; 1.0981x over previous
//
#include <hip/hip_runtime.h>
#include <math.h>

#define HDIM 256
#define NMOL 4096
#define NPROT 4096
#define NEDGE 65536
#define NG 32

typedef _Float16 f16x8 __attribute__((ext_vector_type(8)));
typedef __attribute__((ext_vector_type(4))) float f32x4;

__device__ __forceinline__ void splitf(float x, _Float16& h, _Float16& l) {
  h = (_Float16)x;
  l = (_Float16)(x - (float)h);
}

// ---------------------------------------------------------------------------
// Transpose + convert 14 H x H fp32 weights into split f16 planes Wt[n][k].
struct PtrPack { const float* p[14]; };

__global__ __launch_bounds__(256) void k_prep_wt(PtrPack pk, _Float16* __restrict__ dh,
                                                 _Float16* __restrict__ dl) {
  __shared__ float Ts[64][68];
  const int m = blockIdx.z;
  const int n0 = blockIdx.y * 64, k0 = blockIdx.x * 64;
  const float* W = pk.p[m];
  const int t = threadIdx.x;
#pragma unroll
  for (int rep = 0; rep < 16; ++rep) {
    int k = rep * 4 + (t >> 6);
    int n = t & 63;
    Ts[n][k] = W[(size_t)(k0 + k) * 256 + n0 + n];
  }
  __syncthreads();
#pragma unroll
  for (int rep = 0; rep < 2; ++rep) {
    int idx = t + rep * 256;
    int nr = idx >> 3, koff = (idx & 7) * 8;
    f16x8 vh, vl;
#pragma unroll
    for (int i = 0; i < 8; ++i) {
      _Float16 h, l;
      splitf(Ts[nr][koff + i], h, l);
      vh[i] = h; vl[i] = l;
    }
    size_t off = (size_t)m * 65536 + (size_t)(n0 + nr) * 256 + k0 + koff;
    *(f16x8*)&dh[off] = vh;
    *(f16x8*)&dl[off] = vl;
  }
}

// ---------------------------------------------------------------------------
// node embedding (fp32 out), both graphs in one dispatch (blockIdx.y)
struct EmbJob { const float* x; const float* w; const float* b; float* out; int K; };

__global__ __launch_bounds__(256) void k_node_embed2(EmbJob j0, EmbJob j1) {
  const EmbJob& j = blockIdx.y ? j1 : j0;
  const int i = blockIdx.x;
  const int c = threadIdx.x;
  float acc = j.b[c];
  for (int k = 0; k < j.K; ++k) acc += j.x[i * j.K + k] * j.w[k * HDIM + c];
  j.out[(size_t)i * HDIM + c] = acc;
}

// ---------------------------------------------------------------------------
// CSR build (both graphs per dispatch)
__global__ __launch_bounds__(256) void k_csr_count2(const int* __restrict__ ei0,
                                                    const int* __restrict__ ei1,
                                                    int* __restrict__ cur0,
                                                    int* __restrict__ cur1, int E) {
  const int* ei = blockIdx.y ? ei1 : ei0;
  int* cur = blockIdx.y ? cur1 : cur0;
  const int e = blockIdx.x * 256 + threadIdx.x;
  if (e < E) atomicAdd(&cur[ei[E + e]], 1);
}

__global__ __launch_bounds__(256) void k_csr_scan2(int* __restrict__ c0, int* __restrict__ o0,
                                                   int* __restrict__ c1, int* __restrict__ o1,
                                                   int N) {
  int* cnt_cur = blockIdx.x ? c1 : c0;
  int* off = blockIdx.x ? o1 : o0;
  __shared__ int tsum[256], tpre[257];
  const int t = threadIdx.x;
  const int base = t * 16;
  int loc[16], s = 0;
#pragma unroll
  for (int i = 0; i < 16; ++i) { loc[i] = cnt_cur[base + i]; s += loc[i]; }
  tsum[t] = s;
  __syncthreads();
  if (t == 0) {
    int a = 0;
    for (int i = 0; i < 256; ++i) { tpre[i] = a; a += tsum[i]; }
    tpre[256] = a;
  }
  __syncthreads();
  int a = tpre[t];
#pragma unroll
  for (int i = 0; i < 16; ++i) {
    off[base + i] = a;
    cnt_cur[base + i] = a;
    a += loc[i];
  }
  if (t == 255) off[N] = tpre[256];
}

__global__ __launch_bounds__(256) void k_csr_scatter2(const int* __restrict__ ei0,
                                                      const int* __restrict__ ei1,
                                                      int* __restrict__ cur0,
                                                      int* __restrict__ cur1,
                                                      int* __restrict__ eid0,
                                                      int* __restrict__ eid1, int E) {
  const int* ei = blockIdx.y ? ei1 : ei0;
  int* cur = blockIdx.y ? cur1 : cur0;
  int* eid = blockIdx.y ? eid1 : eid0;
  const int e = blockIdx.x * 256 + threadIdx.x;
  if (e < E) {
    int pos = atomicAdd(&cur[ei[E + e]], 1);
    eid[pos] = e;
  }
}

// ---------------------------------------------------------------------------
// GINE aggregation via CSR gather, both graphs per dispatch
struct AggJob {
  const float* x; const float* ea; const int* eis; const int* off;
  const int* eid; const float* we; const float* be; float* agg;
};

__global__ __launch_bounds__(256) void k_agg2(AggJob a0, AggJob a1) {
  const AggJob& a = blockIdx.y ? a1 : a0;
  const int n = blockIdx.x;
  const int c = threadIdx.x;
  const float w0 = a.we[c], w1 = a.we[HDIM + c], bb = a.be[c];
  const int j0 = a.off[n], j1 = a.off[n + 1];
  float sum = 0.f;
  for (int j = j0; j < j1; ++j) {
    int e = a.eid[j];
    int src = a.eis[e];
    float e0 = a.ea[2 * e], e1 = a.ea[2 * e + 1];
    float m = a.x[(size_t)src * HDIM + c] + e0 * w0 + e1 * w1 + bb;
    sum += fmaxf(m, 0.f);
  }
  a.agg[(size_t)n * HDIM + c] = sum;
}

// ---------------------------------------------------------------------------
// Unified split-f16 MFMA GEMM, K=256, job table indexed by blockIdx.z.
// flags: 1=relu, 2=hasA2, 4=presplit A; outmode=flags>>4:
//   0 = fp32 C; 1 = split f16 planes (scaled); 2 = fp32 C AND split planes.
struct GJob {
  const float* A1; const float* A2;
  const _Float16* Ah; const _Float16* Al;
  const _Float16* Bh; const _Float16* Bl;
  const float* bias; float* C;
  _Float16* Ch; _Float16* Cl;
  float oscale; int flags;
};
struct GJobs { GJob j[6]; };

__global__ __launch_bounds__(256) void k_gemm(GJobs js) {
  const GJob J = js.j[blockIdx.z];
  const int relu = J.flags & 1, hasa2 = J.flags & 2, presplit = J.flags & 4;
  const int outmode = J.flags >> 4;
  __shared__ _Float16 Ah[64][72], Al[64][72], Bh[64][72], Bl[64][72];
  const int t = threadIdx.x;
  const int bm = blockIdx.x * 64, bn = blockIdx.y * 64;
  const int lane = t & 63, w = t >> 6;
  const int l15 = lane & 15, l4 = lane >> 4;
  const int wm = (w >> 1) * 32, wn = (w & 1) * 32;
  f32x4 acc[2][2] = {};
  for (int k0 = 0; k0 < 256; k0 += 64) {
    __syncthreads();
    if (presplit) {
#pragma unroll
      for (int rep = 0; rep < 2; ++rep) {
        int idx = t + rep * 256;
        int r = idx >> 3, k8 = (idx & 7) * 8;
        size_t off = (size_t)(bm + r) * 256 + k0 + k8;
        *(f16x8*)&Ah[r][k8] = *(const f16x8*)&J.Ah[off];
        *(f16x8*)&Al[r][k8] = *(const f16x8*)&J.Al[off];
      }
    } else {
#pragma unroll
      for (int rep = 0; rep < 4; ++rep) {
        int idx = t + rep * 256;
        int r = idx >> 4, c4 = (idx & 15) * 4;
        float4 a = *(const float4*)&J.A1[(size_t)(bm + r) * 256 + k0 + c4];
        if (hasa2) {
          float4 a2 = *(const float4*)&J.A2[(size_t)(bm + r) * 256 + k0 + c4];
          a.x += a2.x; a.y += a2.y; a.z += a2.z; a.w += a2.w;
        }
        float av[4] = {a.x, a.y, a.z, a.w};
#pragma unroll
        for (int i = 0; i < 4; ++i) splitf(av[i], Ah[r][c4 + i], Al[r][c4 + i]);
      }
    }
#pragma unroll
    for (int rep = 0; rep < 2; ++rep) {
      int idx = t + rep * 256;
      int nr = idx >> 3, koff = (idx & 7) * 8;
      size_t off = (size_t)(bn + nr) * 256 + k0 + koff;
      *(f16x8*)&Bh[nr][koff] = *(const f16x8*)&J.Bh[off];
      *(f16x8*)&Bl[nr][koff] = *(const f16x8*)&J.Bl[off];
    }
    __syncthreads();
#pragma unroll
    for (int kh = 0; kh < 2; ++kh) {
      f16x8 a0h = *(f16x8*)&Ah[wm + l15][kh * 32 + l4 * 8];
      f16x8 a0l = *(f16x8*)&Al[wm + l15][kh * 32 + l4 * 8];
      f16x8 a1h = *(f16x8*)&Ah[wm + 16 + l15][kh * 32 + l4 * 8];
      f16x8 a1l = *(f16x8*)&Al[wm + 16 + l15][kh * 32 + l4 * 8];
      f16x8 b0h = *(f16x8*)&Bh[wn + l15][kh * 32 + l4 * 8];
      f16x8 b0l = *(f16x8*)&Bl[wn + l15][kh * 32 + l4 * 8];
      f16x8 b1h = *(f16x8*)&Bh[wn + 16 + l15][kh * 32 + l4 * 8];
      f16x8 b1l = *(f16x8*)&Bl[wn + 16 + l15][kh * 32 + l4 * 8];
      acc[0][0] = __builtin_amdgcn_mfma_f32_16x16x32_f16(a0h, b0h, acc[0][0], 0, 0, 0);
      acc[0][0] = __builtin_amdgcn_mfma_f32_16x16x32_f16(a0h, b0l, acc[0][0], 0, 0, 0);
      acc[0][0] = __builtin_amdgcn_mfma_f32_16x16x32_f16(a0l, b0h, acc[0][0], 0, 0, 0);
      acc[0][1] = __builtin_amdgcn_mfma_f32_16x16x32_f16(a0h, b1h, acc[0][1], 0, 0, 0);
      acc[0][1] = __builtin_amdgcn_mfma_f32_16x16x32_f16(a0h, b1l, acc[0][1], 0, 0, 0);
      acc[0][1] = __builtin_amdgcn_mfma_f32_16x16x32_f16(a0l, b1h, acc[0][1], 0, 0, 0);
      acc[1][0] = __builtin_amdgcn_mfma_f32_16x16x32_f16(a1h, b0h, acc[1][0], 0, 0, 0);
      acc[1][0] = __builtin_amdgcn_mfma_f32_16x16x32_f16(a1h, b0l, acc[1][0], 0, 0, 0);
      acc[1][0] = __builtin_amdgcn_mfma_f32_16x16x32_f16(a1l, b0h, acc[1][0], 0, 0, 0);
      acc[1][1] = __builtin_amdgcn_mfma_f32_16x16x32_f16(a1h, b1h, acc[1][1], 0, 0, 0);
      acc[1][1] = __builtin_amdgcn_mfma_f32_16x16x32_f16(a1h, b1l, acc[1][1], 0, 0, 0);
      acc[1][1] = __builtin_amdgcn_mfma_f32_16x16x32_f16(a1l, b1h, acc[1][1], 0, 0, 0);
    }
  }
#pragma unroll
  for (int mi = 0; mi < 2; ++mi)
#pragma unroll
    for (int ni = 0; ni < 2; ++ni) {
      int col = bn + wn + ni * 16 + l15;
      float bv = J.bias[col];
#pragma unroll
      for (int r = 0; r < 4; ++r) {
        int row = bm + wm + mi * 16 + l4 * 4 + r;
        float v = acc[mi][ni][r] + bv;
        if (relu) v = fmaxf(v, 0.f);
        if (outmode != 1) J.C[(size_t)row * 256 + col] = v;
        if (outmode != 0) {
          float vs = v * J.oscale;
          _Float16 hh, ll;
          splitf(vs, hh, ll);
          J.Ch[(size_t)row * 256 + col] = hh;
          J.Cl[(size_t)row * 256 + col] = ll;
        }
      }
    }
}

// ---------------------------------------------------------------------------
// Transpose + split V for both dirs: fp32 [4096][256] -> f16 planes [256][4096]
__global__ __launch_bounds__(256) void k_transpose2(
    const float* __restrict__ V0, const float* __restrict__ V1,
    _Float16* __restrict__ Th0, _Float16* __restrict__ Tl0,
    _Float16* __restrict__ Th1, _Float16* __restrict__ Tl1) {
  __shared__ float Ts[64][65];
  const int dir = blockIdx.z;
  const float* V = dir ? V1 : V0;
  _Float16* Th = dir ? Th1 : Th0;
  _Float16* Tl = dir ? Tl1 : Tl0;
  const int r0 = blockIdx.x * 64, c0 = blockIdx.y * 64;
  const int t = threadIdx.x;
#pragma unroll
  for (int rep = 0; rep < 16; ++rep) {
    int idx = rep * 256 + t;
    int r = idx >> 6, c = idx & 63;
    Ts[r][c] = V[(size_t)(r0 + r) * 256 + c0 + c];
  }
  __syncthreads();
#pragma unroll
  for (int rep = 0; rep < 2; ++rep) {
    int idx = rep * 256 + t;
    int c = idx >> 3, r8 = (idx & 7) * 8;
    f16x8 vh, vl;
#pragma unroll
    for (int i = 0; i < 8; ++i) {
      _Float16 h, l;
      splitf(Ts[r8 + i][c], h, l);
      vh[i] = h; vl[i] = l;
    }
    size_t off = (size_t)(c0 + c) * 4096 + r0 + r8;
    *(f16x8*)&Th[off] = vh;
    *(f16x8*)&Tl[off] = vl;
  }
}

// ---------------------------------------------------------------------------
// Merged flash attention: grid (64 q-tiles, 8 = dir*4+head, 2 k-halves).
// P-lo term dropped in PV (P in [0,1], error ~2^-11 relative to row sum).
struct AttnArgs {
  const _Float16* Qh[2]; const _Float16* Ql[2];
  const _Float16* Kh[2]; const _Float16* Kl[2];
  const _Float16* Vth[2]; const _Float16* Vtl[2];
  float* Opart; float* mpart; float* lpart;
};

__global__ __launch_bounds__(256) void k_attn3(AttnArgs A, int nk_half) {
  __shared__ _Float16 Ksh[64][72], Ksl[64][72];   // [k][d]
  __shared__ _Float16 Vsh[64][72], Vsl[64][72];   // [d][k], chunk-swizzled
  __shared__ _Float16 Psh[4][16][72];             // per-wave P hi [q][k]
  const int t = threadIdx.x;
  const int dir = blockIdx.y >> 2, h = blockIdx.y & 3;
  const int q0 = blockIdx.x * 64;
  const int half = blockIdx.z;
  const int kbase = half * nk_half;
  const int lane = t & 63, w = t >> 6;
  const int l15 = lane & 15, l4 = lane >> 4;

  const _Float16* Qh_g = A.Qh[dir];
  const _Float16* Ql_g = A.Ql[dir];
  const _Float16* Kh_g = A.Kh[dir];
  const _Float16* Kl_g = A.Kl[dir];
  const _Float16* Vth_g = A.Vth[dir];
  const _Float16* Vtl_g = A.Vtl[dir];

  f16x8 qh[2], ql[2];
  {
    size_t qoff = (size_t)(q0 + w * 16 + l15) * 256 + h * 64;
#pragma unroll
    for (int kh = 0; kh < 2; ++kh) {
      qh[kh] = *(const f16x8*)&Qh_g[qoff + kh * 32 + l4 * 8];
      ql[kh] = *(const f16x8*)&Ql_g[qoff + kh * 32 + l4 * 8];
    }
  }
  f32x4 o[4] = {};
  float mrun[4] = {-1e30f, -1e30f, -1e30f, -1e30f};
  float lrun[4] = {0.f, 0.f, 0.f, 0.f};

  for (int kt = 0; kt < nk_half; kt += 64) {
    const int k0 = kbase + kt;
    __syncthreads();
#pragma unroll
    for (int rep = 0; rep < 2; ++rep) {
      int idx = t + rep * 256;
      int r = idx >> 3, c8 = idx & 7;
      size_t koff = (size_t)(k0 + r) * 256 + h * 64 + c8 * 8;
      *(f16x8*)&Ksh[r][c8 * 8] = *(const f16x8*)&Kh_g[koff];
      *(f16x8*)&Ksl[r][c8 * 8] = *(const f16x8*)&Kl_g[koff];
      int sc = c8 ^ ((r >> 3) & 7);
      size_t voff = (size_t)(h * 64 + r) * 4096 + k0 + c8 * 8;
      *(f16x8*)&Vsh[r][sc * 8] = *(const f16x8*)&Vth_g[voff];
      *(f16x8*)&Vsl[r][sc * 8] = *(const f16x8*)&Vtl_g[voff];
    }
    __syncthreads();

    // S = Q K^T (per wave: 16 q x 64 k)
    f32x4 sf[4] = {};
#pragma unroll
    for (int kc = 0; kc < 4; ++kc) {
      f16x8 kf0h = *(f16x8*)&Ksh[kc * 16 + l15][l4 * 8];
      f16x8 kf0l = *(f16x8*)&Ksl[kc * 16 + l15][l4 * 8];
      f16x8 kf1h = *(f16x8*)&Ksh[kc * 16 + l15][32 + l4 * 8];
      f16x8 kf1l = *(f16x8*)&Ksl[kc * 16 + l15][32 + l4 * 8];
      sf[kc] = __builtin_amdgcn_mfma_f32_16x16x32_f16(qh[0], kf0h, sf[kc], 0, 0, 0);
      sf[kc] = __builtin_amdgcn_mfma_f32_16x16x32_f16(qh[0], kf0l, sf[kc], 0, 0, 0);
      sf[kc] = __builtin_amdgcn_mfma_f32_16x16x32_f16(ql[0], kf0h, sf[kc], 0, 0, 0);
      sf[kc] = __builtin_amdgcn_mfma_f32_16x16x32_f16(qh[1], kf1h, sf[kc], 0, 0, 0);
      sf[kc] = __builtin_amdgcn_mfma_f32_16x16x32_f16(qh[1], kf1l, sf[kc], 0, 0, 0);
      sf[kc] = __builtin_amdgcn_mfma_f32_16x16x32_f16(ql[1], kf1h, sf[kc], 0, 0, 0);
    }

    // online softmax per q-row
#pragma unroll
    for (int r = 0; r < 4; ++r) {
      float s0 = sf[0][r], s1 = sf[1][r], s2 = sf[2][r], s3 = sf[3][r];
      float mt = fmaxf(fmaxf(s0, s1), fmaxf(s2, s3));
      mt = fmaxf(mt, __shfl_xor(mt, 1, 64));
      mt = fmaxf(mt, __shfl_xor(mt, 2, 64));
      mt = fmaxf(mt, __shfl_xor(mt, 4, 64));
      mt = fmaxf(mt, __shfl_xor(mt, 8, 64));
      float mn = fmaxf(mrun[r], mt);
      float alpha = __expf(mrun[r] - mn);
      mrun[r] = mn;
      float p0 = __expf(s0 - mn), p1 = __expf(s1 - mn);
      float p2 = __expf(s2 - mn), p3 = __expf(s3 - mn);
      float rs = p0 + p1 + p2 + p3;
      rs += __shfl_xor(rs, 1, 64);
      rs += __shfl_xor(rs, 2, 64);
      rs += __shfl_xor(rs, 4, 64);
      rs += __shfl_xor(rs, 8, 64);
      lrun[r] = lrun[r] * alpha + rs;
      o[0][r] *= alpha; o[1][r] *= alpha; o[2][r] *= alpha; o[3][r] *= alpha;
      int prow = l4 * 4 + r;
      Psh[w][prow][0 * 16 + l15] = (_Float16)p0;
      Psh[w][prow][1 * 16 + l15] = (_Float16)p1;
      Psh[w][prow][2 * 16 + l15] = (_Float16)p2;
      Psh[w][prow][3 * 16 + l15] = (_Float16)p3;
    }

    // O += P @ V (P-lo dropped; keep V-lo term)
#pragma unroll
    for (int kh = 0; kh < 2; ++kh) {
      f16x8 pah = *(f16x8*)&Psh[w][l15][kh * 32 + l4 * 8];
#pragma unroll
      for (int oc = 0; oc < 4; ++oc) {
        int d = oc * 16 + l15;
        int chunk = (kh * 4 + l4) ^ ((d >> 3) & 7);
        f16x8 vbh = *(f16x8*)&Vsh[d][chunk * 8];
        f16x8 vbl = *(f16x8*)&Vsl[d][chunk * 8];
        o[oc] = __builtin_amdgcn_mfma_f32_16x16x32_f16(pah, vbh, o[oc], 0, 0, 0);
        o[oc] = __builtin_amdgcn_mfma_f32_16x16x32_f16(pah, vbl, o[oc], 0, 0, 0);
      }
    }
  }

  const int slot = dir * 2 + half;
#pragma unroll
  for (int oc = 0; oc < 4; ++oc) {
    int col = h * 64 + oc * 16 + l15;
#pragma unroll
    for (int r = 0; r < 4; ++r) {
      int row = q0 + w * 16 + l4 * 4 + r;
      A.Opart[((size_t)slot * 4096 + row) * 256 + col] = o[oc][r];
    }
  }
  if (l15 == 0) {
#pragma unroll
    for (int r = 0; r < 4; ++r) {
      int row = q0 + w * 16 + l4 * 4 + r;
      A.mpart[(size_t)(slot * 4 + h) * 4096 + row] = mrun[r];
      A.lpart[(size_t)(slot * 4 + h) * 4096 + row] = lrun[r];
    }
  }
}

// ---------------------------------------------------------------------------
// Combine k-halves + residual + segment-sum pooling, both dirs per dispatch.
__global__ __launch_bounds__(256) void k_combine_pool(
    const float* __restrict__ Opart, const float* __restrict__ mpart,
    const float* __restrict__ lpart, const float* __restrict__ hm,
    const float* __restrict__ hp, const int* __restrict__ b_mol,
    const int* __restrict__ b_prot, float* __restrict__ z, float* __restrict__ cnt) {
  const int row = blockIdx.x;
  const int dir = blockIdx.y;
  const int c = threadIdx.x;
  const int h = c >> 6;
  const float* Hin = dir ? hp : hm;
  const int g = (dir ? b_prot : b_mol)[row];
  size_t mi0 = (size_t)((dir * 2 + 0) * 4 + h) * 4096 + row;
  size_t mi1 = (size_t)((dir * 2 + 1) * 4 + h) * 4096 + row;
  float m1 = mpart[mi0], m2 = mpart[mi1];
  float l1 = lpart[mi0], l2 = lpart[mi1];
  float M = fmaxf(m1, m2);
  float e1 = __expf(m1 - M), e2 = __expf(m2 - M);
  float L = l1 * e1 + l2 * e2;
  float O1 = Opart[((size_t)(dir * 2 + 0) * 4096 + row) * 256 + c];
  float O2 = Opart[((size_t)(dir * 2 + 1) * 4096 + row) * 256 + c];
  float v = (O1 * e1 + O2 * e2) / L + Hin[(size_t)row * 256 + c];
  atomicAdd(&z[(size_t)g * 512 + dir * 256 + c], v);
  if (c == 0) atomicAdd(&cnt[dir * 32 + g], 1.0f);
}

__global__ __launch_bounds__(256) void k_segdiv(float* __restrict__ z,
                                                const float* __restrict__ cnt) {
  const int idx = blockIdx.x * 256 + threadIdx.x;  // 32*512
  const int g = idx >> 9, c = idx & 511;
  const float cc = cnt[(c < 256) ? g : (32 + g)];
  z[idx] /= fmaxf(cc, 1.0f);
}

__global__ __launch_bounds__(256) void k_fc1(
    const float* __restrict__ z, const float* __restrict__ w,
    const float* __restrict__ b, float* __restrict__ out) {
  const int idx = blockIdx.x * 256 + threadIdx.x;  // 32*256
  const int r = idx >> 8, c = idx & 255;
  float acc = b[c];
  for (int k = 0; k < 512; ++k) acc += z[r * 512 + k] * w[k * HDIM + c];
  out[idx] = fmaxf(acc, 0.f);
}

__global__ __launch_bounds__(64) void k_fc2(
    const float* __restrict__ xin, const float* __restrict__ w,
    const float* __restrict__ b, float* __restrict__ out) {
  const int r = threadIdx.x;
  if (r < NG) {
    float acc = b[0];
    for (int k = 0; k < HDIM; ++k) acc += xin[r * HDIM + k] * w[k];
    out[r] = 1.0f / (1.0f + __expf(-acc));
  }
}

// ---------------------------------------------------------------------------
extern "C" void kernel_launch(void* const* d_in, const int* in_sizes, int n_in,
                              void* d_out, int out_size, void* d_ws, size_t ws_size,
                              hipStream_t stream) {
  const float* x_mol   = (const float*)d_in[0];
  const float* x_prot  = (const float*)d_in[1];
  const float* ea_mol  = (const float*)d_in[2];
  const float* ea_prot = (const float*)d_in[3];
  const int*   ei_mol  = (const int*)d_in[4];
  const int*   ei_prot = (const int*)d_in[5];
  const int*   b_mol   = (const int*)d_in[6];
  const int*   b_prot  = (const int*)d_in[7];
  const float* nlm_w = (const float*)d_in[8];
  const float* nlm_b = (const float*)d_in[9];
  const float* nlp_w = (const float*)d_in[10];
  const float* nlp_b = (const float*)d_in[11];
  const float* elm_w = (const float*)d_in[12];
  const float* elm_b = (const float*)d_in[13];
  const float* elp_w = (const float*)d_in[14];
  const float* elp_b = (const float*)d_in[15];
  const float* mol_w1 = (const float*)d_in[16];
  const float* mol_b1 = (const float*)d_in[17];
  const float* mol_w2 = (const float*)d_in[18];
  const float* mol_b2 = (const float*)d_in[19];
  const float* prot_w1 = (const float*)d_in[20];
  const float* prot_b1 = (const float*)d_in[21];
  const float* prot_w2 = (const float*)d_in[22];
  const float* prot_b2 = (const float*)d_in[23];
  const float* mp_wq = (const float*)d_in[24];
  const float* mp_bq = (const float*)d_in[25];
  const float* mp_wk = (const float*)d_in[26];
  const float* mp_bk = (const float*)d_in[27];
  const float* mp_wv = (const float*)d_in[28];
  const float* mp_bv = (const float*)d_in[29];
  const float* pm_wq = (const float*)d_in[30];
  const float* pm_bq = (const float*)d_in[31];
  const float* pm_wk = (const float*)d_in[32];
  const float* pm_bk = (const float*)d_in[33];
  const float* pm_wv = (const float*)d_in[34];
  const float* pm_bv = (const float*)d_in[35];
  const float* fc1_w = (const float*)d_in[36];
  const float* fc1_b = (const float*)d_in[37];
  const float* fc2_w = (const float*)d_in[38];
  const float* fc2_b = (const float*)d_in[39];
  float* out = (float*)d_out;

  // workspace carve (MB offsets); peak ~88 MB
  char* W8 = (char*)d_ws;
  const size_t MB = 1u << 20;
  float* hm    = (float*)(W8 + 0 * MB);
  float* hp    = (float*)(W8 + 4 * MB);
  float* t1m   = (float*)(W8 + 8 * MB);
  float* aggm  = (float*)(W8 + 12 * MB);
  float* aggp  = (float*)(W8 + 16 * MB);
  _Float16* wtH = (_Float16*)(W8 + 20 * MB);
  _Float16* wtL = (_Float16*)(W8 + 22 * MB);
  _Float16* hmh = (_Float16*)(W8 + 24 * MB);
  _Float16* hml = (_Float16*)(W8 + 26 * MB);
  _Float16* hph = (_Float16*)(W8 + 28 * MB);
  _Float16* hpl = (_Float16*)(W8 + 30 * MB);
  _Float16* Qh0 = (_Float16*)(W8 + 32 * MB);
  _Float16* Ql0 = (_Float16*)(W8 + 34 * MB);
  _Float16* Kh0 = (_Float16*)(W8 + 36 * MB);
  _Float16* Kl0 = (_Float16*)(W8 + 38 * MB);
  _Float16* Qh1 = (_Float16*)(W8 + 40 * MB);
  _Float16* Ql1 = (_Float16*)(W8 + 42 * MB);
  _Float16* Kh1 = (_Float16*)(W8 + 44 * MB);
  _Float16* Kl1 = (_Float16*)(W8 + 46 * MB);
  float* Vb0   = (float*)(W8 + 48 * MB);
  float* Vb1   = (float*)(W8 + 52 * MB);
  _Float16* Vth0 = (_Float16*)(W8 + 56 * MB);
  _Float16* Vtl0 = (_Float16*)(W8 + 58 * MB);
  _Float16* Vth1 = (_Float16*)(W8 + 60 * MB);
  _Float16* Vtl1 = (_Float16*)(W8 + 62 * MB);
  float* Opart = (float*)(W8 + 64 * MB);   // 16 MB: [dir*2+half][4096][256]
  float* mpart = (float*)(W8 + 80 * MB);   // 16*4096 floats
  float* lpart = mpart + 65536;
  float* zb    = lpart + 65536;            // 32*512
  float* cnt   = zb + 32 * 512;            // 64
  float* fch   = cnt + 64;                 // 32*256
  float* t1p   = (float*)(W8 + 82 * MB);
  int* off_m = (int*)(W8 + 86 * MB);
  int* cur_m = off_m + 4224;
  int* eid_m = cur_m + 4224;
  int* off_p = (int*)(W8 + 87 * MB);
  int* cur_p = off_p + 4224;
  int* eid_p = cur_p + 4224;

  // weights: 0,1 mol_w1 | 2,3 mol_w2 | 4,5 prot_w1 | 6,7 prot_w2
  // 8 mp_wq 9 mp_wk 10 mp_wv | 11 pm_wq 12 pm_wk 13 pm_wv
  PtrPack pk;
  pk.p[0] = mol_w1;           pk.p[1] = mol_w1 + 65536;
  pk.p[2] = mol_w2;           pk.p[3] = mol_w2 + 65536;
  pk.p[4] = prot_w1;          pk.p[5] = prot_w1 + 65536;
  pk.p[6] = prot_w2;          pk.p[7] = prot_w2 + 65536;
  pk.p[8] = mp_wq;  pk.p[9] = mp_wk;  pk.p[10] = mp_wv;
  pk.p[11] = pm_wq; pk.p[12] = pm_wk; pk.p[13] = pm_wv;
  k_prep_wt<<<dim3(4, 4, 14), 256, 0, stream>>>(pk, wtH, wtL);

  hipMemsetAsync(cur_m, 0, 4096 * 4, stream);
  hipMemsetAsync(cur_p, 0, 4096 * 4, stream);
  k_csr_count2<<<dim3(NEDGE / 256, 2), 256, 0, stream>>>(ei_mol, ei_prot, cur_m, cur_p, NEDGE);
  k_csr_scan2<<<2, 256, 0, stream>>>(cur_m, off_m, cur_p, off_p, NMOL);
  k_csr_scatter2<<<dim3(NEDGE / 256, 2), 256, 0, stream>>>(ei_mol, ei_prot, cur_m, cur_p,
                                                           eid_m, eid_p, NEDGE);

  EmbJob em = {x_mol, nlm_w, nlm_b, hm, 8};
  EmbJob ep = {x_prot, nlp_w, nlp_b, hp, 4};
  k_node_embed2<<<dim3(NMOL, 2), 256, 0, stream>>>(em, ep);

#define WTH(i) (wtH + (size_t)(i) * 65536)
#define WTL(i) (wtL + (size_t)(i) * 65536)

  AggJob am = {hm, ea_mol, ei_mol, off_m, eid_m, elm_w, elm_b, aggm};
  AggJob ap = {hp, ea_prot, ei_prot, off_p, eid_p, elp_w, elp_b, aggp};

  for (int l = 0; l < 2; ++l) {
    k_agg2<<<dim3(NMOL, 2), 256, 0, stream>>>(am, ap);
    GJobs g1 = {};
    g1.j[0] = {hm, aggm, nullptr, nullptr, WTH(l), WTL(l), mol_b1 + l * 256,
               t1m, nullptr, nullptr, 1.0f, 3};
    g1.j[1] = {hp, aggp, nullptr, nullptr, WTH(4 + l), WTL(4 + l), prot_b1 + l * 256,
               t1p, nullptr, nullptr, 1.0f, 3};
    k_gemm<<<dim3(64, 4, 2), 256, 0, stream>>>(g1);
    GJobs g2 = {};
    int fl = (l == 1) ? (1 | (2 << 4)) : 1;  // last layer: fp32 + split planes
    g2.j[0] = {t1m, nullptr, nullptr, nullptr, WTH(2 + l), WTL(2 + l), mol_b2 + l * 256,
               hm, hmh, hml, 1.0f, fl};
    g2.j[1] = {t1p, nullptr, nullptr, nullptr, WTH(6 + l), WTL(6 + l), prot_b2 + l * 256,
               hp, hph, hpl, 1.0f, fl};
    k_gemm<<<dim3(64, 4, 2), 256, 0, stream>>>(g2);
  }

  // QKV for both attention directions, one dispatch (z=6)
  {
    GJobs q = {};
    q.j[0] = {nullptr, nullptr, hmh, hml, WTH(8), WTL(8), mp_bq,
              nullptr, Qh0, Ql0, 0.125f, 4 | (1 << 4)};
    q.j[1] = {nullptr, nullptr, hph, hpl, WTH(9), WTL(9), mp_bk,
              nullptr, Kh0, Kl0, 1.0f, 4 | (1 << 4)};
    q.j[2] = {nullptr, nullptr, hph, hpl, WTH(10), WTL(10), mp_bv,
              Vb0, nullptr, nullptr, 1.0f, 4};
    q.j[3] = {nullptr, nullptr, hph, hpl, WTH(11), WTL(11), pm_bq,
              nullptr, Qh1, Ql1, 0.125f, 4 | (1 << 4)};
    q.j[4] = {nullptr, nullptr, hmh, hml, WTH(12), WTL(12), pm_bk,
              nullptr, Kh1, Kl1, 1.0f, 4 | (1 << 4)};
    q.j[5] = {nullptr, nullptr, hmh, hml, WTH(13), WTL(13), pm_bv,
              Vb1, nullptr, nullptr, 1.0f, 4};
    k_gemm<<<dim3(64, 4, 6), 256, 0, stream>>>(q);
  }

  k_transpose2<<<dim3(64, 4, 2), 256, 0, stream>>>(Vb0, Vb1, Vth0, Vtl0, Vth1, Vtl1);

  AttnArgs aa;
  aa.Qh[0] = Qh0; aa.Ql[0] = Ql0; aa.Kh[0] = Kh0; aa.Kl[0] = Kl0;
  aa.Vth[0] = Vth0; aa.Vtl[0] = Vtl0;
  aa.Qh[1] = Qh1; aa.Ql[1] = Ql1; aa.Kh[1] = Kh1; aa.Kl[1] = Kl1;
  aa.Vth[1] = Vth1; aa.Vtl[1] = Vtl1;
  aa.Opart = Opart; aa.mpart = mpart; aa.lpart = lpart;
  k_attn3<<<dim3(64, 8, 2), 256, 0, stream>>>(aa, 2048);

  hipMemsetAsync(zb, 0, (32 * 512 + 64) * 4, stream);
  k_combine_pool<<<dim3(4096, 2), 256, 0, stream>>>(Opart, mpart, lpart, hm, hp,
                                                    b_mol, b_prot, zb, cnt);
  k_segdiv<<<64, 256, 0, stream>>>(zb, cnt);
  k_fc1<<<32, 256, 0, stream>>>(zb, fc1_w, fc1_b, fch);
  k_fc2<<<1, 64, 0, stream>>>(fch, fc2_w, fc2_b, out);
#undef WTH
#undef WTL
}

// Round 8
// 545.951 us; speedup vs baseline: 4.0981x; 1.2788x over previous
//
#include <hip/hip_runtime.h>
#include <math.h>

#define HDIM 256
#define NMOL 4096
#define NPROT 4096
#define NEDGE 65536
#define NG 32

typedef _Float16 f16x8 __attribute__((ext_vector_type(8)));
typedef _Float16 f16x4 __attribute__((ext_vector_type(4)));
typedef __attribute__((ext_vector_type(4))) float f32x4;

__device__ __forceinline__ void splitf(float x, _Float16& h, _Float16& l) {
  h = (_Float16)x;
  l = (_Float16)(x - (float)h);
}

// ---------------------------------------------------------------------------
// Transpose + convert 14 H x H fp32 weights into split f16 planes Wt[n][k].
struct PtrPack { const float* p[14]; };

__global__ __launch_bounds__(256) void k_prep_wt(PtrPack pk, _Float16* __restrict__ dh,
                                                 _Float16* __restrict__ dl) {
  __shared__ float Ts[64][68];
  const int m = blockIdx.z;
  const int n0 = blockIdx.y * 64, k0 = blockIdx.x * 64;
  const float* W = pk.p[m];
  const int t = threadIdx.x;
#pragma unroll
  for (int rep = 0; rep < 16; ++rep) {
    int k = rep * 4 + (t >> 6);
    int n = t & 63;
    Ts[n][k] = W[(size_t)(k0 + k) * 256 + n0 + n];
  }
  __syncthreads();
#pragma unroll
  for (int rep = 0; rep < 2; ++rep) {
    int idx = t + rep * 256;
    int nr = idx >> 3, koff = (idx & 7) * 8;
    f16x8 vh, vl;
#pragma unroll
    for (int i = 0; i < 8; ++i) {
      _Float16 h, l;
      splitf(Ts[nr][koff + i], h, l);
      vh[i] = h; vl[i] = l;
    }
    size_t off = (size_t)m * 65536 + (size_t)(n0 + nr) * 256 + k0 + koff;
    *(f16x8*)&dh[off] = vh;
    *(f16x8*)&dl[off] = vl;
  }
}

// ---------------------------------------------------------------------------
// node embedding (fp32 out), both graphs in one dispatch (blockIdx.y)
struct EmbJob { const float* x; const float* w; const float* b; float* out; int K; };

__global__ __launch_bounds__(256) void k_node_embed2(EmbJob j0, EmbJob j1) {
  const EmbJob& j = blockIdx.y ? j1 : j0;
  const int i = blockIdx.x;
  const int c = threadIdx.x;
  float acc = j.b[c];
  for (int k = 0; k < j.K; ++k) acc += j.x[i * j.K + k] * j.w[k * HDIM + c];
  j.out[(size_t)i * HDIM + c] = acc;
}

// ---------------------------------------------------------------------------
// CSR build (both graphs per dispatch)
__global__ __launch_bounds__(256) void k_csr_count2(const int* __restrict__ ei0,
                                                    const int* __restrict__ ei1,
                                                    int* __restrict__ cur0,
                                                    int* __restrict__ cur1, int E) {
  const int* ei = blockIdx.y ? ei1 : ei0;
  int* cur = blockIdx.y ? cur1 : cur0;
  const int e = blockIdx.x * 256 + threadIdx.x;
  if (e < E) atomicAdd(&cur[ei[E + e]], 1);
}

__global__ __launch_bounds__(256) void k_csr_scan2(int* __restrict__ c0, int* __restrict__ o0,
                                                   int* __restrict__ c1, int* __restrict__ o1,
                                                   int N) {
  int* cnt_cur = blockIdx.x ? c1 : c0;
  int* off = blockIdx.x ? o1 : o0;
  __shared__ int tsum[256], tpre[257];
  const int t = threadIdx.x;
  const int base = t * 16;
  int loc[16], s = 0;
#pragma unroll
  for (int i = 0; i < 16; ++i) { loc[i] = cnt_cur[base + i]; s += loc[i]; }
  tsum[t] = s;
  __syncthreads();
  if (t == 0) {
    int a = 0;
    for (int i = 0; i < 256; ++i) { tpre[i] = a; a += tsum[i]; }
    tpre[256] = a;
  }
  __syncthreads();
  int a = tpre[t];
#pragma unroll
  for (int i = 0; i < 16; ++i) {
    off[base + i] = a;
    cnt_cur[base + i] = a;
    a += loc[i];
  }
  if (t == 255) off[N] = tpre[256];
}

__global__ __launch_bounds__(256) void k_csr_scatter2(const int* __restrict__ ei0,
                                                      const int* __restrict__ ei1,
                                                      int* __restrict__ cur0,
                                                      int* __restrict__ cur1,
                                                      int* __restrict__ eid0,
                                                      int* __restrict__ eid1, int E) {
  const int* ei = blockIdx.y ? ei1 : ei0;
  int* cur = blockIdx.y ? cur1 : cur0;
  int* eid = blockIdx.y ? eid1 : eid0;
  const int e = blockIdx.x * 256 + threadIdx.x;
  if (e < E) {
    int pos = atomicAdd(&cur[ei[E + e]], 1);
    eid[pos] = e;
  }
}

// ---------------------------------------------------------------------------
// GINE aggregation via CSR gather, both graphs per dispatch
struct AggJob {
  const float* x; const float* ea; const int* eis; const int* off;
  const int* eid; const float* we; const float* be; float* agg;
};

__global__ __launch_bounds__(256) void k_agg2(AggJob a0, AggJob a1) {
  const AggJob& a = blockIdx.y ? a1 : a0;
  const int n = blockIdx.x;
  const int c = threadIdx.x;
  const float w0 = a.we[c], w1 = a.we[HDIM + c], bb = a.be[c];
  const int j0 = a.off[n], j1 = a.off[n + 1];
  float sum = 0.f;
  for (int j = j0; j < j1; ++j) {
    int e = a.eid[j];
    int src = a.eis[e];
    float e0 = a.ea[2 * e], e1 = a.ea[2 * e + 1];
    float m = a.x[(size_t)src * HDIM + c] + e0 * w0 + e1 * w1 + bb;
    sum += fmaxf(m, 0.f);
  }
  a.agg[(size_t)n * HDIM + c] = sum;
}

// ---------------------------------------------------------------------------
// Unified split-f16 MFMA GEMM, K=256, job table indexed by blockIdx.z.
// flags: 1=relu, 2=hasA2, 4=presplit A; outmode=flags>>4:
//   0 = fp32 C; 1 = split f16 planes (scaled); 2 = fp32 C AND split planes.
struct GJob {
  const float* A1; const float* A2;
  const _Float16* Ah; const _Float16* Al;
  const _Float16* Bh; const _Float16* Bl;
  const float* bias; float* C;
  _Float16* Ch; _Float16* Cl;
  float oscale; int flags;
};
struct GJobs { GJob j[6]; };

__global__ __launch_bounds__(256) void k_gemm(GJobs js) {
  const GJob J = js.j[blockIdx.z];
  const int relu = J.flags & 1, hasa2 = J.flags & 2, presplit = J.flags & 4;
  const int outmode = J.flags >> 4;
  __shared__ _Float16 Ah[64][72], Al[64][72], Bh[64][72], Bl[64][72];
  const int t = threadIdx.x;
  const int bm = blockIdx.x * 64, bn = blockIdx.y * 64;
  const int lane = t & 63, w = t >> 6;
  const int l15 = lane & 15, l4 = lane >> 4;
  const int wm = (w >> 1) * 32, wn = (w & 1) * 32;
  f32x4 acc[2][2] = {};
  for (int k0 = 0; k0 < 256; k0 += 64) {
    __syncthreads();
    if (presplit) {
#pragma unroll
      for (int rep = 0; rep < 2; ++rep) {
        int idx = t + rep * 256;
        int r = idx >> 3, k8 = (idx & 7) * 8;
        size_t off = (size_t)(bm + r) * 256 + k0 + k8;
        *(f16x8*)&Ah[r][k8] = *(const f16x8*)&J.Ah[off];
        *(f16x8*)&Al[r][k8] = *(const f16x8*)&J.Al[off];
      }
    } else {
#pragma unroll
      for (int rep = 0; rep < 4; ++rep) {
        int idx = t + rep * 256;
        int r = idx >> 4, c4 = (idx & 15) * 4;
        float4 a = *(const float4*)&J.A1[(size_t)(bm + r) * 256 + k0 + c4];
        if (hasa2) {
          float4 a2 = *(const float4*)&J.A2[(size_t)(bm + r) * 256 + k0 + c4];
          a.x += a2.x; a.y += a2.y; a.z += a2.z; a.w += a2.w;
        }
        float av[4] = {a.x, a.y, a.z, a.w};
#pragma unroll
        for (int i = 0; i < 4; ++i) splitf(av[i], Ah[r][c4 + i], Al[r][c4 + i]);
      }
    }
#pragma unroll
    for (int rep = 0; rep < 2; ++rep) {
      int idx = t + rep * 256;
      int nr = idx >> 3, koff = (idx & 7) * 8;
      size_t off = (size_t)(bn + nr) * 256 + k0 + koff;
      *(f16x8*)&Bh[nr][koff] = *(const f16x8*)&J.Bh[off];
      *(f16x8*)&Bl[nr][koff] = *(const f16x8*)&J.Bl[off];
    }
    __syncthreads();
#pragma unroll
    for (int kh = 0; kh < 2; ++kh) {
      f16x8 a0h = *(f16x8*)&Ah[wm + l15][kh * 32 + l4 * 8];
      f16x8 a0l = *(f16x8*)&Al[wm + l15][kh * 32 + l4 * 8];
      f16x8 a1h = *(f16x8*)&Ah[wm + 16 + l15][kh * 32 + l4 * 8];
      f16x8 a1l = *(f16x8*)&Al[wm + 16 + l15][kh * 32 + l4 * 8];
      f16x8 b0h = *(f16x8*)&Bh[wn + l15][kh * 32 + l4 * 8];
      f16x8 b0l = *(f16x8*)&Bl[wn + l15][kh * 32 + l4 * 8];
      f16x8 b1h = *(f16x8*)&Bh[wn + 16 + l15][kh * 32 + l4 * 8];
      f16x8 b1l = *(f16x8*)&Bl[wn + 16 + l15][kh * 32 + l4 * 8];
      acc[0][0] = __builtin_amdgcn_mfma_f32_16x16x32_f16(a0h, b0h, acc[0][0], 0, 0, 0);
      acc[0][0] = __builtin_amdgcn_mfma_f32_16x16x32_f16(a0h, b0l, acc[0][0], 0, 0, 0);
      acc[0][0] = __builtin_amdgcn_mfma_f32_16x16x32_f16(a0l, b0h, acc[0][0], 0, 0, 0);
      acc[0][1] = __builtin_amdgcn_mfma_f32_16x16x32_f16(a0h, b1h, acc[0][1], 0, 0, 0);
      acc[0][1] = __builtin_amdgcn_mfma_f32_16x16x32_f16(a0h, b1l, acc[0][1], 0, 0, 0);
      acc[0][1] = __builtin_amdgcn_mfma_f32_16x16x32_f16(a0l, b1h, acc[0][1], 0, 0, 0);
      acc[1][0] = __builtin_amdgcn_mfma_f32_16x16x32_f16(a1h, b0h, acc[1][0], 0, 0, 0);
      acc[1][0] = __builtin_amdgcn_mfma_f32_16x16x32_f16(a1h, b0l, acc[1][0], 0, 0, 0);
      acc[1][0] = __builtin_amdgcn_mfma_f32_16x16x32_f16(a1l, b0h, acc[1][0], 0, 0, 0);
      acc[1][1] = __builtin_amdgcn_mfma_f32_16x16x32_f16(a1h, b1h, acc[1][1], 0, 0, 0);
      acc[1][1] = __builtin_amdgcn_mfma_f32_16x16x32_f16(a1h, b1l, acc[1][1], 0, 0, 0);
      acc[1][1] = __builtin_amdgcn_mfma_f32_16x16x32_f16(a1l, b1h, acc[1][1], 0, 0, 0);
    }
  }
#pragma unroll
  for (int mi = 0; mi < 2; ++mi)
#pragma unroll
    for (int ni = 0; ni < 2; ++ni) {
      int col = bn + wn + ni * 16 + l15;
      float bv = J.bias[col];
#pragma unroll
      for (int r = 0; r < 4; ++r) {
        int row = bm + wm + mi * 16 + l4 * 4 + r;
        float v = acc[mi][ni][r] + bv;
        if (relu) v = fmaxf(v, 0.f);
        if (outmode != 1) J.C[(size_t)row * 256 + col] = v;
        if (outmode != 0) {
          float vs = v * J.oscale;
          _Float16 hh, ll;
          splitf(vs, hh, ll);
          J.Ch[(size_t)row * 256 + col] = hh;
          J.Cl[(size_t)row * 256 + col] = ll;
        }
      }
    }
}

// ---------------------------------------------------------------------------
// Transpose V (hi plane only): fp32 [4096][256] -> f16 [256][4096]
__global__ __launch_bounds__(256) void k_transpose2(
    const float* __restrict__ V0, const float* __restrict__ V1,
    _Float16* __restrict__ Th0, _Float16* __restrict__ Th1) {
  __shared__ float Ts[64][65];
  const int dir = blockIdx.z;
  const float* V = dir ? V1 : V0;
  _Float16* Th = dir ? Th1 : Th0;
  const int r0 = blockIdx.x * 64, c0 = blockIdx.y * 64;
  const int t = threadIdx.x;
#pragma unroll
  for (int rep = 0; rep < 16; ++rep) {
    int idx = rep * 256 + t;
    int r = idx >> 6, c = idx & 63;
    Ts[r][c] = V[(size_t)(r0 + r) * 256 + c0 + c];
  }
  __syncthreads();
#pragma unroll
  for (int rep = 0; rep < 2; ++rep) {
    int idx = rep * 256 + t;
    int c = idx >> 3, r8 = (idx & 7) * 8;
    f16x8 vh;
#pragma unroll
    for (int i = 0; i < 8; ++i) vh[i] = (_Float16)Ts[r8 + i][c];
    *(f16x8*)&Th[(size_t)(c0 + c) * 4096 + r0 + r8] = vh;
  }
}

// ---------------------------------------------------------------------------
// Swapped-QK flash attention: S^T = mfma(A=K, B=Q) so each lane owns one
// q-row (q = lane&15) -> softmax is in-lane tree + 2 shfl_xor; P packs into
// 4x ds_write_b64. V-lo dropped in PV (2^-11 relative, validated scale).
// LDS 36.9 KB -> 4 blocks/CU. Grid (64 q-tiles, dir*4+head, 2 k-halves).
struct AttnArgs {
  const _Float16* Qh[2]; const _Float16* Ql[2];
  const _Float16* Kh[2]; const _Float16* Kl[2];
  const _Float16* Vth[2];
  float* Opart; float* mpart; float* lpart;
};

__global__ __launch_bounds__(256) void k_attn4(AttnArgs A, int nk_half) {
  __shared__ _Float16 Ksh[64][72], Ksl[64][72];  // [k][d]
  __shared__ _Float16 Vsh[64][72];               // [d][k], chunk-swizzled, hi only
  __shared__ _Float16 Psh[4][16][72];            // per-wave P [q][k]
  const int t = threadIdx.x;
  const int dir = blockIdx.y >> 2, h = blockIdx.y & 3;
  const int q0 = blockIdx.x * 64;
  const int half = blockIdx.z;
  const int kbase = half * nk_half;
  const int lane = t & 63, w = t >> 6;
  const int l15 = lane & 15, l4 = lane >> 4;

  const _Float16* Qh_g = A.Qh[dir];
  const _Float16* Ql_g = A.Ql[dir];
  const _Float16* Kh_g = A.Kh[dir];
  const _Float16* Kl_g = A.Kl[dir];
  const _Float16* Vth_g = A.Vth[dir];

  // Q B-frag: lane holds Q[q = q0+w*16+l15][d = kh*32 + l4*8 + j]
  f16x8 qh[2], ql[2];
  {
    size_t qoff = (size_t)(q0 + w * 16 + l15) * 256 + h * 64;
#pragma unroll
    for (int kh = 0; kh < 2; ++kh) {
      qh[kh] = *(const f16x8*)&Qh_g[qoff + kh * 32 + l4 * 8];
      ql[kh] = *(const f16x8*)&Ql_g[qoff + kh * 32 + l4 * 8];
    }
  }
  f32x4 o[4] = {};            // o[oc][r] = O[q = w*16+4*l4+r][d = oc*16+l15]
  float mrun = -1e30f;        // softmax state for q = q0 + w*16 + l15 (per lane)
  float lrun = 0.f;

  for (int kt = 0; kt < nk_half; kt += 64) {
    const int k0 = kbase + kt;
    __syncthreads();
#pragma unroll
    for (int rep = 0; rep < 2; ++rep) {
      int idx = t + rep * 256;
      int r = idx >> 3, c8 = idx & 7;
      size_t koff = (size_t)(k0 + r) * 256 + h * 64 + c8 * 8;
      *(f16x8*)&Ksh[r][c8 * 8] = *(const f16x8*)&Kh_g[koff];
      *(f16x8*)&Ksl[r][c8 * 8] = *(const f16x8*)&Kl_g[koff];
      int sc = c8 ^ ((r >> 3) & 7);
      size_t voff = (size_t)(h * 64 + r) * 4096 + k0 + c8 * 8;
      *(f16x8*)&Vsh[r][sc * 8] = *(const f16x8*)&Vth_g[voff];
    }
    __syncthreads();

    // S^T: lane gets sf[kc][r] = S[q = l15][k = kc*16 + 4*l4 + r]
    f32x4 sf[4] = {};
#pragma unroll
    for (int kc = 0; kc < 4; ++kc) {
      f16x8 kf0h = *(f16x8*)&Ksh[kc * 16 + l15][l4 * 8];
      f16x8 kf0l = *(f16x8*)&Ksl[kc * 16 + l15][l4 * 8];
      f16x8 kf1h = *(f16x8*)&Ksh[kc * 16 + l15][32 + l4 * 8];
      f16x8 kf1l = *(f16x8*)&Ksl[kc * 16 + l15][32 + l4 * 8];
      sf[kc] = __builtin_amdgcn_mfma_f32_16x16x32_f16(kf0h, qh[0], sf[kc], 0, 0, 0);
      sf[kc] = __builtin_amdgcn_mfma_f32_16x16x32_f16(kf0h, ql[0], sf[kc], 0, 0, 0);
      sf[kc] = __builtin_amdgcn_mfma_f32_16x16x32_f16(kf0l, qh[0], sf[kc], 0, 0, 0);
      sf[kc] = __builtin_amdgcn_mfma_f32_16x16x32_f16(kf1h, qh[1], sf[kc], 0, 0, 0);
      sf[kc] = __builtin_amdgcn_mfma_f32_16x16x32_f16(kf1h, ql[1], sf[kc], 0, 0, 0);
      sf[kc] = __builtin_amdgcn_mfma_f32_16x16x32_f16(kf1l, qh[1], sf[kc], 0, 0, 0);
    }

    // online softmax for q = l15: in-lane tree + cross-l4 shfl (lanes l15+16k)
    float mt = -1e30f;
#pragma unroll
    for (int kc = 0; kc < 4; ++kc) {
      float a = fmaxf(fmaxf(sf[kc][0], sf[kc][1]), fmaxf(sf[kc][2], sf[kc][3]));
      mt = fmaxf(mt, a);
    }
    mt = fmaxf(mt, __shfl_xor(mt, 16, 64));
    mt = fmaxf(mt, __shfl_xor(mt, 32, 64));
    float mn = fmaxf(mrun, mt);
    float alpha = __expf(mrun - mn);
    mrun = mn;
    float rs = 0.f;
    _Float16 pf[4][4];
#pragma unroll
    for (int kc = 0; kc < 4; ++kc)
#pragma unroll
      for (int r = 0; r < 4; ++r) {
        float pv = __expf(sf[kc][r] - mn);
        rs += pv;
        pf[kc][r] = (_Float16)pv;
      }
    rs += __shfl_xor(rs, 16, 64);
    rs += __shfl_xor(rs, 32, 64);
    lrun = lrun * alpha + rs;

    // rescale O: alpha for row q' = 4*l4 + r lives at lane q'
#pragma unroll
    for (int r = 0; r < 4; ++r) {
      float ar = __shfl(alpha, 4 * l4 + r, 64);
      o[0][r] *= ar; o[1][r] *= ar; o[2][r] *= ar; o[3][r] *= ar;
    }

    // store P: lane q=l15 writes k = kc*16 + 4*l4 + {0..3} as one b64
#pragma unroll
    for (int kc = 0; kc < 4; ++kc) {
      f16x4 pv = {pf[kc][0], pf[kc][1], pf[kc][2], pf[kc][3]};
      *(f16x4*)&Psh[w][l15][kc * 16 + 4 * l4] = pv;
    }

    // O += P @ V (same-wave P write->read; V hi only)
#pragma unroll
    for (int kh = 0; kh < 2; ++kh) {
      f16x8 pa = *(f16x8*)&Psh[w][l15][kh * 32 + l4 * 8];
#pragma unroll
      for (int oc = 0; oc < 4; ++oc) {
        int d = oc * 16 + l15;
        int chunk = (kh * 4 + l4) ^ ((d >> 3) & 7);
        f16x8 vb = *(f16x8*)&Vsh[d][chunk * 8];
        o[oc] = __builtin_amdgcn_mfma_f32_16x16x32_f16(pa, vb, o[oc], 0, 0, 0);
      }
    }
  }

  const int slot = dir * 2 + half;
#pragma unroll
  for (int oc = 0; oc < 4; ++oc) {
    int col = h * 64 + oc * 16 + l15;
#pragma unroll
    for (int r = 0; r < 4; ++r) {
      int row = q0 + w * 16 + 4 * l4 + r;
      A.Opart[((size_t)slot * 4096 + row) * 256 + col] = o[oc][r];
    }
  }
  if (lane < 16) {
    int row = q0 + w * 16 + l15;
    A.mpart[(size_t)(slot * 4 + h) * 4096 + row] = mrun;
    A.lpart[(size_t)(slot * 4 + h) * 4096 + row] = lrun;
  }
}

// ---------------------------------------------------------------------------
// Combine k-halves + residual + segment-sum pooling, both dirs per dispatch.
__global__ __launch_bounds__(256) void k_combine_pool(
    const float* __restrict__ Opart, const float* __restrict__ mpart,
    const float* __restrict__ lpart, const float* __restrict__ hm,
    const float* __restrict__ hp, const int* __restrict__ b_mol,
    const int* __restrict__ b_prot, float* __restrict__ z, float* __restrict__ cnt) {
  const int row = blockIdx.x;
  const int dir = blockIdx.y;
  const int c = threadIdx.x;
  const int h = c >> 6;
  const float* Hin = dir ? hp : hm;
  const int g = (dir ? b_prot : b_mol)[row];
  size_t mi0 = (size_t)((dir * 2 + 0) * 4 + h) * 4096 + row;
  size_t mi1 = (size_t)((dir * 2 + 1) * 4 + h) * 4096 + row;
  float m1 = mpart[mi0], m2 = mpart[mi1];
  float l1 = lpart[mi0], l2 = lpart[mi1];
  float M = fmaxf(m1, m2);
  float e1 = __expf(m1 - M), e2 = __expf(m2 - M);
  float L = l1 * e1 + l2 * e2;
  float O1 = Opart[((size_t)(dir * 2 + 0) * 4096 + row) * 256 + c];
  float O2 = Opart[((size_t)(dir * 2 + 1) * 4096 + row) * 256 + c];
  float v = (O1 * e1 + O2 * e2) / L + Hin[(size_t)row * 256 + c];
  atomicAdd(&z[(size_t)g * 512 + dir * 256 + c], v);
  if (c == 0) atomicAdd(&cnt[dir * 32 + g], 1.0f);
}

__global__ __launch_bounds__(256) void k_segdiv(float* __restrict__ z,
                                                const float* __restrict__ cnt) {
  const int idx = blockIdx.x * 256 + threadIdx.x;  // 32*512
  const int g = idx >> 9, c = idx & 511;
  const float cc = cnt[(c < 256) ? g : (32 + g)];
  z[idx] /= fmaxf(cc, 1.0f);
}

__global__ __launch_bounds__(256) void k_fc1(
    const float* __restrict__ z, const float* __restrict__ w,
    const float* __restrict__ b, float* __restrict__ out) {
  const int idx = blockIdx.x * 256 + threadIdx.x;  // 32*256
  const int r = idx >> 8, c = idx & 255;
  float acc = b[c];
  for (int k = 0; k < 512; ++k) acc += z[r * 512 + k] * w[k * HDIM + c];
  out[idx] = fmaxf(acc, 0.f);
}

__global__ __launch_bounds__(64) void k_fc2(
    const float* __restrict__ xin, const float* __restrict__ w,
    const float* __restrict__ b, float* __restrict__ out) {
  const int r = threadIdx.x;
  if (r < NG) {
    float acc = b[0];
    for (int k = 0; k < HDIM; ++k) acc += xin[r * HDIM + k] * w[k];
    out[r] = 1.0f / (1.0f + __expf(-acc));
  }
}

// ---------------------------------------------------------------------------
extern "C" void kernel_launch(void* const* d_in, const int* in_sizes, int n_in,
                              void* d_out, int out_size, void* d_ws, size_t ws_size,
                              hipStream_t stream) {
  const float* x_mol   = (const float*)d_in[0];
  const float* x_prot  = (const float*)d_in[1];
  const float* ea_mol  = (const float*)d_in[2];
  const float* ea_prot = (const float*)d_in[3];
  const int*   ei_mol  = (const int*)d_in[4];
  const int*   ei_prot = (const int*)d_in[5];
  const int*   b_mol   = (const int*)d_in[6];
  const int*   b_prot  = (const int*)d_in[7];
  const float* nlm_w = (const float*)d_in[8];
  const float* nlm_b = (const float*)d_in[9];
  const float* nlp_w = (const float*)d_in[10];
  const float* nlp_b = (const float*)d_in[11];
  const float* elm_w = (const float*)d_in[12];
  const float* elm_b = (const float*)d_in[13];
  const float* elp_w = (const float*)d_in[14];
  const float* elp_b = (const float*)d_in[15];
  const float* mol_w1 = (const float*)d_in[16];
  const float* mol_b1 = (const float*)d_in[17];
  const float* mol_w2 = (const float*)d_in[18];
  const float* mol_b2 = (const float*)d_in[19];
  const float* prot_w1 = (const float*)d_in[20];
  const float* prot_b1 = (const float*)d_in[21];
  const float* prot_w2 = (const float*)d_in[22];
  const float* prot_b2 = (const float*)d_in[23];
  const float* mp_wq = (const float*)d_in[24];
  const float* mp_bq = (const float*)d_in[25];
  const float* mp_wk = (const float*)d_in[26];
  const float* mp_bk = (const float*)d_in[27];
  const float* mp_wv = (const float*)d_in[28];
  const float* mp_bv = (const float*)d_in[29];
  const float* pm_wq = (const float*)d_in[30];
  const float* pm_bq = (const float*)d_in[31];
  const float* pm_wk = (const float*)d_in[32];
  const float* pm_bk = (const float*)d_in[33];
  const float* pm_wv = (const float*)d_in[34];
  const float* pm_bv = (const float*)d_in[35];
  const float* fc1_w = (const float*)d_in[36];
  const float* fc1_b = (const float*)d_in[37];
  const float* fc2_w = (const float*)d_in[38];
  const float* fc2_b = (const float*)d_in[39];
  float* out = (float*)d_out;

  // workspace carve (MB offsets); peak ~88 MB
  char* W8 = (char*)d_ws;
  const size_t MB = 1u << 20;
  float* hm    = (float*)(W8 + 0 * MB);
  float* hp    = (float*)(W8 + 4 * MB);
  float* t1m   = (float*)(W8 + 8 * MB);
  float* aggm  = (float*)(W8 + 12 * MB);
  float* aggp  = (float*)(W8 + 16 * MB);
  _Float16* wtH = (_Float16*)(W8 + 20 * MB);
  _Float16* wtL = (_Float16*)(W8 + 22 * MB);
  _Float16* hmh = (_Float16*)(W8 + 24 * MB);
  _Float16* hml = (_Float16*)(W8 + 26 * MB);
  _Float16* hph = (_Float16*)(W8 + 28 * MB);
  _Float16* hpl = (_Float16*)(W8 + 30 * MB);
  _Float16* Qh0 = (_Float16*)(W8 + 32 * MB);
  _Float16* Ql0 = (_Float16*)(W8 + 34 * MB);
  _Float16* Kh0 = (_Float16*)(W8 + 36 * MB);
  _Float16* Kl0 = (_Float16*)(W8 + 38 * MB);
  _Float16* Qh1 = (_Float16*)(W8 + 40 * MB);
  _Float16* Ql1 = (_Float16*)(W8 + 42 * MB);
  _Float16* Kh1 = (_Float16*)(W8 + 44 * MB);
  _Float16* Kl1 = (_Float16*)(W8 + 46 * MB);
  float* Vb0   = (float*)(W8 + 48 * MB);
  float* Vb1   = (float*)(W8 + 52 * MB);
  _Float16* Vth0 = (_Float16*)(W8 + 56 * MB);
  _Float16* Vth1 = (_Float16*)(W8 + 60 * MB);
  float* Opart = (float*)(W8 + 64 * MB);   // 16 MB: [dir*2+half][4096][256]
  float* mpart = (float*)(W8 + 80 * MB);   // 16*4096 floats
  float* lpart = mpart + 65536;
  float* zb    = lpart + 65536;            // 32*512
  float* cnt   = zb + 32 * 512;            // 64
  float* fch   = cnt + 64;                 // 32*256
  float* t1p   = (float*)(W8 + 82 * MB);
  int* off_m = (int*)(W8 + 86 * MB);
  int* cur_m = off_m + 4224;
  int* eid_m = cur_m + 4224;
  int* off_p = (int*)(W8 + 87 * MB);
  int* cur_p = off_p + 4224;
  int* eid_p = cur_p + 4224;

  // weights: 0,1 mol_w1 | 2,3 mol_w2 | 4,5 prot_w1 | 6,7 prot_w2
  // 8 mp_wq 9 mp_wk 10 mp_wv | 11 pm_wq 12 pm_wk 13 pm_wv
  PtrPack pk;
  pk.p[0] = mol_w1;           pk.p[1] = mol_w1 + 65536;
  pk.p[2] = mol_w2;           pk.p[3] = mol_w2 + 65536;
  pk.p[4] = prot_w1;          pk.p[5] = prot_w1 + 65536;
  pk.p[6] = prot_w2;          pk.p[7] = prot_w2 + 65536;
  pk.p[8] = mp_wq;  pk.p[9] = mp_wk;  pk.p[10] = mp_wv;
  pk.p[11] = pm_wq; pk.p[12] = pm_wk; pk.p[13] = pm_wv;
  k_prep_wt<<<dim3(4, 4, 14), 256, 0, stream>>>(pk, wtH, wtL);

  hipMemsetAsync(cur_m, 0, 4096 * 4, stream);
  hipMemsetAsync(cur_p, 0, 4096 * 4, stream);
  k_csr_count2<<<dim3(NEDGE / 256, 2), 256, 0, stream>>>(ei_mol, ei_prot, cur_m, cur_p, NEDGE);
  k_csr_scan2<<<2, 256, 0, stream>>>(cur_m, off_m, cur_p, off_p, NMOL);
  k_csr_scatter2<<<dim3(NEDGE / 256, 2), 256, 0, stream>>>(ei_mol, ei_prot, cur_m, cur_p,
                                                           eid_m, eid_p, NEDGE);

  EmbJob em = {x_mol, nlm_w, nlm_b, hm, 8};
  EmbJob ep = {x_prot, nlp_w, nlp_b, hp, 4};
  k_node_embed2<<<dim3(NMOL, 2), 256, 0, stream>>>(em, ep);

#define WTH(i) (wtH + (size_t)(i) * 65536)
#define WTL(i) (wtL + (size_t)(i) * 65536)

  AggJob am = {hm, ea_mol, ei_mol, off_m, eid_m, elm_w, elm_b, aggm};
  AggJob ap = {hp, ea_prot, ei_prot, off_p, eid_p, elp_w, elp_b, aggp};

  for (int l = 0; l < 2; ++l) {
    k_agg2<<<dim3(NMOL, 2), 256, 0, stream>>>(am, ap);
    GJobs g1 = {};
    g1.j[0] = {hm, aggm, nullptr, nullptr, WTH(l), WTL(l), mol_b1 + l * 256,
               t1m, nullptr, nullptr, 1.0f, 3};
    g1.j[1] = {hp, aggp, nullptr, nullptr, WTH(4 + l), WTL(4 + l), prot_b1 + l * 256,
               t1p, nullptr, nullptr, 1.0f, 3};
    k_gemm<<<dim3(64, 4, 2), 256, 0, stream>>>(g1);
    GJobs g2 = {};
    int fl = (l == 1) ? (1 | (2 << 4)) : 1;  // last layer: fp32 + split planes
    g2.j[0] = {t1m, nullptr, nullptr, nullptr, WTH(2 + l), WTL(2 + l), mol_b2 + l * 256,
               hm, hmh, hml, 1.0f, fl};
    g2.j[1] = {t1p, nullptr, nullptr, nullptr, WTH(6 + l), WTL(6 + l), prot_b2 + l * 256,
               hp, hph, hpl, 1.0f, fl};
    k_gemm<<<dim3(64, 4, 2), 256, 0, stream>>>(g2);
  }

  // QKV for both attention directions, one dispatch (z=6)
  {
    GJobs q = {};
    q.j[0] = {nullptr, nullptr, hmh, hml, WTH(8), WTL(8), mp_bq,
              nullptr, Qh0, Ql0, 0.125f, 4 | (1 << 4)};
    q.j[1] = {nullptr, nullptr, hph, hpl, WTH(9), WTL(9), mp_bk,
              nullptr, Kh0, Kl0, 1.0f, 4 | (1 << 4)};
    q.j[2] = {nullptr, nullptr, hph, hpl, WTH(10), WTL(10), mp_bv,
              Vb0, nullptr, nullptr, 1.0f, 4};
    q.j[3] = {nullptr, nullptr, hph, hpl, WTH(11), WTL(11), pm_bq,
              nullptr, Qh1, Ql1, 0.125f, 4 | (1 << 4)};
    q.j[4] = {nullptr, nullptr, hmh, hml, WTH(12), WTL(12), pm_bk,
              nullptr, Kh1, Kl1, 1.0f, 4 | (1 << 4)};
    q.j[5] = {nullptr, nullptr, hmh, hml, WTH(13), WTL(13), pm_bv,
              Vb1, nullptr, nullptr, 1.0f, 4};
    k_gemm<<<dim3(64, 4, 6), 256, 0, stream>>>(q);
  }

  k_transpose2<<<dim3(64, 4, 2), 256, 0, stream>>>(Vb0, Vb1, Vth0, Vth1);

  AttnArgs aa;
  aa.Qh[0] = Qh0; aa.Ql[0] = Ql0; aa.Kh[0] = Kh0; aa.Kl[0] = Kl0; aa.Vth[0] = Vth0;
  aa.Qh[1] = Qh1; aa.Ql[1] = Ql1; aa.Kh[1] = Kh1; aa.Kl[1] = Kl1; aa.Vth[1] = Vth1;
  aa.Opart = Opart; aa.mpart = mpart; aa.lpart = lpart;
  k_attn4<<<dim3(64, 8, 2), 256, 0, stream>>>(aa, 2048);

  hipMemsetAsync(zb, 0, (32 * 512 + 64) * 4, stream);
  k_combine_pool<<<dim3(4096, 2), 256, 0, stream>>>(Opart, mpart, lpart, hm, hp,
                                                    b_mol, b_prot, zb, cnt);
  k_segdiv<<<64, 256, 0, stream>>>(zb, cnt);
  k_fc1<<<32, 256, 0, stream>>>(zb, fc1_w, fc1_b, fch);
  k_fc2<<<1, 64, 0, stream>>>(fch, fc2_w, fc2_b, out);
#undef WTH
#undef WTL
}

// Round 9
// 535.156 us; speedup vs baseline: 4.1807x; 1.0202x over previous
//
#include <hip/hip_runtime.h>
#include <math.h>

#define HDIM 256
#define NMOL 4096
#define NPROT 4096
#define NEDGE 65536
#define NG 32

typedef _Float16 f16x8 __attribute__((ext_vector_type(8)));
typedef _Float16 f16x4 __attribute__((ext_vector_type(4)));
typedef __attribute__((ext_vector_type(4))) float f32x4;

__device__ __forceinline__ void splitf(float x, _Float16& h, _Float16& l) {
  h = (_Float16)x;
  l = (_Float16)(x - (float)h);
}

// ---------------------------------------------------------------------------
// Transpose + convert 14 H x H fp32 weights into split f16 planes Wt[n][k].
struct PtrPack { const float* p[14]; };

__global__ __launch_bounds__(256) void k_prep_wt(PtrPack pk, _Float16* __restrict__ dh,
                                                 _Float16* __restrict__ dl) {
  __shared__ float Ts[64][68];
  const int m = blockIdx.z;
  const int n0 = blockIdx.y * 64, k0 = blockIdx.x * 64;
  const float* W = pk.p[m];
  const int t = threadIdx.x;
#pragma unroll
  for (int rep = 0; rep < 16; ++rep) {
    int k = rep * 4 + (t >> 6);
    int n = t & 63;
    Ts[n][k] = W[(size_t)(k0 + k) * 256 + n0 + n];
  }
  __syncthreads();
#pragma unroll
  for (int rep = 0; rep < 2; ++rep) {
    int idx = t + rep * 256;
    int nr = idx >> 3, koff = (idx & 7) * 8;
    f16x8 vh, vl;
#pragma unroll
    for (int i = 0; i < 8; ++i) {
      _Float16 h, l;
      splitf(Ts[nr][koff + i], h, l);
      vh[i] = h; vl[i] = l;
    }
    size_t off = (size_t)m * 65536 + (size_t)(n0 + nr) * 256 + k0 + koff;
    *(f16x8*)&dh[off] = vh;
    *(f16x8*)&dl[off] = vl;
  }
}

// ---------------------------------------------------------------------------
// node embedding -> split planes, both graphs per dispatch
struct EmbJob {
  const float* x; const float* w; const float* b;
  _Float16* oh; _Float16* ol; int K;
};

__global__ __launch_bounds__(256) void k_node_embed2(EmbJob j0, EmbJob j1) {
  const EmbJob& j = blockIdx.y ? j1 : j0;
  const int i = blockIdx.x;
  const int c = threadIdx.x;
  float acc = j.b[c];
  for (int k = 0; k < j.K; ++k) acc += j.x[i * j.K + k] * j.w[k * HDIM + c];
  _Float16 h, l;
  splitf(acc, h, l);
  j.oh[(size_t)i * HDIM + c] = h;
  j.ol[(size_t)i * HDIM + c] = l;
}

// ---------------------------------------------------------------------------
// CSR build (both graphs per dispatch)
__global__ __launch_bounds__(256) void k_csr_count2(const int* __restrict__ ei0,
                                                    const int* __restrict__ ei1,
                                                    int* __restrict__ cur0,
                                                    int* __restrict__ cur1, int E) {
  const int* ei = blockIdx.y ? ei1 : ei0;
  int* cur = blockIdx.y ? cur1 : cur0;
  const int e = blockIdx.x * 256 + threadIdx.x;
  if (e < E) atomicAdd(&cur[ei[E + e]], 1);
}

__global__ __launch_bounds__(256) void k_csr_scan2(int* __restrict__ c0, int* __restrict__ o0,
                                                   int* __restrict__ c1, int* __restrict__ o1,
                                                   int N) {
  int* cnt_cur = blockIdx.x ? c1 : c0;
  int* off = blockIdx.x ? o1 : o0;
  __shared__ int tsum[256], tpre[257];
  const int t = threadIdx.x;
  const int base = t * 16;
  int loc[16], s = 0;
#pragma unroll
  for (int i = 0; i < 16; ++i) { loc[i] = cnt_cur[base + i]; s += loc[i]; }
  tsum[t] = s;
  __syncthreads();
  if (t == 0) {
    int a = 0;
    for (int i = 0; i < 256; ++i) { tpre[i] = a; a += tsum[i]; }
    tpre[256] = a;
  }
  __syncthreads();
  int a = tpre[t];
#pragma unroll
  for (int i = 0; i < 16; ++i) {
    off[base + i] = a;
    cnt_cur[base + i] = a;
    a += loc[i];
  }
  if (t == 255) off[N] = tpre[256];
}

__global__ __launch_bounds__(256) void k_csr_scatter2(const int* __restrict__ ei0,
                                                      const int* __restrict__ ei1,
                                                      int* __restrict__ cur0,
                                                      int* __restrict__ cur1,
                                                      int* __restrict__ eid0,
                                                      int* __restrict__ eid1, int E) {
  const int* ei = blockIdx.y ? ei1 : ei0;
  int* cur = blockIdx.y ? cur1 : cur0;
  int* eid = blockIdx.y ? eid1 : eid0;
  const int e = blockIdx.x * 256 + threadIdx.x;
  if (e < E) {
    int pos = atomicAdd(&cur[ei[E + e]], 1);
    eid[pos] = e;
  }
}

// ---------------------------------------------------------------------------
// GINE aggregation via CSR gather; x from split planes; emits split(x+agg).
struct AggJob {
  const _Float16* xh; const _Float16* xl; const float* ea;
  const int* eis; const int* off; const int* eid;
  const float* we; const float* be;
  _Float16* sh; _Float16* sl;
};

__global__ __launch_bounds__(256) void k_agg2(AggJob a0, AggJob a1) {
  const AggJob& a = blockIdx.y ? a1 : a0;
  const int n = blockIdx.x;
  const int c = threadIdx.x;
  const float w0 = a.we[c], w1 = a.we[HDIM + c], bb = a.be[c];
  const int j0 = a.off[n], j1 = a.off[n + 1];
  float sum = 0.f;
  for (int j = j0; j < j1; ++j) {
    int e = a.eid[j];
    int src = a.eis[e];
    float e0 = a.ea[2 * e], e1 = a.ea[2 * e + 1];
    float xv = (float)a.xh[(size_t)src * HDIM + c] + (float)a.xl[(size_t)src * HDIM + c];
    float m = xv + e0 * w0 + e1 * w1 + bb;
    sum += fmaxf(m, 0.f);
  }
  float self = (float)a.xh[(size_t)n * HDIM + c] + (float)a.xl[(size_t)n * HDIM + c];
  _Float16 h, l;
  splitf(self + sum, h, l);
  a.sh[(size_t)n * HDIM + c] = h;
  a.sl[(size_t)n * HDIM + c] = l;
}

// ---------------------------------------------------------------------------
// Split-f16 MFMA GEMM, K=256, pre-split planes in AND out, job table (z).
// flags: bit0 = relu; outmode = flags>>4: 1 = split planes (scaled by oscale);
// 3 = transposed f16-hi output Vt[dcol][4096-row] (for attention V).
struct GJob {
  const _Float16* Ah; const _Float16* Al;
  const _Float16* Bh; const _Float16* Bl;
  const float* bias;
  _Float16* Ch; _Float16* Cl; _Float16* Vt;
  float oscale; int flags;
};
struct GJobs { GJob j[6]; };

__global__ __launch_bounds__(256) void k_gemm(GJobs js) {
  const GJob J = js.j[blockIdx.z];
  const int relu = J.flags & 1;
  const int outmode = J.flags >> 4;
  __shared__ _Float16 Ah[64][72], Al[64][72], Bh[64][72], Bl[64][72];
  const int t = threadIdx.x;
  const int bm = blockIdx.x * 64, bn = blockIdx.y * 64;
  const int lane = t & 63, w = t >> 6;
  const int l15 = lane & 15, l4 = lane >> 4;
  const int wm = (w >> 1) * 32, wn = (w & 1) * 32;
  f32x4 acc[2][2] = {};
  for (int k0 = 0; k0 < 256; k0 += 64) {
    __syncthreads();
#pragma unroll
    for (int rep = 0; rep < 2; ++rep) {
      int idx = t + rep * 256;
      int r = idx >> 3, k8 = (idx & 7) * 8;
      size_t offa = (size_t)(bm + r) * 256 + k0 + k8;
      *(f16x8*)&Ah[r][k8] = *(const f16x8*)&J.Ah[offa];
      *(f16x8*)&Al[r][k8] = *(const f16x8*)&J.Al[offa];
      size_t offb = (size_t)(bn + r) * 256 + k0 + k8;
      *(f16x8*)&Bh[r][k8] = *(const f16x8*)&J.Bh[offb];
      *(f16x8*)&Bl[r][k8] = *(const f16x8*)&J.Bl[offb];
    }
    __syncthreads();
#pragma unroll
    for (int kh = 0; kh < 2; ++kh) {
      f16x8 a0h = *(f16x8*)&Ah[wm + l15][kh * 32 + l4 * 8];
      f16x8 a0l = *(f16x8*)&Al[wm + l15][kh * 32 + l4 * 8];
      f16x8 a1h = *(f16x8*)&Ah[wm + 16 + l15][kh * 32 + l4 * 8];
      f16x8 a1l = *(f16x8*)&Al[wm + 16 + l15][kh * 32 + l4 * 8];
      f16x8 b0h = *(f16x8*)&Bh[wn + l15][kh * 32 + l4 * 8];
      f16x8 b0l = *(f16x8*)&Bl[wn + l15][kh * 32 + l4 * 8];
      f16x8 b1h = *(f16x8*)&Bh[wn + 16 + l15][kh * 32 + l4 * 8];
      f16x8 b1l = *(f16x8*)&Bl[wn + 16 + l15][kh * 32 + l4 * 8];
      acc[0][0] = __builtin_amdgcn_mfma_f32_16x16x32_f16(a0h, b0h, acc[0][0], 0, 0, 0);
      acc[0][0] = __builtin_amdgcn_mfma_f32_16x16x32_f16(a0h, b0l, acc[0][0], 0, 0, 0);
      acc[0][0] = __builtin_amdgcn_mfma_f32_16x16x32_f16(a0l, b0h, acc[0][0], 0, 0, 0);
      acc[0][1] = __builtin_amdgcn_mfma_f32_16x16x32_f16(a0h, b1h, acc[0][1], 0, 0, 0);
      acc[0][1] = __builtin_amdgcn_mfma_f32_16x16x32_f16(a0h, b1l, acc[0][1], 0, 0, 0);
      acc[0][1] = __builtin_amdgcn_mfma_f32_16x16x32_f16(a0l, b1h, acc[0][1], 0, 0, 0);
      acc[1][0] = __builtin_amdgcn_mfma_f32_16x16x32_f16(a1h, b0h, acc[1][0], 0, 0, 0);
      acc[1][0] = __builtin_amdgcn_mfma_f32_16x16x32_f16(a1h, b0l, acc[1][0], 0, 0, 0);
      acc[1][0] = __builtin_amdgcn_mfma_f32_16x16x32_f16(a1l, b0h, acc[1][0], 0, 0, 0);
      acc[1][1] = __builtin_amdgcn_mfma_f32_16x16x32_f16(a1h, b1h, acc[1][1], 0, 0, 0);
      acc[1][1] = __builtin_amdgcn_mfma_f32_16x16x32_f16(a1h, b1l, acc[1][1], 0, 0, 0);
      acc[1][1] = __builtin_amdgcn_mfma_f32_16x16x32_f16(a1l, b1h, acc[1][1], 0, 0, 0);
    }
  }
  if (outmode == 3) __syncthreads();  // about to reuse Ah as transpose buffer
#pragma unroll
  for (int mi = 0; mi < 2; ++mi)
#pragma unroll
    for (int ni = 0; ni < 2; ++ni) {
      int col = bn + wn + ni * 16 + l15;
      float bv = J.bias[col];
#pragma unroll
      for (int r = 0; r < 4; ++r) {
        int row = bm + wm + mi * 16 + l4 * 4 + r;
        float v = acc[mi][ni][r] + bv;
        if (relu) v = fmaxf(v, 0.f);
        if (outmode == 1) {
          float vs = v * J.oscale;
          _Float16 hh, ll;
          splitf(vs, hh, ll);
          J.Ch[(size_t)row * 256 + col] = hh;
          J.Cl[(size_t)row * 256 + col] = ll;
        } else {
          // stage C^T (f16 hi) into LDS: Ah[d_local][n_local]
          Ah[wn + ni * 16 + l15][wm + mi * 16 + l4 * 4 + r] = (_Float16)v;
        }
      }
    }
  if (outmode == 3) {
    __syncthreads();
#pragma unroll
    for (int rep = 0; rep < 2; ++rep) {
      int idx = t + rep * 256;
      int d = idx >> 3, n8 = (idx & 7) * 8;
      *(f16x8*)&J.Vt[(size_t)(bn + d) * 4096 + bm + n8] = *(f16x8*)&Ah[d][n8];
    }
  }
}

// ---------------------------------------------------------------------------
// Swapped-QK flash attention (unchanged from round 8).
struct AttnArgs {
  const _Float16* Qh[2]; const _Float16* Ql[2];
  const _Float16* Kh[2]; const _Float16* Kl[2];
  const _Float16* Vth[2];
  float* Opart; float* mpart; float* lpart;
};

__global__ __launch_bounds__(256) void k_attn4(AttnArgs A, int nk_half) {
  __shared__ _Float16 Ksh[64][72], Ksl[64][72];  // [k][d]
  __shared__ _Float16 Vsh[64][72];               // [d][k], chunk-swizzled, hi only
  __shared__ _Float16 Psh[4][16][72];            // per-wave P [q][k]
  const int t = threadIdx.x;
  const int dir = blockIdx.y >> 2, h = blockIdx.y & 3;
  const int q0 = blockIdx.x * 64;
  const int half = blockIdx.z;
  const int kbase = half * nk_half;
  const int lane = t & 63, w = t >> 6;
  const int l15 = lane & 15, l4 = lane >> 4;

  const _Float16* Qh_g = A.Qh[dir];
  const _Float16* Ql_g = A.Ql[dir];
  const _Float16* Kh_g = A.Kh[dir];
  const _Float16* Kl_g = A.Kl[dir];
  const _Float16* Vth_g = A.Vth[dir];

  f16x8 qh[2], ql[2];
  {
    size_t qoff = (size_t)(q0 + w * 16 + l15) * 256 + h * 64;
#pragma unroll
    for (int kh = 0; kh < 2; ++kh) {
      qh[kh] = *(const f16x8*)&Qh_g[qoff + kh * 32 + l4 * 8];
      ql[kh] = *(const f16x8*)&Ql_g[qoff + kh * 32 + l4 * 8];
    }
  }
  f32x4 o[4] = {};
  float mrun = -1e30f;
  float lrun = 0.f;

  for (int kt = 0; kt < nk_half; kt += 64) {
    const int k0 = kbase + kt;
    __syncthreads();
#pragma unroll
    for (int rep = 0; rep < 2; ++rep) {
      int idx = t + rep * 256;
      int r = idx >> 3, c8 = idx & 7;
      size_t koff = (size_t)(k0 + r) * 256 + h * 64 + c8 * 8;
      *(f16x8*)&Ksh[r][c8 * 8] = *(const f16x8*)&Kh_g[koff];
      *(f16x8*)&Ksl[r][c8 * 8] = *(const f16x8*)&Kl_g[koff];
      int sc = c8 ^ ((r >> 3) & 7);
      size_t voff = (size_t)(h * 64 + r) * 4096 + k0 + c8 * 8;
      *(f16x8*)&Vsh[r][sc * 8] = *(const f16x8*)&Vth_g[voff];
    }
    __syncthreads();

    f32x4 sf[4] = {};
#pragma unroll
    for (int kc = 0; kc < 4; ++kc) {
      f16x8 kf0h = *(f16x8*)&Ksh[kc * 16 + l15][l4 * 8];
      f16x8 kf0l = *(f16x8*)&Ksl[kc * 16 + l15][l4 * 8];
      f16x8 kf1h = *(f16x8*)&Ksh[kc * 16 + l15][32 + l4 * 8];
      f16x8 kf1l = *(f16x8*)&Ksl[kc * 16 + l15][32 + l4 * 8];
      sf[kc] = __builtin_amdgcn_mfma_f32_16x16x32_f16(kf0h, qh[0], sf[kc], 0, 0, 0);
      sf[kc] = __builtin_amdgcn_mfma_f32_16x16x32_f16(kf0h, ql[0], sf[kc], 0, 0, 0);
      sf[kc] = __builtin_amdgcn_mfma_f32_16x16x32_f16(kf0l, qh[0], sf[kc], 0, 0, 0);
      sf[kc] = __builtin_amdgcn_mfma_f32_16x16x32_f16(kf1h, qh[1], sf[kc], 0, 0, 0);
      sf[kc] = __builtin_amdgcn_mfma_f32_16x16x32_f16(kf1h, ql[1], sf[kc], 0, 0, 0);
      sf[kc] = __builtin_amdgcn_mfma_f32_16x16x32_f16(kf1l, qh[1], sf[kc], 0, 0, 0);
    }

    float mt = -1e30f;
#pragma unroll
    for (int kc = 0; kc < 4; ++kc) {
      float a = fmaxf(fmaxf(sf[kc][0], sf[kc][1]), fmaxf(sf[kc][2], sf[kc][3]));
      mt = fmaxf(mt, a);
    }
    mt = fmaxf(mt, __shfl_xor(mt, 16, 64));
    mt = fmaxf(mt, __shfl_xor(mt, 32, 64));
    float mn = fmaxf(mrun, mt);
    float alpha = __expf(mrun - mn);
    mrun = mn;
    float rs = 0.f;
    _Float16 pf[4][4];
#pragma unroll
    for (int kc = 0; kc < 4; ++kc)
#pragma unroll
      for (int r = 0; r < 4; ++r) {
        float pv = __expf(sf[kc][r] - mn);
        rs += pv;
        pf[kc][r] = (_Float16)pv;
      }
    rs += __shfl_xor(rs, 16, 64);
    rs += __shfl_xor(rs, 32, 64);
    lrun = lrun * alpha + rs;

#pragma unroll
    for (int r = 0; r < 4; ++r) {
      float ar = __shfl(alpha, 4 * l4 + r, 64);
      o[0][r] *= ar; o[1][r] *= ar; o[2][r] *= ar; o[3][r] *= ar;
    }

#pragma unroll
    for (int kc = 0; kc < 4; ++kc) {
      f16x4 pv = {pf[kc][0], pf[kc][1], pf[kc][2], pf[kc][3]};
      *(f16x4*)&Psh[w][l15][kc * 16 + 4 * l4] = pv;
    }

#pragma unroll
    for (int kh = 0; kh < 2; ++kh) {
      f16x8 pa = *(f16x8*)&Psh[w][l15][kh * 32 + l4 * 8];
#pragma unroll
      for (int oc = 0; oc < 4; ++oc) {
        int d = oc * 16 + l15;
        int chunk = (kh * 4 + l4) ^ ((d >> 3) & 7);
        f16x8 vb = *(f16x8*)&Vsh[d][chunk * 8];
        o[oc] = __builtin_amdgcn_mfma_f32_16x16x32_f16(pa, vb, o[oc], 0, 0, 0);
      }
    }
  }

  const int slot = dir * 2 + half;
#pragma unroll
  for (int oc = 0; oc < 4; ++oc) {
    int col = h * 64 + oc * 16 + l15;
#pragma unroll
    for (int r = 0; r < 4; ++r) {
      int row = q0 + w * 16 + 4 * l4 + r;
      A.Opart[((size_t)slot * 4096 + row) * 256 + col] = o[oc][r];
    }
  }
  if (lane < 16) {
    int row = q0 + w * 16 + l15;
    A.mpart[(size_t)(slot * 4 + h) * 4096 + row] = mrun;
    A.lpart[(size_t)(slot * 4 + h) * 4096 + row] = lrun;
  }
}

// ---------------------------------------------------------------------------
// Combine k-halves + residual (from planes) + segment-sum pooling.
__global__ __launch_bounds__(256) void k_combine_pool(
    const float* __restrict__ Opart, const float* __restrict__ mpart,
    const float* __restrict__ lpart,
    const _Float16* __restrict__ hmh, const _Float16* __restrict__ hml,
    const _Float16* __restrict__ hph, const _Float16* __restrict__ hpl,
    const int* __restrict__ b_mol, const int* __restrict__ b_prot,
    float* __restrict__ z, float* __restrict__ cnt) {
  const int row = blockIdx.x;
  const int dir = blockIdx.y;
  const int c = threadIdx.x;
  const int h = c >> 6;
  const _Float16* Hh = dir ? hph : hmh;
  const _Float16* Hl = dir ? hpl : hml;
  const int g = (dir ? b_prot : b_mol)[row];
  size_t mi0 = (size_t)((dir * 2 + 0) * 4 + h) * 4096 + row;
  size_t mi1 = (size_t)((dir * 2 + 1) * 4 + h) * 4096 + row;
  float m1 = mpart[mi0], m2 = mpart[mi1];
  float l1 = lpart[mi0], l2 = lpart[mi1];
  float M = fmaxf(m1, m2);
  float e1 = __expf(m1 - M), e2 = __expf(m2 - M);
  float L = l1 * e1 + l2 * e2;
  float O1 = Opart[((size_t)(dir * 2 + 0) * 4096 + row) * 256 + c];
  float O2 = Opart[((size_t)(dir * 2 + 1) * 4096 + row) * 256 + c];
  float hin = (float)Hh[(size_t)row * 256 + c] + (float)Hl[(size_t)row * 256 + c];
  float v = (O1 * e1 + O2 * e2) / L + hin;
  atomicAdd(&z[(size_t)g * 512 + dir * 256 + c], v);
  if (c == 0) atomicAdd(&cnt[dir * 32 + g], 1.0f);
}

__global__ __launch_bounds__(256) void k_segdiv(float* __restrict__ z,
                                                const float* __restrict__ cnt) {
  const int idx = blockIdx.x * 256 + threadIdx.x;  // 32*512
  const int g = idx >> 9, c = idx & 511;
  const float cc = cnt[(c < 256) ? g : (32 + g)];
  z[idx] /= fmaxf(cc, 1.0f);
}

__global__ __launch_bounds__(256) void k_fc1(
    const float* __restrict__ z, const float* __restrict__ w,
    const float* __restrict__ b, float* __restrict__ out) {
  const int idx = blockIdx.x * 256 + threadIdx.x;  // 32*256
  const int r = idx >> 8, c = idx & 255;
  float acc = b[c];
  for (int k = 0; k < 512; ++k) acc += z[r * 512 + k] * w[k * HDIM + c];
  out[idx] = fmaxf(acc, 0.f);
}

__global__ __launch_bounds__(64) void k_fc2(
    const float* __restrict__ xin, const float* __restrict__ w,
    const float* __restrict__ b, float* __restrict__ out) {
  const int r = threadIdx.x;
  if (r < NG) {
    float acc = b[0];
    for (int k = 0; k < HDIM; ++k) acc += xin[r * HDIM + k] * w[k];
    out[r] = 1.0f / (1.0f + __expf(-acc));
  }
}

// ---------------------------------------------------------------------------
extern "C" void kernel_launch(void* const* d_in, const int* in_sizes, int n_in,
                              void* d_out, int out_size, void* d_ws, size_t ws_size,
                              hipStream_t stream) {
  const float* x_mol   = (const float*)d_in[0];
  const float* x_prot  = (const float*)d_in[1];
  const float* ea_mol  = (const float*)d_in[2];
  const float* ea_prot = (const float*)d_in[3];
  const int*   ei_mol  = (const int*)d_in[4];
  const int*   ei_prot = (const int*)d_in[5];
  const int*   b_mol   = (const int*)d_in[6];
  const int*   b_prot  = (const int*)d_in[7];
  const float* nlm_w = (const float*)d_in[8];
  const float* nlm_b = (const float*)d_in[9];
  const float* nlp_w = (const float*)d_in[10];
  const float* nlp_b = (const float*)d_in[11];
  const float* elm_w = (const float*)d_in[12];
  const float* elm_b = (const float*)d_in[13];
  const float* elp_w = (const float*)d_in[14];
  const float* elp_b = (const float*)d_in[15];
  const float* mol_w1 = (const float*)d_in[16];
  const float* mol_b1 = (const float*)d_in[17];
  const float* mol_w2 = (const float*)d_in[18];
  const float* mol_b2 = (const float*)d_in[19];
  const float* prot_w1 = (const float*)d_in[20];
  const float* prot_b1 = (const float*)d_in[21];
  const float* prot_w2 = (const float*)d_in[22];
  const float* prot_b2 = (const float*)d_in[23];
  const float* mp_wq = (const float*)d_in[24];
  const float* mp_bq = (const float*)d_in[25];
  const float* mp_wk = (const float*)d_in[26];
  const float* mp_bk = (const float*)d_in[27];
  const float* mp_wv = (const float*)d_in[28];
  const float* mp_bv = (const float*)d_in[29];
  const float* pm_wq = (const float*)d_in[30];
  const float* pm_bq = (const float*)d_in[31];
  const float* pm_wk = (const float*)d_in[32];
  const float* pm_bk = (const float*)d_in[33];
  const float* pm_wv = (const float*)d_in[34];
  const float* pm_bv = (const float*)d_in[35];
  const float* fc1_w = (const float*)d_in[36];
  const float* fc1_b = (const float*)d_in[37];
  const float* fc2_w = (const float*)d_in[38];
  const float* fc2_b = (const float*)d_in[39];
  float* out = (float*)d_out;

  // workspace carve (2 MB units for the f16 planes); peak ~67 MB
  char* W8 = (char*)d_ws;
  const size_t MB = 1u << 20;
  _Float16* wtH  = (_Float16*)(W8 + 0 * MB);   // 1.75 MB used
  _Float16* wtL  = (_Float16*)(W8 + 2 * MB);
  _Float16* hmh  = (_Float16*)(W8 + 4 * MB);
  _Float16* hml  = (_Float16*)(W8 + 6 * MB);
  _Float16* hph  = (_Float16*)(W8 + 8 * MB);
  _Float16* hpl  = (_Float16*)(W8 + 10 * MB);
  _Float16* amh  = (_Float16*)(W8 + 12 * MB);
  _Float16* aml  = (_Float16*)(W8 + 14 * MB);
  _Float16* aph  = (_Float16*)(W8 + 16 * MB);
  _Float16* apl  = (_Float16*)(W8 + 18 * MB);
  _Float16* t1mh = (_Float16*)(W8 + 20 * MB);
  _Float16* t1ml = (_Float16*)(W8 + 22 * MB);
  _Float16* t1ph = (_Float16*)(W8 + 24 * MB);
  _Float16* t1pl = (_Float16*)(W8 + 26 * MB);
  _Float16* Qh0  = (_Float16*)(W8 + 28 * MB);
  _Float16* Ql0  = (_Float16*)(W8 + 30 * MB);
  _Float16* Kh0  = (_Float16*)(W8 + 32 * MB);
  _Float16* Kl0  = (_Float16*)(W8 + 34 * MB);
  _Float16* Qh1  = (_Float16*)(W8 + 36 * MB);
  _Float16* Ql1  = (_Float16*)(W8 + 38 * MB);
  _Float16* Kh1  = (_Float16*)(W8 + 40 * MB);
  _Float16* Kl1  = (_Float16*)(W8 + 42 * MB);
  _Float16* Vth0 = (_Float16*)(W8 + 44 * MB);
  _Float16* Vth1 = (_Float16*)(W8 + 46 * MB);
  float* Opart = (float*)(W8 + 48 * MB);   // 16 MB: [dir*2+half][4096][256]
  float* mpart = (float*)(W8 + 64 * MB);   // 16*4096 floats
  float* lpart = mpart + 65536;
  float* zb    = lpart + 65536;            // 32*512
  float* cnt   = zb + 32 * 512;            // 64
  float* fch   = cnt + 64;                 // 32*256
  int* off_m = (int*)(W8 + 65 * MB);
  int* cur_m = off_m + 4224;
  int* eid_m = cur_m + 4224;
  int* off_p = (int*)(W8 + 66 * MB);
  int* cur_p = off_p + 4224;
  int* eid_p = cur_p + 4224;

  // weights: 0,1 mol_w1 | 2,3 mol_w2 | 4,5 prot_w1 | 6,7 prot_w2
  // 8 mp_wq 9 mp_wk 10 mp_wv | 11 pm_wq 12 pm_wk 13 pm_wv
  PtrPack pk;
  pk.p[0] = mol_w1;           pk.p[1] = mol_w1 + 65536;
  pk.p[2] = mol_w2;           pk.p[3] = mol_w2 + 65536;
  pk.p[4] = prot_w1;          pk.p[5] = prot_w1 + 65536;
  pk.p[6] = prot_w2;          pk.p[7] = prot_w2 + 65536;
  pk.p[8] = mp_wq;  pk.p[9] = mp_wk;  pk.p[10] = mp_wv;
  pk.p[11] = pm_wq; pk.p[12] = pm_wk; pk.p[13] = pm_wv;
  k_prep_wt<<<dim3(4, 4, 14), 256, 0, stream>>>(pk, wtH, wtL);

  hipMemsetAsync(cur_m, 0, 4096 * 4, stream);
  hipMemsetAsync(cur_p, 0, 4096 * 4, stream);
  k_csr_count2<<<dim3(NEDGE / 256, 2), 256, 0, stream>>>(ei_mol, ei_prot, cur_m, cur_p, NEDGE);
  k_csr_scan2<<<2, 256, 0, stream>>>(cur_m, off_m, cur_p, off_p, NMOL);
  k_csr_scatter2<<<dim3(NEDGE / 256, 2), 256, 0, stream>>>(ei_mol, ei_prot, cur_m, cur_p,
                                                           eid_m, eid_p, NEDGE);

  EmbJob em = {x_mol, nlm_w, nlm_b, hmh, hml, 8};
  EmbJob ep = {x_prot, nlp_w, nlp_b, hph, hpl, 4};
  k_node_embed2<<<dim3(NMOL, 2), 256, 0, stream>>>(em, ep);

#define WTH(i) (wtH + (size_t)(i) * 65536)
#define WTL(i) (wtL + (size_t)(i) * 65536)

  AggJob am = {hmh, hml, ea_mol, ei_mol, off_m, eid_m, elm_w, elm_b, amh, aml};
  AggJob ap = {hph, hpl, ea_prot, ei_prot, off_p, eid_p, elp_w, elp_b, aph, apl};

  for (int l = 0; l < 2; ++l) {
    k_agg2<<<dim3(NMOL, 2), 256, 0, stream>>>(am, ap);
    GJobs g1 = {};
    g1.j[0] = {amh, aml, WTH(l), WTL(l), mol_b1 + l * 256,
               t1mh, t1ml, nullptr, 1.0f, 1 | (1 << 4)};
    g1.j[1] = {aph, apl, WTH(4 + l), WTL(4 + l), prot_b1 + l * 256,
               t1ph, t1pl, nullptr, 1.0f, 1 | (1 << 4)};
    k_gemm<<<dim3(64, 4, 2), 256, 0, stream>>>(g1);
    GJobs g2 = {};
    g2.j[0] = {t1mh, t1ml, WTH(2 + l), WTL(2 + l), mol_b2 + l * 256,
               hmh, hml, nullptr, 1.0f, 1 | (1 << 4)};
    g2.j[1] = {t1ph, t1pl, WTH(6 + l), WTL(6 + l), prot_b2 + l * 256,
               hph, hpl, nullptr, 1.0f, 1 | (1 << 4)};
    k_gemm<<<dim3(64, 4, 2), 256, 0, stream>>>(g2);
  }

  // QKV for both attention directions, one dispatch (z=6); V transposed in-epilogue
  {
    GJobs q = {};
    q.j[0] = {hmh, hml, WTH(8), WTL(8), mp_bq, Qh0, Ql0, nullptr, 0.125f, 1 << 4};
    q.j[1] = {hph, hpl, WTH(9), WTL(9), mp_bk, Kh0, Kl0, nullptr, 1.0f, 1 << 4};
    q.j[2] = {hph, hpl, WTH(10), WTL(10), mp_bv, nullptr, nullptr, Vth0, 1.0f, 3 << 4};
    q.j[3] = {hph, hpl, WTH(11), WTL(11), pm_bq, Qh1, Ql1, nullptr, 0.125f, 1 << 4};
    q.j[4] = {hmh, hml, WTH(12), WTL(12), pm_bk, Kh1, Kl1, nullptr, 1.0f, 1 << 4};
    q.j[5] = {hmh, hml, WTH(13), WTL(13), pm_bv, nullptr, nullptr, Vth1, 1.0f, 3 << 4};
    k_gemm<<<dim3(64, 4, 6), 256, 0, stream>>>(q);
  }

  AttnArgs aa;
  aa.Qh[0] = Qh0; aa.Ql[0] = Ql0; aa.Kh[0] = Kh0; aa.Kl[0] = Kl0; aa.Vth[0] = Vth0;
  aa.Qh[1] = Qh1; aa.Ql[1] = Ql1; aa.Kh[1] = Kh1; aa.Kl[1] = Kl1; aa.Vth[1] = Vth1;
  aa.Opart = Opart; aa.mpart = mpart; aa.lpart = lpart;
  k_attn4<<<dim3(64, 8, 2), 256, 0, stream>>>(aa, 2048);

  hipMemsetAsync(zb, 0, (32 * 512 + 64) * 4, stream);
  k_combine_pool<<<dim3(4096, 2), 256, 0, stream>>>(Opart, mpart, lpart,
                                                    hmh, hml, hph, hpl,
                                                    b_mol, b_prot, zb, cnt);
  k_segdiv<<<64, 256, 0, stream>>>(zb, cnt);
  k_fc1<<<32, 256, 0, stream>>>(zb, fc1_w, fc1_b, fch);
  k_fc2<<<1, 64, 0, stream>>>(fch, fc2_w, fc2_b, out);
#undef WTH
#undef WTL
}

// Round 10
// 501.721 us; speedup vs baseline: 4.4594x; 1.0666x over previous
//
#include <hip/hip_runtime.h>
#include <math.h>

#define HDIM 256
#define NMOL 4096
#define NPROT 4096
#define NEDGE 65536
#define NG 32

typedef _Float16 f16x8 __attribute__((ext_vector_type(8)));
typedef _Float16 f16x4 __attribute__((ext_vector_type(4)));
typedef __attribute__((ext_vector_type(4))) float f32x4;

__device__ __forceinline__ void splitf(float x, _Float16& h, _Float16& l) {
  h = (_Float16)x;
  l = (_Float16)(x - (float)h);
}

struct __align__(16) EdgeRec { int src; float a0; float a1; int pad; };

// ---------------------------------------------------------------------------
// Transpose + convert 14 H x H fp32 weights into split f16 planes Wt[n][k].
struct PtrPack { const float* p[14]; };

__global__ __launch_bounds__(256) void k_prep_wt(PtrPack pk, _Float16* __restrict__ dh,
                                                 _Float16* __restrict__ dl) {
  __shared__ float Ts[64][68];
  const int m = blockIdx.z;
  const int n0 = blockIdx.y * 64, k0 = blockIdx.x * 64;
  const float* W = pk.p[m];
  const int t = threadIdx.x;
#pragma unroll
  for (int rep = 0; rep < 16; ++rep) {
    int k = rep * 4 + (t >> 6);
    int n = t & 63;
    Ts[n][k] = W[(size_t)(k0 + k) * 256 + n0 + n];
  }
  __syncthreads();
#pragma unroll
  for (int rep = 0; rep < 2; ++rep) {
    int idx = t + rep * 256;
    int nr = idx >> 3, koff = (idx & 7) * 8;
    f16x8 vh, vl;
#pragma unroll
    for (int i = 0; i < 8; ++i) {
      _Float16 h, l;
      splitf(Ts[nr][koff + i], h, l);
      vh[i] = h; vl[i] = l;
    }
    size_t off = (size_t)m * 65536 + (size_t)(n0 + nr) * 256 + k0 + koff;
    *(f16x8*)&dh[off] = vh;
    *(f16x8*)&dl[off] = vl;
  }
}

// ---------------------------------------------------------------------------
// node embedding -> split planes, both graphs per dispatch
struct EmbJob {
  const float* x; const float* w; const float* b;
  _Float16* oh; _Float16* ol; int K;
};

__global__ __launch_bounds__(256) void k_node_embed2(EmbJob j0, EmbJob j1) {
  const EmbJob& j = blockIdx.y ? j1 : j0;
  const int i = blockIdx.x;
  const int c = threadIdx.x;
  float acc = j.b[c];
  for (int k = 0; k < j.K; ++k) acc += j.x[i * j.K + k] * j.w[k * HDIM + c];
  _Float16 h, l;
  splitf(acc, h, l);
  j.oh[(size_t)i * HDIM + c] = h;
  j.ol[(size_t)i * HDIM + c] = l;
}

// ---------------------------------------------------------------------------
// CSR build (both graphs per dispatch); scatter writes packed EdgeRec
__global__ __launch_bounds__(256) void k_csr_count2(const int* __restrict__ ei0,
                                                    const int* __restrict__ ei1,
                                                    int* __restrict__ cur0,
                                                    int* __restrict__ cur1, int E) {
  const int* ei = blockIdx.y ? ei1 : ei0;
  int* cur = blockIdx.y ? cur1 : cur0;
  const int e = blockIdx.x * 256 + threadIdx.x;
  if (e < E) atomicAdd(&cur[ei[E + e]], 1);
}

__global__ __launch_bounds__(256) void k_csr_scan2(int* __restrict__ c0, int* __restrict__ o0,
                                                   int* __restrict__ c1, int* __restrict__ o1,
                                                   int N) {
  int* cnt_cur = blockIdx.x ? c1 : c0;
  int* off = blockIdx.x ? o1 : o0;
  __shared__ int tsum[256], tpre[257];
  const int t = threadIdx.x;
  const int base = t * 16;
  int loc[16], s = 0;
#pragma unroll
  for (int i = 0; i < 16; ++i) { loc[i] = cnt_cur[base + i]; s += loc[i]; }
  tsum[t] = s;
  __syncthreads();
  if (t == 0) {
    int a = 0;
    for (int i = 0; i < 256; ++i) { tpre[i] = a; a += tsum[i]; }
    tpre[256] = a;
  }
  __syncthreads();
  int a = tpre[t];
#pragma unroll
  for (int i = 0; i < 16; ++i) {
    off[base + i] = a;
    cnt_cur[base + i] = a;
    a += loc[i];
  }
  if (t == 255) off[N] = tpre[256];
}

__global__ __launch_bounds__(256) void k_csr_scatter2(
    const int* __restrict__ ei0, const int* __restrict__ ei1,
    const float* __restrict__ ea0, const float* __restrict__ ea1,
    int* __restrict__ cur0, int* __restrict__ cur1,
    EdgeRec* __restrict__ er0, EdgeRec* __restrict__ er1, int E) {
  const int* ei = blockIdx.y ? ei1 : ei0;
  const float* ea = blockIdx.y ? ea1 : ea0;
  int* cur = blockIdx.y ? cur1 : cur0;
  EdgeRec* er = blockIdx.y ? er1 : er0;
  const int e = blockIdx.x * 256 + threadIdx.x;
  if (e < E) {
    int pos = atomicAdd(&cur[ei[E + e]], 1);
    EdgeRec r;
    r.src = ei[e];
    r.a0 = ea[2 * e];
    r.a1 = ea[2 * e + 1];
    r.pad = 0;
    er[pos] = r;
  }
}

// ---------------------------------------------------------------------------
// GINE aggregation via packed-edge CSR gather; emits split(x+agg).
struct AggJob {
  const _Float16* xh; const _Float16* xl; const EdgeRec* er;
  const int* off; const float* we; const float* be;
  _Float16* sh; _Float16* sl;
};

__global__ __launch_bounds__(256) void k_agg2(AggJob a0, AggJob a1) {
  const AggJob& a = blockIdx.y ? a1 : a0;
  const int n = blockIdx.x;
  const int c = threadIdx.x;
  const float w0 = a.we[c], w1 = a.we[HDIM + c], bb = a.be[c];
  const int j0 = a.off[n], j1 = a.off[n + 1];
  float sum = 0.f;
  int j = j0;
  for (; j + 1 < j1; j += 2) {  // 2-way ILP on the load chain
    EdgeRec ra = a.er[j];
    EdgeRec rb = a.er[j + 1];
    float xa = (float)a.xh[(size_t)ra.src * HDIM + c] + (float)a.xl[(size_t)ra.src * HDIM + c];
    float xb = (float)a.xh[(size_t)rb.src * HDIM + c] + (float)a.xl[(size_t)rb.src * HDIM + c];
    sum += fmaxf(xa + ra.a0 * w0 + ra.a1 * w1 + bb, 0.f);
    sum += fmaxf(xb + rb.a0 * w0 + rb.a1 * w1 + bb, 0.f);
  }
  if (j < j1) {
    EdgeRec ra = a.er[j];
    float xa = (float)a.xh[(size_t)ra.src * HDIM + c] + (float)a.xl[(size_t)ra.src * HDIM + c];
    sum += fmaxf(xa + ra.a0 * w0 + ra.a1 * w1 + bb, 0.f);
  }
  float self = (float)a.xh[(size_t)n * HDIM + c] + (float)a.xl[(size_t)n * HDIM + c];
  _Float16 h, l;
  splitf(self + sum, h, l);
  a.sh[(size_t)n * HDIM + c] = h;
  a.sl[(size_t)n * HDIM + c] = l;
}

// ---------------------------------------------------------------------------
// Split-f16 MFMA GEMM, K=256, pre-split planes in AND out, job table (z).
// flags: bit0 = relu; outmode = flags>>4: 1 = split planes (scaled by oscale);
// 3 = transposed f16-hi output Vt[dcol][4096-row] (for attention V).
struct GJob {
  const _Float16* Ah; const _Float16* Al;
  const _Float16* Bh; const _Float16* Bl;
  const float* bias;
  _Float16* Ch; _Float16* Cl; _Float16* Vt;
  float oscale; int flags;
};
struct GJobs { GJob j[6]; };

__global__ __launch_bounds__(256) void k_gemm(GJobs js) {
  const GJob J = js.j[blockIdx.z];
  const int relu = J.flags & 1;
  const int outmode = J.flags >> 4;
  __shared__ _Float16 Ah[64][72], Al[64][72], Bh[64][72], Bl[64][72];
  const int t = threadIdx.x;
  const int bm = blockIdx.x * 64, bn = blockIdx.y * 64;
  const int lane = t & 63, w = t >> 6;
  const int l15 = lane & 15, l4 = lane >> 4;
  const int wm = (w >> 1) * 32, wn = (w & 1) * 32;
  f32x4 acc[2][2] = {};
  for (int k0 = 0; k0 < 256; k0 += 64) {
    __syncthreads();
#pragma unroll
    for (int rep = 0; rep < 2; ++rep) {
      int idx = t + rep * 256;
      int r = idx >> 3, k8 = (idx & 7) * 8;
      size_t offa = (size_t)(bm + r) * 256 + k0 + k8;
      *(f16x8*)&Ah[r][k8] = *(const f16x8*)&J.Ah[offa];
      *(f16x8*)&Al[r][k8] = *(const f16x8*)&J.Al[offa];
      size_t offb = (size_t)(bn + r) * 256 + k0 + k8;
      *(f16x8*)&Bh[r][k8] = *(const f16x8*)&J.Bh[offb];
      *(f16x8*)&Bl[r][k8] = *(const f16x8*)&J.Bl[offb];
    }
    __syncthreads();
#pragma unroll
    for (int kh = 0; kh < 2; ++kh) {
      f16x8 a0h = *(f16x8*)&Ah[wm + l15][kh * 32 + l4 * 8];
      f16x8 a0l = *(f16x8*)&Al[wm + l15][kh * 32 + l4 * 8];
      f16x8 a1h = *(f16x8*)&Ah[wm + 16 + l15][kh * 32 + l4 * 8];
      f16x8 a1l = *(f16x8*)&Al[wm + 16 + l15][kh * 32 + l4 * 8];
      f16x8 b0h = *(f16x8*)&Bh[wn + l15][kh * 32 + l4 * 8];
      f16x8 b0l = *(f16x8*)&Bl[wn + l15][kh * 32 + l4 * 8];
      f16x8 b1h = *(f16x8*)&Bh[wn + 16 + l15][kh * 32 + l4 * 8];
      f16x8 b1l = *(f16x8*)&Bl[wn + 16 + l15][kh * 32 + l4 * 8];
      acc[0][0] = __builtin_amdgcn_mfma_f32_16x16x32_f16(a0h, b0h, acc[0][0], 0, 0, 0);
      acc[0][0] = __builtin_amdgcn_mfma_f32_16x16x32_f16(a0h, b0l, acc[0][0], 0, 0, 0);
      acc[0][0] = __builtin_amdgcn_mfma_f32_16x16x32_f16(a0l, b0h, acc[0][0], 0, 0, 0);
      acc[0][1] = __builtin_amdgcn_mfma_f32_16x16x32_f16(a0h, b1h, acc[0][1], 0, 0, 0);
      acc[0][1] = __builtin_amdgcn_mfma_f32_16x16x32_f16(a0h, b1l, acc[0][1], 0, 0, 0);
      acc[0][1] = __builtin_amdgcn_mfma_f32_16x16x32_f16(a0l, b1h, acc[0][1], 0, 0, 0);
      acc[1][0] = __builtin_amdgcn_mfma_f32_16x16x32_f16(a1h, b0h, acc[1][0], 0, 0, 0);
      acc[1][0] = __builtin_amdgcn_mfma_f32_16x16x32_f16(a1h, b0l, acc[1][0], 0, 0, 0);
      acc[1][0] = __builtin_amdgcn_mfma_f32_16x16x32_f16(a1l, b0h, acc[1][0], 0, 0, 0);
      acc[1][1] = __builtin_amdgcn_mfma_f32_16x16x32_f16(a1h, b1h, acc[1][1], 0, 0, 0);
      acc[1][1] = __builtin_amdgcn_mfma_f32_16x16x32_f16(a1h, b1l, acc[1][1], 0, 0, 0);
      acc[1][1] = __builtin_amdgcn_mfma_f32_16x16x32_f16(a1l, b1h, acc[1][1], 0, 0, 0);
    }
  }
  if (outmode == 3) __syncthreads();  // about to reuse Ah as transpose buffer
#pragma unroll
  for (int mi = 0; mi < 2; ++mi)
#pragma unroll
    for (int ni = 0; ni < 2; ++ni) {
      int col = bn + wn + ni * 16 + l15;
      float bv = J.bias[col];
#pragma unroll
      for (int r = 0; r < 4; ++r) {
        int row = bm + wm + mi * 16 + l4 * 4 + r;
        float v = acc[mi][ni][r] + bv;
        if (relu) v = fmaxf(v, 0.f);
        if (outmode == 1) {
          float vs = v * J.oscale;
          _Float16 hh, ll;
          splitf(vs, hh, ll);
          J.Ch[(size_t)row * 256 + col] = hh;
          J.Cl[(size_t)row * 256 + col] = ll;
        } else {
          Ah[wn + ni * 16 + l15][wm + mi * 16 + l4 * 4 + r] = (_Float16)v;
        }
      }
    }
  if (outmode == 3) {
    __syncthreads();
#pragma unroll
    for (int rep = 0; rep < 2; ++rep) {
      int idx = t + rep * 256;
      int d = idx >> 3, n8 = (idx & 7) * 8;
      *(f16x8*)&J.Vt[(size_t)(bn + d) * 4096 + bm + n8] = *(f16x8*)&Ah[d][n8];
    }
  }
}

// ---------------------------------------------------------------------------
// Swapped-QK flash attention, 128 q-rows/block (4 waves x 32 q). The A=K
// fragment reads are identical across q, so doubling q per wave halves the
// per-q LDS traffic. Grid (32 q-tiles, dir*4+head, 2 k-halves) = 512 blocks.
struct AttnArgs {
  const _Float16* Qh[2]; const _Float16* Ql[2];
  const _Float16* Kh[2]; const _Float16* Kl[2];
  const _Float16* Vth[2];
  float* Opart; float* mpart; float* lpart;
};

__global__ __launch_bounds__(256) void k_attn5(AttnArgs A, int nk_half) {
  __shared__ _Float16 Ksh[64][72], Ksl[64][72];  // [k][d]
  __shared__ _Float16 Vsh[64][72];               // [d][k], chunk-swizzled, hi only
  __shared__ _Float16 Psh[4][32][72];            // per-wave P [q][k]
  const int t = threadIdx.x;
  const int dir = blockIdx.y >> 2, h = blockIdx.y & 3;
  const int q0 = blockIdx.x * 128;
  const int half = blockIdx.z;
  const int kbase = half * nk_half;
  const int lane = t & 63, w = t >> 6;
  const int l15 = lane & 15, l4 = lane >> 4;
  const int qw = q0 + w * 32;

  const _Float16* Qh_g = A.Qh[dir];
  const _Float16* Ql_g = A.Ql[dir];
  const _Float16* Kh_g = A.Kh[dir];
  const _Float16* Kl_g = A.Kl[dir];
  const _Float16* Vth_g = A.Vth[dir];

  f16x8 qh[2][2], ql[2][2];  // [qhalf][kh]
#pragma unroll
  for (int qf = 0; qf < 2; ++qf) {
    size_t qoff = (size_t)(qw + qf * 16 + l15) * 256 + h * 64;
#pragma unroll
    for (int kh = 0; kh < 2; ++kh) {
      qh[qf][kh] = *(const f16x8*)&Qh_g[qoff + kh * 32 + l4 * 8];
      ql[qf][kh] = *(const f16x8*)&Ql_g[qoff + kh * 32 + l4 * 8];
    }
  }
  f32x4 o[2][4] = {};             // o[qf][oc][r] = O[qf*16+4*l4+r][oc*16+l15]
  float mrun[2] = {-1e30f, -1e30f};
  float lrun[2] = {0.f, 0.f};

  for (int kt = 0; kt < nk_half; kt += 64) {
    const int k0 = kbase + kt;
    __syncthreads();
#pragma unroll
    for (int rep = 0; rep < 2; ++rep) {
      int idx = t + rep * 256;
      int r = idx >> 3, c8 = idx & 7;
      size_t koff = (size_t)(k0 + r) * 256 + h * 64 + c8 * 8;
      *(f16x8*)&Ksh[r][c8 * 8] = *(const f16x8*)&Kh_g[koff];
      *(f16x8*)&Ksl[r][c8 * 8] = *(const f16x8*)&Kl_g[koff];
      int sc = c8 ^ ((r >> 3) & 7);
      size_t voff = (size_t)(h * 64 + r) * 4096 + k0 + c8 * 8;
      *(f16x8*)&Vsh[r][sc * 8] = *(const f16x8*)&Vth_g[voff];
    }
    __syncthreads();

    // S^T for 32 q: sf[qf][kc][r] = S[q = qf*16+l15][k = kc*16+4*l4+r]
    f32x4 sf[2][4] = {};
#pragma unroll
    for (int kc = 0; kc < 4; ++kc) {
      f16x8 kf0h = *(f16x8*)&Ksh[kc * 16 + l15][l4 * 8];
      f16x8 kf0l = *(f16x8*)&Ksl[kc * 16 + l15][l4 * 8];
      f16x8 kf1h = *(f16x8*)&Ksh[kc * 16 + l15][32 + l4 * 8];
      f16x8 kf1l = *(f16x8*)&Ksl[kc * 16 + l15][32 + l4 * 8];
#pragma unroll
      for (int qf = 0; qf < 2; ++qf) {
        sf[qf][kc] = __builtin_amdgcn_mfma_f32_16x16x32_f16(kf0h, qh[qf][0], sf[qf][kc], 0, 0, 0);
        sf[qf][kc] = __builtin_amdgcn_mfma_f32_16x16x32_f16(kf0h, ql[qf][0], sf[qf][kc], 0, 0, 0);
        sf[qf][kc] = __builtin_amdgcn_mfma_f32_16x16x32_f16(kf0l, qh[qf][0], sf[qf][kc], 0, 0, 0);
        sf[qf][kc] = __builtin_amdgcn_mfma_f32_16x16x32_f16(kf1h, qh[qf][1], sf[qf][kc], 0, 0, 0);
        sf[qf][kc] = __builtin_amdgcn_mfma_f32_16x16x32_f16(kf1h, ql[qf][1], sf[qf][kc], 0, 0, 0);
        sf[qf][kc] = __builtin_amdgcn_mfma_f32_16x16x32_f16(kf1l, qh[qf][1], sf[qf][kc], 0, 0, 0);
      }
    }

    // online softmax per q-half (in-lane tree + 2 shfl_xor); P stored per half
#pragma unroll
    for (int qf = 0; qf < 2; ++qf) {
      float mt = -1e30f;
#pragma unroll
      for (int kc = 0; kc < 4; ++kc) {
        float a = fmaxf(fmaxf(sf[qf][kc][0], sf[qf][kc][1]),
                        fmaxf(sf[qf][kc][2], sf[qf][kc][3]));
        mt = fmaxf(mt, a);
      }
      mt = fmaxf(mt, __shfl_xor(mt, 16, 64));
      mt = fmaxf(mt, __shfl_xor(mt, 32, 64));
      float mn = fmaxf(mrun[qf], mt);
      float alpha = __expf(mrun[qf] - mn);
      mrun[qf] = mn;
      float rs = 0.f;
#pragma unroll
      for (int kc = 0; kc < 4; ++kc) {
        float p0 = __expf(sf[qf][kc][0] - mn);
        float p1 = __expf(sf[qf][kc][1] - mn);
        float p2 = __expf(sf[qf][kc][2] - mn);
        float p3 = __expf(sf[qf][kc][3] - mn);
        rs += (p0 + p1) + (p2 + p3);
        f16x4 pv = {(_Float16)p0, (_Float16)p1, (_Float16)p2, (_Float16)p3};
        *(f16x4*)&Psh[w][qf * 16 + l15][kc * 16 + 4 * l4] = pv;
      }
      rs += __shfl_xor(rs, 16, 64);
      rs += __shfl_xor(rs, 32, 64);
      lrun[qf] = lrun[qf] * alpha + rs;
#pragma unroll
      for (int r = 0; r < 4; ++r) {
        float ar = __shfl(alpha, 4 * l4 + r, 64);
        o[qf][0][r] *= ar; o[qf][1][r] *= ar;
        o[qf][2][r] *= ar; o[qf][3][r] *= ar;
      }
    }

    // O += P @ V; V fragment reads shared by both q-halves
#pragma unroll
    for (int kh = 0; kh < 2; ++kh) {
      f16x8 pa0 = *(f16x8*)&Psh[w][l15][kh * 32 + l4 * 8];
      f16x8 pa1 = *(f16x8*)&Psh[w][16 + l15][kh * 32 + l4 * 8];
#pragma unroll
      for (int oc = 0; oc < 4; ++oc) {
        int d = oc * 16 + l15;
        int chunk = (kh * 4 + l4) ^ ((d >> 3) & 7);
        f16x8 vb = *(f16x8*)&Vsh[d][chunk * 8];
        o[0][oc] = __builtin_amdgcn_mfma_f32_16x16x32_f16(pa0, vb, o[0][oc], 0, 0, 0);
        o[1][oc] = __builtin_amdgcn_mfma_f32_16x16x32_f16(pa1, vb, o[1][oc], 0, 0, 0);
      }
    }
  }

  const int slot = dir * 2 + half;
#pragma unroll
  for (int qf = 0; qf < 2; ++qf)
#pragma unroll
    for (int oc = 0; oc < 4; ++oc) {
      int col = h * 64 + oc * 16 + l15;
#pragma unroll
      for (int r = 0; r < 4; ++r) {
        int row = qw + qf * 16 + 4 * l4 + r;
        A.Opart[((size_t)slot * 4096 + row) * 256 + col] = o[qf][oc][r];
      }
    }
  if (lane < 16) {
#pragma unroll
    for (int qf = 0; qf < 2; ++qf) {
      int row = qw + qf * 16 + l15;
      A.mpart[(size_t)(slot * 4 + h) * 4096 + row] = mrun[qf];
      A.lpart[(size_t)(slot * 4 + h) * 4096 + row] = lrun[qf];
    }
  }
}

// ---------------------------------------------------------------------------
// Combine k-halves + residual (from planes) + segment-sum pooling.
__global__ __launch_bounds__(256) void k_combine_pool(
    const float* __restrict__ Opart, const float* __restrict__ mpart,
    const float* __restrict__ lpart,
    const _Float16* __restrict__ hmh, const _Float16* __restrict__ hml,
    const _Float16* __restrict__ hph, const _Float16* __restrict__ hpl,
    const int* __restrict__ b_mol, const int* __restrict__ b_prot,
    float* __restrict__ z, float* __restrict__ cnt) {
  const int row = blockIdx.x;
  const int dir = blockIdx.y;
  const int c = threadIdx.x;
  const int h = c >> 6;
  const _Float16* Hh = dir ? hph : hmh;
  const _Float16* Hl = dir ? hpl : hml;
  const int g = (dir ? b_prot : b_mol)[row];
  size_t mi0 = (size_t)((dir * 2 + 0) * 4 + h) * 4096 + row;
  size_t mi1 = (size_t)((dir * 2 + 1) * 4 + h) * 4096 + row;
  float m1 = mpart[mi0], m2 = mpart[mi1];
  float l1 = lpart[mi0], l2 = lpart[mi1];
  float M = fmaxf(m1, m2);
  float e1 = __expf(m1 - M), e2 = __expf(m2 - M);
  float L = l1 * e1 + l2 * e2;
  float O1 = Opart[((size_t)(dir * 2 + 0) * 4096 + row) * 256 + c];
  float O2 = Opart[((size_t)(dir * 2 + 1) * 4096 + row) * 256 + c];
  float hin = (float)Hh[(size_t)row * 256 + c] + (float)Hl[(size_t)row * 256 + c];
  float v = (O1 * e1 + O2 * e2) / L + hin;
  atomicAdd(&z[(size_t)g * 512 + dir * 256 + c], v);
  if (c == 0) atomicAdd(&cnt[dir * 32 + g], 1.0f);
}

// ---------------------------------------------------------------------------
// Fused head: z-mean (inline count division) -> fc1+relu -> fc2 -> sigmoid.
// One block per graph (32 blocks), 256 threads.
__global__ __launch_bounds__(256) void k_head(
    const float* __restrict__ z, const float* __restrict__ cnt,
    const float* __restrict__ w1, const float* __restrict__ b1,
    const float* __restrict__ w2, const float* __restrict__ b2,
    float* __restrict__ out) {
  __shared__ float wsum[4];
  const int r = blockIdx.x;
  const int c = threadIdx.x;
  const float im = 1.0f / fmaxf(cnt[r], 1.0f);
  const float ip = 1.0f / fmaxf(cnt[32 + r], 1.0f);
  float acc = b1[c];
  for (int k = 0; k < 256; ++k) acc += (z[r * 512 + k] * im) * w1[k * HDIM + c];
  for (int k = 256; k < 512; ++k) acc += (z[r * 512 + k] * ip) * w1[k * HDIM + c];
  acc = fmaxf(acc, 0.f);
  float p = acc * w2[c];
#pragma unroll
  for (int off = 1; off < 64; off <<= 1) p += __shfl_xor(p, off, 64);
  if ((c & 63) == 0) wsum[c >> 6] = p;
  __syncthreads();
  if (c == 0) {
    float s = (wsum[0] + wsum[1]) + (wsum[2] + wsum[3]) + b2[0];
    out[r] = 1.0f / (1.0f + __expf(-s));
  }
}

// ---------------------------------------------------------------------------
extern "C" void kernel_launch(void* const* d_in, const int* in_sizes, int n_in,
                              void* d_out, int out_size, void* d_ws, size_t ws_size,
                              hipStream_t stream) {
  const float* x_mol   = (const float*)d_in[0];
  const float* x_prot  = (const float*)d_in[1];
  const float* ea_mol  = (const float*)d_in[2];
  const float* ea_prot = (const float*)d_in[3];
  const int*   ei_mol  = (const int*)d_in[4];
  const int*   ei_prot = (const int*)d_in[5];
  const int*   b_mol   = (const int*)d_in[6];
  const int*   b_prot  = (const int*)d_in[7];
  const float* nlm_w = (const float*)d_in[8];
  const float* nlm_b = (const float*)d_in[9];
  const float* nlp_w = (const float*)d_in[10];
  const float* nlp_b = (const float*)d_in[11];
  const float* elm_w = (const float*)d_in[12];
  const float* elm_b = (const float*)d_in[13];
  const float* elp_w = (const float*)d_in[14];
  const float* elp_b = (const float*)d_in[15];
  const float* mol_w1 = (const float*)d_in[16];
  const float* mol_b1 = (const float*)d_in[17];
  const float* mol_w2 = (const float*)d_in[18];
  const float* mol_b2 = (const float*)d_in[19];
  const float* prot_w1 = (const float*)d_in[20];
  const float* prot_b1 = (const float*)d_in[21];
  const float* prot_w2 = (const float*)d_in[22];
  const float* prot_b2 = (const float*)d_in[23];
  const float* mp_wq = (const float*)d_in[24];
  const float* mp_bq = (const float*)d_in[25];
  const float* mp_wk = (const float*)d_in[26];
  const float* mp_bk = (const float*)d_in[27];
  const float* mp_wv = (const float*)d_in[28];
  const float* mp_bv = (const float*)d_in[29];
  const float* pm_wq = (const float*)d_in[30];
  const float* pm_bq = (const float*)d_in[31];
  const float* pm_wk = (const float*)d_in[32];
  const float* pm_bk = (const float*)d_in[33];
  const float* pm_wv = (const float*)d_in[34];
  const float* pm_bv = (const float*)d_in[35];
  const float* fc1_w = (const float*)d_in[36];
  const float* fc1_b = (const float*)d_in[37];
  const float* fc2_w = (const float*)d_in[38];
  const float* fc2_b = (const float*)d_in[39];
  float* out = (float*)d_out;

  // workspace carve (MB offsets); peak ~70 MB
  char* W8 = (char*)d_ws;
  const size_t MB = 1u << 20;
  _Float16* wtH  = (_Float16*)(W8 + 0 * MB);
  _Float16* wtL  = (_Float16*)(W8 + 2 * MB);
  _Float16* hmh  = (_Float16*)(W8 + 4 * MB);
  _Float16* hml  = (_Float16*)(W8 + 6 * MB);
  _Float16* hph  = (_Float16*)(W8 + 8 * MB);
  _Float16* hpl  = (_Float16*)(W8 + 10 * MB);
  _Float16* amh  = (_Float16*)(W8 + 12 * MB);
  _Float16* aml  = (_Float16*)(W8 + 14 * MB);
  _Float16* aph  = (_Float16*)(W8 + 16 * MB);
  _Float16* apl  = (_Float16*)(W8 + 18 * MB);
  _Float16* t1mh = (_Float16*)(W8 + 20 * MB);
  _Float16* t1ml = (_Float16*)(W8 + 22 * MB);
  _Float16* t1ph = (_Float16*)(W8 + 24 * MB);
  _Float16* t1pl = (_Float16*)(W8 + 26 * MB);
  _Float16* Qh0  = (_Float16*)(W8 + 28 * MB);
  _Float16* Ql0  = (_Float16*)(W8 + 30 * MB);
  _Float16* Kh0  = (_Float16*)(W8 + 32 * MB);
  _Float16* Kl0  = (_Float16*)(W8 + 34 * MB);
  _Float16* Qh1  = (_Float16*)(W8 + 36 * MB);
  _Float16* Ql1  = (_Float16*)(W8 + 38 * MB);
  _Float16* Kh1  = (_Float16*)(W8 + 40 * MB);
  _Float16* Kl1  = (_Float16*)(W8 + 42 * MB);
  _Float16* Vth0 = (_Float16*)(W8 + 44 * MB);
  _Float16* Vth1 = (_Float16*)(W8 + 46 * MB);
  float* Opart = (float*)(W8 + 48 * MB);   // 16 MB: [dir*2+half][4096][256]
  float* mpart = (float*)(W8 + 64 * MB);   // 16*4096 floats
  float* lpart = mpart + 65536;
  float* zb    = lpart + 65536;            // 32*512
  float* cnt   = zb + 32 * 512;            // 64
  int* off_m = (int*)(W8 + 65 * MB);
  int* cur_m = off_m + 4224;
  int* off_p = (int*)(W8 + 66 * MB);
  int* cur_p = off_p + 4224;
  EdgeRec* er_m = (EdgeRec*)(W8 + 67 * MB);  // 1 MB
  EdgeRec* er_p = (EdgeRec*)(W8 + 68 * MB);  // 1 MB

  // weights: 0,1 mol_w1 | 2,3 mol_w2 | 4,5 prot_w1 | 6,7 prot_w2
  // 8 mp_wq 9 mp_wk 10 mp_wv | 11 pm_wq 12 pm_wk 13 pm_wv
  PtrPack pk;
  pk.p[0] = mol_w1;           pk.p[1] = mol_w1 + 65536;
  pk.p[2] = mol_w2;           pk.p[3] = mol_w2 + 65536;
  pk.p[4] = prot_w1;          pk.p[5] = prot_w1 + 65536;
  pk.p[6] = prot_w2;          pk.p[7] = prot_w2 + 65536;
  pk.p[8] = mp_wq;  pk.p[9] = mp_wk;  pk.p[10] = mp_wv;
  pk.p[11] = pm_wq; pk.p[12] = pm_wk; pk.p[13] = pm_wv;
  k_prep_wt<<<dim3(4, 4, 14), 256, 0, stream>>>(pk, wtH, wtL);

  hipMemsetAsync(cur_m, 0, 4096 * 4, stream);
  hipMemsetAsync(cur_p, 0, 4096 * 4, stream);
  k_csr_count2<<<dim3(NEDGE / 256, 2), 256, 0, stream>>>(ei_mol, ei_prot, cur_m, cur_p, NEDGE);
  k_csr_scan2<<<2, 256, 0, stream>>>(cur_m, off_m, cur_p, off_p, NMOL);
  k_csr_scatter2<<<dim3(NEDGE / 256, 2), 256, 0, stream>>>(ei_mol, ei_prot, ea_mol, ea_prot,
                                                           cur_m, cur_p, er_m, er_p, NEDGE);

  EmbJob em = {x_mol, nlm_w, nlm_b, hmh, hml, 8};
  EmbJob ep = {x_prot, nlp_w, nlp_b, hph, hpl, 4};
  k_node_embed2<<<dim3(NMOL, 2), 256, 0, stream>>>(em, ep);

#define WTH(i) (wtH + (size_t)(i) * 65536)
#define WTL(i) (wtL + (size_t)(i) * 65536)

  AggJob am = {hmh, hml, er_m, off_m, elm_w, elm_b, amh, aml};
  AggJob ap = {hph, hpl, er_p, off_p, elp_w, elp_b, aph, apl};

  for (int l = 0; l < 2; ++l) {
    k_agg2<<<dim3(NMOL, 2), 256, 0, stream>>>(am, ap);
    GJobs g1 = {};
    g1.j[0] = {amh, aml, WTH(l), WTL(l), mol_b1 + l * 256,
               t1mh, t1ml, nullptr, 1.0f, 1 | (1 << 4)};
    g1.j[1] = {aph, apl, WTH(4 + l), WTL(4 + l), prot_b1 + l * 256,
               t1ph, t1pl, nullptr, 1.0f, 1 | (1 << 4)};
    k_gemm<<<dim3(64, 4, 2), 256, 0, stream>>>(g1);
    GJobs g2 = {};
    g2.j[0] = {t1mh, t1ml, WTH(2 + l), WTL(2 + l), mol_b2 + l * 256,
               hmh, hml, nullptr, 1.0f, 1 | (1 << 4)};
    g2.j[1] = {t1ph, t1pl, WTH(6 + l), WTL(6 + l), prot_b2 + l * 256,
               hph, hpl, nullptr, 1.0f, 1 | (1 << 4)};
    k_gemm<<<dim3(64, 4, 2), 256, 0, stream>>>(g2);
  }

  // QKV for both attention directions, one dispatch (z=6); V transposed in-epilogue
  {
    GJobs q = {};
    q.j[0] = {hmh, hml, WTH(8), WTL(8), mp_bq, Qh0, Ql0, nullptr, 0.125f, 1 << 4};
    q.j[1] = {hph, hpl, WTH(9), WTL(9), mp_bk, Kh0, Kl0, nullptr, 1.0f, 1 << 4};
    q.j[2] = {hph, hpl, WTH(10), WTL(10), mp_bv, nullptr, nullptr, Vth0, 1.0f, 3 << 4};
    q.j[3] = {hph, hpl, WTH(11), WTL(11), pm_bq, Qh1, Ql1, nullptr, 0.125f, 1 << 4};
    q.j[4] = {hmh, hml, WTH(12), WTL(12), pm_bk, Kh1, Kl1, nullptr, 1.0f, 1 << 4};
    q.j[5] = {hmh, hml, WTH(13), WTL(13), pm_bv, nullptr, nullptr, Vth1, 1.0f, 3 << 4};
    k_gemm<<<dim3(64, 4, 6), 256, 0, stream>>>(q);
  }

  AttnArgs aa;
  aa.Qh[0] = Qh0; aa.Ql[0] = Ql0; aa.Kh[0] = Kh0; aa.Kl[0] = Kl0; aa.Vth[0] = Vth0;
  aa.Qh[1] = Qh1; aa.Ql[1] = Ql1; aa.Kh[1] = Kh1; aa.Kl[1] = Kl1; aa.Vth[1] = Vth1;
  aa.Opart = Opart; aa.mpart = mpart; aa.lpart = lpart;
  k_attn5<<<dim3(32, 8, 2), 256, 0, stream>>>(aa, 2048);

  hipMemsetAsync(zb, 0, (32 * 512 + 64) * 4, stream);
  k_combine_pool<<<dim3(4096, 2), 256, 0, stream>>>(Opart, mpart, lpart,
                                                    hmh, hml, hph, hpl,
                                                    b_mol, b_prot, zb, cnt);
  k_head<<<NG, 256, 0, stream>>>(zb, cnt, fc1_w, fc1_b, fc2_w, fc2_b, out);
#undef WTH
#undef WTL
}